// Round 15
// baseline (1869.220 us; speedup 1.0000x reference)
//
#include <hip/hip_runtime.h>
#include <hip/hip_bf16.h>
#include <math.h>

typedef unsigned short u16;
typedef __attribute__((ext_vector_type(8))) short bf16x8;
typedef __attribute__((ext_vector_type(4))) float f32x4;

__device__ __forceinline__ float b2f(u16 v) {
  unsigned u = ((unsigned)v) << 16;
  return __builtin_bit_cast(float, u);
}
__device__ __forceinline__ u16 f2b(float f) {
  unsigned u = __builtin_bit_cast(unsigned, f);
  unsigned r = u + 0x7fffu + ((u >> 16) & 1u);
  return (u16)(r >> 16);
}
__device__ __forceinline__ void gload_lds16(const u16* g, u16* l) {
  __builtin_amdgcn_global_load_lds(
      (const __attribute__((address_space(1))) void*)g,
      (__attribute__((address_space(3))) void*)l, 16, 0, 0);
}

// ---------------- fp32 -> bf16 convert ----------------
__global__ __launch_bounds__(256) void cvt_bf16_k(const float* __restrict__ s,
                                                  u16* __restrict__ d, int n4) {
  int i = blockIdx.x * 256 + threadIdx.x;
  if (i < n4) {
    float4 v = ((const float4*)s)[i];
    ushort4 o;
    o.x = f2b(v.x); o.y = f2b(v.y); o.z = f2b(v.z); o.w = f2b(v.w);
    ((ushort4*)d)[i] = o;
  }
}

// ---------------- Toeplitz expansion of 31x31 kernel ----------------
__global__ __launch_bounds__(256) void toeplitz_k(
    const float* __restrict__ kw, u16* __restrict__ tb)
{
  int i = blockIdx.x * 256 + threadIdx.x;
  if (i >= 31744) return;
  int k = i & 31, n = (i >> 5) & 15, h = (i >> 9) & 1, ki = i >> 10;
  int t = h * 32 + k - n;
  float v = (t >= 0 && t <= 30) ? kw[ki * 31 + t] : 0.f;
  tb[i] = f2b(v);
}

// ---------------- patchify + pos embed -> h fp32 + h_bf ----------------
__global__ __launch_bounds__(256) void patchify_k(
    const float* __restrict__ x, const int* __restrict__ mask,
    const float* __restrict__ pw, const float* __restrict__ pb,
    const float* __restrict__ pos, float* __restrict__ h, u16* __restrict__ hb)
{
  int g1 = blockIdx.x, b = blockIdx.y, tid = threadIdx.x;
  __shared__ float sX[64 * 17];
  __shared__ float sW[2048];
  for (int i = tid; i < 64 * 16; i += 256) {
    int r = i >> 4, c = i & 15;
    int gi = (b * 64 + r) * 4096 + g1 * 16 + c;
    sX[r * 17 + c] = mask[gi] ? 0.f : x[gi];
  }
  for (int i = tid; i < 2048; i += 256) sW[i] = pw[i];
  __syncthreads();
  for (int m = tid; m < 2048; m += 256) {
    int e = m >> 5, g0 = m & 31;
    float acc = pb[e];
    const float* w = &sW[e * 32];
#pragma unroll
    for (int kh = 0; kh < 2; ++kh)
#pragma unroll
      for (int kw = 0; kw < 16; ++kw)
        acc += sX[(2 * g0 + kh) * 17 + kw] * w[kh * 16 + kw];
    float v = acc + pos[g1 * 2048 + m];
    long o = ((long)b * 256 + g1) * 2048 + m;
    h[o] = v;
    hb[o] = f2b(v);
  }
}

// ========== 256x256x(BK=32) 8-wave MFMA GEMM for in_proj ====================
// BK=32 + split conv epilogue -> 69.2 KB LDS -> 2 blocks/CU co-resident.
// Granule swizzle s^=(row&3)^(((row>>2)&1)<<1) (involution, 2-way = free).
// Counted vmcnt(4): retire tile kt, keep tile kt+1's 4 loads in flight.
__global__ __launch_bounds__(512, 4) void gemm256_k(
    const u16* __restrict__ A0,               // h_bf (2048 x 2048)
    const u16* __restrict__ B0, long bStride, // Wip_bf (8192 x 2048) per dir
    u16* __restrict__ C0, long cStride,       // xz_bf (2048 x 8192) per dir
    const float* __restrict__ cw,             // conv weights (2,4096,4)
    const float* __restrict__ cb,             // conv bias (2,4096)
    u16* __restrict__ ub)                     // u_bf (2,8,256,4096)
{
  constexpr int K = 2048, N = 8192, LDA = 2048;
  // GEMM: As = lds[0..8191]x2buf (16KB each half), Bs = lds[16384..]
  // Epilogue: tile[128][264] = lds[0..33791]; side[3][264] at 33792.
  __shared__ __align__(16) u16 lds[34584];
  u16* As = lds;             // [2][8192]
  u16* Bs = lds + 16384;     // [2][8192]
  const int dir = blockIdx.z;
  const u16* A = A0;
  const u16* B = B0 + (long)dir * bStride;
  u16* C = C0 + (long)dir * cStride;
  const int flip = dir;

  const int tid = threadIdx.x;
  const int wave = tid >> 6, lane = tid & 63;
  const int wr = wave >> 2, wc = wave & 3;    // 2x4 wave grid; 128x64 C/wave
  const int bm = blockIdx.y * 256, bn = blockIdx.x * 256;
  const int lr = lane & 15, lq = lane >> 4;

  f32x4 acc[8][4];
#pragma unroll
  for (int i = 0; i < 8; ++i)
#pragma unroll
    for (int j = 0; j < 4; ++j) acc[i][j] = (f32x4){0.f, 0.f, 0.f, 0.f};

  // stage K-tile kt (32 k) into buf: 4 gload_lds/thread (2 A + 2 B)
  auto stage = [&](int buf, int kt) {
    int k0 = kt << 5;
#pragma unroll
    for (int j = 0; j < 2; ++j) {
      int g = j * 512 + tid;               // granule 0..1023
      int row = g >> 2, sp = g & 3;
      int ss = sp ^ (row & 3) ^ (((row >> 2) & 1) << 1);
      int ar = flip ? (bm + 255 - row) : (bm + row);
      gload_lds16(A + (long)ar * LDA + k0 + ss * 8, &As[buf * 8192 + g * 8]);
      gload_lds16(B + (long)(bn + row) * K + k0 + ss * 8,
                  &Bs[buf * 8192 + g * 8]);
    }
  };

  const int nk = K >> 5;                     // 64 K-tiles
  stage(0, 0);
  for (int kt = 0; kt < nk; ++kt) {
    __builtin_amdgcn_s_barrier();
    __builtin_amdgcn_sched_barrier(0);
    if (kt + 1 < nk) {
      stage((kt + 1) & 1, kt + 1);
      asm volatile("s_waitcnt vmcnt(4)" ::: "memory");   // tile kt landed
    } else {
      asm volatile("s_waitcnt vmcnt(0)" ::: "memory");
    }
    __builtin_amdgcn_sched_barrier(0);
    __builtin_amdgcn_s_barrier();
    __builtin_amdgcn_sched_barrier(0);
    const int buf = kt & 1;
    bf16x8 av[8], bv[4];
#pragma unroll
    for (int i = 0; i < 8; ++i) {
      int R = wr * 128 + i * 16 + lr;
      int gp = lq ^ (R & 3) ^ (((R >> 2) & 1) << 1);
      av[i] = *(const bf16x8*)&As[buf * 8192 + R * 32 + gp * 8];
    }
#pragma unroll
    for (int j = 0; j < 4; ++j) {
      int R = wc * 64 + j * 16 + lr;
      int gp = lq ^ (R & 3) ^ (((R >> 2) & 1) << 1);
      bv[j] = *(const bf16x8*)&Bs[buf * 8192 + R * 32 + gp * 8];
    }
    __builtin_amdgcn_s_setprio(1);
#pragma unroll
    for (int i = 0; i < 8; ++i)
#pragma unroll
      for (int j = 0; j < 4; ++j)
        acc[i][j] = __builtin_amdgcn_mfma_f32_16x16x32_bf16(
            av[i], bv[j], acc[i][j], 0, 0, 0);
    __builtin_amdgcn_s_setprio(0);
  }

  if (bn < 4096) {
    // ---- fused conv1d + SiLU epilogue, two 128-row halves ----
    u16* tile = lds;                  // [128][264]
    u16* side = lds + 33792;          // [3][264]
    const int rgrp = tid >> 5, c8 = tid & 31;
    const int d0 = bn + c8 * 8;
    float wv0[8], wv1[8], wv2[8], wv3[8], cbv[8];
#pragma unroll
    for (int e = 0; e < 8; ++e) {
      const float4 wq = *(const float4*)(cw + ((long)dir * 4096 + d0 + e) * 4);
      wv0[e] = wq.x; wv1[e] = wq.y; wv2[e] = wq.z; wv3[e] = wq.w;
      cbv[e] = cb[dir * 4096 + d0 + e];
    }
    float w0[8], w1[8], w2[8];

    auto writeacc = [&]() {
#pragma unroll
      for (int i = 0; i < 8; ++i) {
        int r0 = i * 16 + lq * 4;     // local row in half
#pragma unroll
        for (int j = 0; j < 4; ++j) {
          int col = wc * 64 + j * 16 + lr;
          f32x4 v = acc[i][j];
#pragma unroll
          for (int r = 0; r < 4; ++r)
            tile[(r0 + r) * 264 + col] = f2b(v[r]);
        }
      }
    };

    auto convhalf = [&](int hh) {
      if (rgrp == 0) {
        if (hh == 0) {
#pragma unroll
          for (int e = 0; e < 8; ++e) { w0[e] = 0.f; w1[e] = 0.f; w2[e] = 0.f; }
        } else {
          bf16x8 t0 = *(const bf16x8*)&side[0 * 264 + c8 * 8];
          bf16x8 t1 = *(const bf16x8*)&side[1 * 264 + c8 * 8];
          bf16x8 t2 = *(const bf16x8*)&side[2 * 264 + c8 * 8];
#pragma unroll
          for (int e = 0; e < 8; ++e) {
            w0[e] = b2f((u16)t0[e]); w1[e] = b2f((u16)t1[e]);
            w2[e] = b2f((u16)t2[e]);
          }
        }
      } else {
        int lb = rgrp * 8;
        bf16x8 t0 = *(const bf16x8*)&tile[(lb - 3) * 264 + c8 * 8];
        bf16x8 t1 = *(const bf16x8*)&tile[(lb - 2) * 264 + c8 * 8];
        bf16x8 t2 = *(const bf16x8*)&tile[(lb - 1) * 264 + c8 * 8];
#pragma unroll
        for (int e = 0; e < 8; ++e) {
          w0[e] = b2f((u16)t0[e]); w1[e] = b2f((u16)t1[e]);
          w2[e] = b2f((u16)t2[e]);
        }
      }
      long ubase = ((long)(dir * 8 + blockIdx.y) * 256 + hh * 128 + rgrp * 8)
                       * 4096 + d0;
#pragma unroll
      for (int l = 0; l < 8; ++l) {
        bf16x8 t = *(const bf16x8*)&tile[(rgrp * 8 + l) * 264 + c8 * 8];
        float cur[8];
#pragma unroll
        for (int e = 0; e < 8; ++e) cur[e] = b2f((u16)t[e]);
        bf16x8 ov;
#pragma unroll
        for (int e = 0; e < 8; ++e) {
          float a = cbv[e] + wv0[e] * w0[e] + wv1[e] * w1[e] + wv2[e] * w2[e] +
                    wv3[e] * cur[e];
          ov[e] = (short)f2b(a / (1.f + __expf(-a)));
        }
        *(bf16x8*)(ub + ubase + (long)l * 4096) = ov;
#pragma unroll
        for (int e = 0; e < 8; ++e) { w0[e] = w1[e]; w1[e] = w2[e]; w2[e] = cur[e]; }
      }
    };

    __syncthreads();                  // K-loop LDS reads retired
    if (wr == 0) writeacc();          // rows 0..127
    __syncthreads();
    convhalf(0);
    if (tid < 96) {                   // save rows 125..127 for half-1 carry
      int rr = tid >> 5, cc = tid & 31;
      *(bf16x8*)&side[rr * 264 + cc * 8] =
          *(const bf16x8*)&tile[(125 + rr) * 264 + cc * 8];
    }
    __syncthreads();
    if (wr == 1) writeacc();          // rows 128..255 (local 0..127)
    __syncthreads();
    convhalf(1);
  } else {
    // ---- z half: plain C write ----
#pragma unroll
    for (int i = 0; i < 8; ++i) {
      int r0 = bm + wr * 128 + i * 16 + lq * 4;
#pragma unroll
      for (int j = 0; j < 4; ++j) {
        int col = bn + wc * 64 + j * 16 + lr;
        f32x4 v = acc[i][j];
#pragma unroll
        for (int r = 0; r < 4; ++r)
          C[(long)(r0 + r) * N + col] = f2b(v[r]);
      }
    }
  }
}

// ---------------- bf16 MFMA GEMM (128x128, m97 structure) ----------------
template <int EPI, int F32OUT, int BFOUT>
__global__ __launch_bounds__(256) void mfma_gemm_k(
    const u16* __restrict__ A0, long aStride,
    const u16* __restrict__ B0, long bStride,
    float* __restrict__ C0, long cStride,
    u16* __restrict__ Cb0, long cbStride,
    const float* __restrict__ bias0, int biasStride,
    int N, int K, int lda, int flipDir1)
{
  __shared__ __align__(16) u16 As[2][4096];
  __shared__ __align__(16) u16 Bs[2][4096];
  const int dir = blockIdx.z;
  const u16* A = A0 + (long)dir * aStride;
  const u16* B = B0 + (long)dir * bStride;
  float* C = F32OUT ? (C0 + (long)dir * cStride) : nullptr;
  u16* Cb = BFOUT ? (Cb0 + (long)dir * cbStride) : nullptr;
  const float* bias = (EPI == 1) ? (bias0 + (long)dir * biasStride) : nullptr;
  const int flip = flipDir1 && (dir == 1);

  const int tid = threadIdx.x;
  const int wave = tid >> 6, lane = tid & 63;
  const int wr = wave >> 1, wc = wave & 1;
  const int bm = blockIdx.y * 128, bn = blockIdx.x * 128;
  const int lr = lane & 15, lq = lane >> 4;

  f32x4 acc[4][4];
#pragma unroll
  for (int i = 0; i < 4; ++i)
#pragma unroll
    for (int j = 0; j < 4; ++j) acc[i][j] = (f32x4){0.f, 0.f, 0.f, 0.f};

  const int nk = K >> 5;

  auto stage = [&](int buf, int k0) {
#pragma unroll
    for (int iss = 0; iss < 2; ++iss) {
      int ob = wave * 2048 + iss * 1024 + lane * 16;
      int row = ob >> 6, kb = (ob >> 4) & 3;
      int rg = bm + row;
      rg = flip ? ((rg & ~255) | (255 - (rg & 255))) : rg;
      gload_lds16(A + (long)rg * lda + k0 + kb * 8,
                  &As[buf][wave * 1024 + iss * 512]);
      int rb = bn + row; rb = (rb < N) ? rb : (N - 1);
      gload_lds16(B + (long)rb * K + k0 + kb * 8,
                  &Bs[buf][wave * 1024 + iss * 512]);
    }
  };

  stage(0, 0);
  for (int kt = 0; kt < nk; ++kt) {
    __syncthreads();
    if (kt + 1 < nk) stage((kt + 1) & 1, (kt + 1) << 5);
    const int buf = kt & 1;
    bf16x8 av[4], bv[4];
#pragma unroll
    for (int i = 0; i < 4; ++i)
      av[i] = *(const bf16x8*)&As[buf][(wr * 64 + i * 16 + lr) * 32 + lq * 8];
#pragma unroll
    for (int j = 0; j < 4; ++j)
      bv[j] = *(const bf16x8*)&Bs[buf][(wc * 64 + j * 16 + lr) * 32 + lq * 8];
#pragma unroll
    for (int i = 0; i < 4; ++i)
#pragma unroll
      for (int j = 0; j < 4; ++j)
        acc[i][j] = __builtin_amdgcn_mfma_f32_16x16x32_bf16(av[i], bv[j],
                                                            acc[i][j], 0, 0, 0);
  }

#pragma unroll
  for (int i = 0; i < 4; ++i) {
    int r0 = bm + wr * 64 + i * 16 + lq * 4;
#pragma unroll
    for (int j = 0; j < 4; ++j) {
      int col = bn + wc * 64 + j * 16 + lr;
      if (col < N) {
        f32x4 v = acc[i][j];
#pragma unroll
        for (int r = 0; r < 4; ++r) {
          float xv = v[r];
          if (EPI == 1) {
            xv += bias[col];
            xv = (xv > 20.f) ? xv : log1pf(expf(xv));
          }
          if (F32OUT) C[(long)(r0 + r) * N + col] = xv;
          if (BFOUT) Cb[(long)(r0 + r) * N + col] = f2b(xv);
        }
      }
    }
  }
}

// ---------------- x_dbl split-K partial GEMM ----------------
__global__ __launch_bounds__(256) void xdbl_part_k(
    const u16* __restrict__ ubf, const u16* __restrict__ Wxbf,
    float* __restrict__ part)
{
  __shared__ __align__(16) u16 As[2][4096];
  __shared__ __align__(16) u16 Bs[2][4096];
  const int dir = blockIdx.z >> 2, split = blockIdx.z & 3;
  const u16* A = ubf + (long)dir * 2048 * 4096;
  const u16* B = Wxbf + (long)dir * 160 * 4096;
  float* C = part + (long)blockIdx.z * 327680;
  const int tid = threadIdx.x;
  const int wave = tid >> 6, lane = tid & 63;
  const int wr = wave >> 1, wc = wave & 1;
  const int bm = blockIdx.y * 128, bn = blockIdx.x * 128;
  const int lr = lane & 15, lq = lane >> 4;

  f32x4 acc[4][4];
#pragma unroll
  for (int i = 0; i < 4; ++i)
#pragma unroll
    for (int j = 0; j < 4; ++j) acc[i][j] = (f32x4){0.f, 0.f, 0.f, 0.f};

  auto stage = [&](int buf, int k0) {
#pragma unroll
    for (int iss = 0; iss < 2; ++iss) {
      int ob = wave * 2048 + iss * 1024 + lane * 16;
      int row = ob >> 6, kb = (ob >> 4) & 3;
      gload_lds16(A + (long)(bm + row) * 4096 + k0 + kb * 8,
                  &As[buf][wave * 1024 + iss * 512]);
      int rb = bn + row; rb = (rb < 160) ? rb : 159;
      gload_lds16(B + (long)rb * 4096 + k0 + kb * 8,
                  &Bs[buf][wave * 1024 + iss * 512]);
    }
  };

  const int kbase = split << 10;
  stage(0, kbase);
  for (int kt = 0; kt < 32; ++kt) {
    __syncthreads();
    if (kt + 1 < 32) stage((kt + 1) & 1, kbase + ((kt + 1) << 5));
    const int buf = kt & 1;
    bf16x8 av[4], bv[4];
#pragma unroll
    for (int i = 0; i < 4; ++i)
      av[i] = *(const bf16x8*)&As[buf][(wr * 64 + i * 16 + lr) * 32 + lq * 8];
#pragma unroll
    for (int j = 0; j < 4; ++j)
      bv[j] = *(const bf16x8*)&Bs[buf][(wc * 64 + j * 16 + lr) * 32 + lq * 8];
#pragma unroll
    for (int i = 0; i < 4; ++i)
#pragma unroll
      for (int j = 0; j < 4; ++j)
        acc[i][j] = __builtin_amdgcn_mfma_f32_16x16x32_bf16(av[i], bv[j],
                                                            acc[i][j], 0, 0, 0);
  }

#pragma unroll
  for (int i = 0; i < 4; ++i) {
    int r0 = bm + wr * 64 + i * 16 + lq * 4;
#pragma unroll
    for (int j = 0; j < 4; ++j) {
      int col = bn + wc * 64 + j * 16 + lr;
      if (col < 160) {
        f32x4 v = acc[i][j];
#pragma unroll
        for (int r = 0; r < 4; ++r)
          C[(long)(r0 + r) * 160 + col] = v[r];
      }
    }
  }
}

// ---------------- x_dbl split-K reduce -> fp32 + bf16 ----------------
__global__ __launch_bounds__(256) void xdbl_reduce_k(
    const float* __restrict__ part, float* __restrict__ xdbl,
    u16* __restrict__ xdbl_bf)
{
  int i = blockIdx.x * 256 + threadIdx.x;
  if (i >= 655360) return;
  int dir = i / 327680, rem = i - dir * 327680;
  long pb = (long)dir * 4 * 327680 + rem;
  float s = part[pb] + part[pb + 327680] + part[pb + 2 * 327680] +
            part[pb + 3 * 327680];
  xdbl[i] = s;
  xdbl_bf[i] = f2b(s);
}

// ---------------- scan pass A: per-chunk local scan (zero init) --------------
__global__ __launch_bounds__(256) void scan_a_k(
    const u16* __restrict__ dtbuf, const u16* __restrict__ ubuf,
    const float* __restrict__ xdbl, const float* __restrict__ A_log,
    const float* __restrict__ Dpv, u16* __restrict__ ypre,
    float* __restrict__ stend, float* __restrict__ dtsum)
{
  int blk = blockIdx.x;
  int dtile = blk & 15, c = (blk >> 4) & 7, b = (blk >> 7) & 7, dir = blk >> 10;
  int tid = threadIdx.x;
  int d = dtile * 256 + tid;
  int db = dir * 8 + b;

  __shared__ float sB[32][16], sC[32][16];
  long r160 = (long)db * 256 * 160;
  for (int i = tid; i < 1024; i += 256) {
    int l = i >> 5, s = i & 31;
    float v = xdbl[r160 + (long)(c * 32 + l) * 160 + 128 + s];
    if (s < 16) sB[l][s] = v; else sC[l][s - 16] = v;
  }
  __syncthreads();

  float A[16], st[16];
  const float4* ap = (const float4*)(A_log + ((long)dir * 4096 + d) * 16);
#pragma unroll
  for (int q = 0; q < 4; ++q) {
    float4 t = ap[q];
    A[q * 4 + 0] = -__expf(t.x); A[q * 4 + 1] = -__expf(t.y);
    A[q * 4 + 2] = -__expf(t.z); A[q * 4 + 3] = -__expf(t.w);
  }
#pragma unroll
  for (int s = 0; s < 16; ++s) st[s] = 0.f;
  float Dpd = Dpv[dir * 4096 + d];

  long base = (long)db * 256 * 4096 + (long)c * 32 * 4096 + d;
  float dts = 0.f;
  for (int i = 0; i < 32; ++i) {
    float dtv = b2f(dtbuf[base + (long)i * 4096]);
    float uv  = b2f(ubuf[base + (long)i * 4096]);
    dts += dtv;
    float du = dtv * uv;
    float y = 0.f;
#pragma unroll
    for (int s = 0; s < 16; ++s) {
      st[s] = st[s] * __expf(dtv * A[s]) + du * sB[i][s];
      y += st[s] * sC[i][s];
    }
    ypre[base + (long)i * 4096] = f2b(y + uv * Dpd);
  }
  long eb = ((long)(db * 8 + c) * 4096 + d) * 16;
  float4* ep = (float4*)(stend + eb);
#pragma unroll
  for (int q = 0; q < 4; ++q)
    ep[q] = make_float4(st[q * 4], st[q * 4 + 1], st[q * 4 + 2], st[q * 4 + 3]);
  dtsum[(long)(db * 8 + c) * 4096 + d] = dts;
}

// ---------------- scan pass B: chunk combine + correction + gating -----------
__global__ __launch_bounds__(512) void scan_b_k(
    const u16* __restrict__ dtbuf, const u16* __restrict__ xzbf,
    const float* __restrict__ xdbl, const float* __restrict__ A_log,
    const float* __restrict__ stend, const float* __restrict__ dtsum,
    u16* __restrict__ ybuf)
{
  int blk = blockIdx.x;
  int dtile = blk & 63, b = (blk >> 6) & 7, dir = blk >> 9;
  int tid = threadIdx.x;
  int c = tid >> 6, dd = tid & 63;
  int d0 = dtile * 64, d = d0 + dd;
  int db = dir * 8 + b;

  __shared__ float sEnd[8][64][17];
  __shared__ float sT[8][64];
  __shared__ float sC[256][16];

  long eBase = (long)db * 8 * 65536;
  for (int i = tid; i < 8192; i += 512) {
    int cc = i >> 10, rem = i & 1023, dd2 = rem >> 4, s = rem & 15;
    sEnd[cc][dd2][s] = stend[eBase + (long)cc * 65536 + (long)(d0 + dd2) * 16 + s];
  }
  {
    int cc = tid >> 6, dd2 = tid & 63;
    sT[cc][dd2] = dtsum[(long)(db * 8 + cc) * 4096 + d0 + dd2];
  }
  long r160 = (long)db * 256 * 160;
  for (int i = tid; i < 4096; i += 512) {
    int l = i >> 4, s = i & 15;
    sC[l][s] = xdbl[r160 + (long)l * 160 + 144 + s];
  }
  __syncthreads();

  float A[16];
  const float4* ap = (const float4*)(A_log + ((long)dir * 4096 + d) * 16);
#pragma unroll
  for (int q = 0; q < 4; ++q) {
    float4 t = ap[q];
    A[q * 4 + 0] = -__expf(t.x); A[q * 4 + 1] = -__expf(t.y);
    A[q * 4 + 2] = -__expf(t.z); A[q * 4 + 3] = -__expf(t.w);
  }
  float g[16];
#pragma unroll
  for (int s = 0; s < 16; ++s) g[s] = 0.f;
  for (int j = 0; j < c; ++j) {
    float Tj = sT[j][dd];
#pragma unroll
    for (int s = 0; s < 16; ++s)
      g[s] = g[s] * __expf(A[s] * Tj) + sEnd[j][dd][s];
  }

  long base  = (long)db * 256 * 4096 + (long)c * 32 * 4096 + d;
  long zbase = (long)db * 256 * 8192 + (long)c * 32 * 8192 + 4096 + d;
  float cum = 0.f;
  if (c == 0) {
    for (int i = 0; i < 32; ++i) {
      float yp = b2f(ybuf[base + (long)i * 4096]);
      float zv = b2f(xzbf[zbase + (long)i * 8192]);
      float y = yp * (zv / (1.f + __expf(-zv)));
      ybuf[base + (long)i * 4096] = f2b(y);
    }
  } else {
    for (int i = 0; i < 32; ++i) {
      float dtv = b2f(dtbuf[base + (long)i * 4096]);
      cum += dtv;
      float yp = b2f(ybuf[base + (long)i * 4096]);
      float corr = 0.f;
      const int l = c * 32 + i;
#pragma unroll
      for (int s = 0; s < 16; ++s)
        corr += sC[l][s] * __expf(A[s] * cum) * g[s];
      float zv = b2f(xzbf[zbase + (long)i * 8192]);
      float y = (yp + corr) * (zv / (1.f + __expf(-zv)));
      ybuf[base + (long)i * 4096] = f2b(y);
    }
  }
}

// ---------------- residual add (fwd + flipped rev) + LayerNorm ----------------
__global__ __launch_bounds__(256) void add_ln_k(
    const float* __restrict__ h, const float* __restrict__ o0,
    const float* __restrict__ o1, const float* __restrict__ g,
    const float* __restrict__ bta, float* __restrict__ h2)
{
  int row = blockIdx.x;
  int b = row >> 8, l = row & 255;
  long base = (long)row * 2048;
  long base1 = ((long)b * 256 + (255 - l)) * 2048;
  int t8 = threadIdx.x * 8;
  float v[8];
  float4 x0 = *(const float4*)(h + base + t8);
  float4 x1 = *(const float4*)(h + base + t8 + 4);
  float4 a0 = *(const float4*)(o0 + base + t8);
  float4 a1 = *(const float4*)(o0 + base + t8 + 4);
  float4 c0 = *(const float4*)(o1 + base1 + t8);
  float4 c1 = *(const float4*)(o1 + base1 + t8 + 4);
  v[0] = x0.x + a0.x + c0.x; v[1] = x0.y + a0.y + c0.y;
  v[2] = x0.z + a0.z + c0.z; v[3] = x0.w + a0.w + c0.w;
  v[4] = x1.x + a1.x + c1.x; v[5] = x1.y + a1.y + c1.y;
  v[6] = x1.z + a1.z + c1.z; v[7] = x1.w + a1.w + c1.w;
  float s = 0.f, ss = 0.f;
#pragma unroll
  for (int j = 0; j < 8; ++j) { s += v[j]; ss += v[j] * v[j]; }
#pragma unroll
  for (int off = 32; off >= 1; off >>= 1) {
    s += __shfl_xor(s, off, 64);
    ss += __shfl_xor(ss, off, 64);
  }
  __shared__ float red[8];
  int wid = threadIdx.x >> 6, lane = threadIdx.x & 63;
  if (lane == 0) { red[wid] = s; red[wid + 4] = ss; }
  __syncthreads();
  if (threadIdx.x == 0) {
    red[0] = red[0] + red[1] + red[2] + red[3];
    red[4] = red[4] + red[5] + red[6] + red[7];
  }
  __syncthreads();
  float mean = red[0] * (1.f / 2048.f);
  float var = red[4] * (1.f / 2048.f) - mean * mean;
  float inv = rsqrtf(var + 1e-5f);
  float o[8];
#pragma unroll
  for (int j = 0; j < 8; ++j)
    o[j] = (v[j] - mean) * inv * g[t8 + j] + bta[t8 + j];
  *(float4*)(h2 + base + t8) = make_float4(o[0], o[1], o[2], o[3]);
  *(float4*)(h2 + base + t8 + 4) = make_float4(o[4], o[5], o[6], o[7]);
}

// ---------------- 31x31 "same" conv via MFMA Toeplitz ----------------
__global__ __launch_bounds__(256) void dec_conv31_k(
    const float* __restrict__ h2, const u16* __restrict__ tb,
    float* __restrict__ dc)
{
  __shared__ __align__(16) u16 sIn[94 * 120];
  const int b = blockIdx.z;
  const int l0 = blockIdx.y * 64;
  const int m0 = blockIdx.x * 64;
  const int tid = threadIdx.x;
  const float* src = h2 + (long)b * 256 * 2048;
  for (int i = tid; i < 94 * 112; i += 256) {
    int r = i / 112, c = i - r * 112;
    int gl = l0 + r - 15, gm = m0 + c - 15;
    float v = 0.f;
    if (gl >= 0 && gl < 256 && gm >= 0 && gm < 2048)
      v = src[(long)gl * 2048 + gm];
    sIn[r * 120 + c] = f2b(v);
  }
  __syncthreads();
  const int wave = tid >> 6, lane = tid & 63;
  const int lr = lane & 15, lq = lane >> 4;

  f32x4 acc[4];
#pragma unroll
  for (int s = 0; s < 4; ++s) acc[s] = (f32x4){0.f, 0.f, 0.f, 0.f};

#pragma unroll 1
  for (int ki = 0; ki < 31; ++ki) {
    const u16* arow = &sIn[(wave * 16 + lr + ki) * 120];
#pragma unroll
    for (int h = 0; h < 2; ++h) {
      bf16x8 bv = *(const bf16x8*)&tb[((ki * 2 + h) * 16 + lr) * 32 + lq * 8];
#pragma unroll
      for (int ms = 0; ms < 4; ++ms) {
        bf16x8 av = *(const bf16x8*)&arow[ms * 16 + h * 32 + lq * 8];
        acc[ms] = __builtin_amdgcn_mfma_f32_16x16x32_bf16(av, bv, acc[ms], 0, 0, 0);
      }
    }
  }
#pragma unroll
  for (int ms = 0; ms < 4; ++ms) {
    f32x4 v = acc[ms];
#pragma unroll
    for (int r = 0; r < 4; ++r)
      dc[((long)b * 256 + l0 + wave * 16 + lq * 4 + r) * 2048 + m0 + ms * 16 + lr]
          = v[r];
  }
}

// ---------------- fused transposed conv (stride 2x16) ----------------
__global__ __launch_bounds__(256) void convT_k(
    const float* __restrict__ dc, const float* __restrict__ w,
    const float* __restrict__ wb, float* __restrict__ out)
{
  int j = blockIdx.x, b = blockIdx.y;
  __shared__ float sD[2048];
  __shared__ float sW[2048];
  int tid = threadIdx.x;
  const float* drow = dc + ((long)b * 256 + j) * 2048;
  for (int i = tid; i < 2048; i += 256) { sD[i] = drow[i]; sW[i] = w[i]; }
  __syncthreads();
  float cb = wb[0];
  int owlo = tid & 15, ohbase = tid >> 4;
#pragma unroll
  for (int q = 0; q < 4; ++q) {
    int oh = ohbase + q * 16;
    int i = oh >> 1, a = oh & 1;
    float acc = cb;
#pragma unroll 8
    for (int e = 0; e < 64; ++e)
      acc += sD[e * 32 + i] * sW[e * 32 + a * 16 + owlo];
    out[((long)b * 64 + oh) * 4096 + j * 16 + owlo] = acc;
  }
}

// ---------------- launcher ----------------
extern "C" void kernel_launch(void* const* d_in, const int* in_sizes, int n_in,
                              void* d_out, int out_size, void* d_ws, size_t ws_size,
                              hipStream_t stream)
{
  const float* x      = (const float*)d_in[0];
  const int*   mask   = (const int*)d_in[1];
  const float* proj_w = (const float*)d_in[2];
  const float* proj_b = (const float*)d_in[3];
  const float* pos    = (const float*)d_in[4];
  const float* Wip    = (const float*)d_in[5];   // (1,2,8192,2048)
  const float* convw  = (const float*)d_in[6];
  const float* convb  = (const float*)d_in[7];
  const float* Wx     = (const float*)d_in[8];   // (1,2,160,4096)
  const float* Wdt    = (const float*)d_in[9];   // (1,2,4096,128)
  const float* bdt    = (const float*)d_in[10];
  const float* Alog   = (const float*)d_in[11];
  const float* Dpv    = (const float*)d_in[12];
  const float* Wout   = (const float*)d_in[13];  // (1,2,2048,4096)
  const float* lng    = (const float*)d_in[14];
  const float* lnb    = (const float*)d_in[15];
  const float* dkw    = (const float*)d_in[16];  // (1,1,31,31)
  const float* ctw    = (const float*)d_in[17];
  const float* ctb    = (const float*)d_in[18];
  float* out = (float*)d_out;

  // workspace layout (bytes)
  char* p = (char*)d_ws;
  u16*   xz_bf   = (u16*)p;            // z-half used; later ob fp32 alias
  float* ob      = (float*)p;
  p += 67108864;
  u16*   u_bf    = (u16*)p;            // later dc alias
  float* dc      = (float*)p;
  p += 33554432;
  u16*   dt_bf   = (u16*)p; p += 67108864;
  float* xdbl    = (float*)p; p += 2621440;
  u16*   xdbl_bf = (u16*)p;  p += 1310720;
  float* h       = (float*)p; p += 16777216;
  u16*   h_bf    = (u16*)p;  p += 8388608;
  float* h2      = (float*)p; p += 16777216;   // also scan dtsum scratch
  u16*   y_bf    = (u16*)p;  p += 33554432;
  u16*   Wpool   = (u16*)p;  p += 67108864;    // Wip_bf; later Wout_bf (1st half)
  u16*   Wx_bf   = (u16*)p;  p += 2621440;
  u16*   Wdt_bf  = (u16*)p;  p += 2097152;
  u16*   tb      = (u16*)p;  p += 65536;       // Toeplitz tiles

  // scratch aliases (temporally disjoint uses of the Wpool 2nd half):
  float* part   = (float*)(Wpool + 16777216);  // x_dbl split-K partials
  float* st_end = (float*)(Wpool + 16777216);  // scan chunk end-states
  float* dtsum  = h2;                          // h2 not written until add_ln

  // weight converts + Toeplitz expansion
  cvt_bf16_k<<<32768, 256, 0, stream>>>(Wip, Wpool, 8388608);
  cvt_bf16_k<<<1280, 256, 0, stream>>>(Wx, Wx_bf, 327680);
  cvt_bf16_k<<<1024, 256, 0, stream>>>(Wdt, Wdt_bf, 262144);
  toeplitz_k<<<124, 256, 0, stream>>>(dkw, tb);

  // 1) patchify + pos embed
  patchify_k<<<dim3(256, 8), 256, 0, stream>>>(x, mask, proj_w, proj_b, pos, h, h_bf);

  // 2) in_proj + fused conv1d/SiLU epilogue (BK=32, 2 blocks/CU)
  gemm256_k<<<dim3(32, 8, 2), 512, 0, stream>>>(
      h_bf, Wpool, (long)8192 * 2048, xz_bf, (long)2048 * 8192,
      convw, convb, u_bf);

  // 3) x_dbl = u @ Wx^T via split-K(4) + reduce (fp32 + bf16 mirror)
  xdbl_part_k<<<dim3(2, 16, 8), 256, 0, stream>>>(u_bf, Wx_bf, part);
  xdbl_reduce_k<<<2560, 256, 0, stream>>>(part, xdbl, xdbl_bf);

  // 4) dt = softplus(x_dbl[:, :128] @ Wdt^T + bdt) -> bf16
  mfma_gemm_k<1, 0, 1><<<dim3(32, 16, 2), 256, 0, stream>>>(
      xdbl_bf, (long)2048 * 160, Wdt_bf, (long)4096 * 128, nullptr, 0L,
      dt_bf, (long)2048 * 4096, bdt, 4096, 4096, 128, 160, 0);

  // 5) chunked selective scan
  scan_a_k<<<2048, 256, 0, stream>>>(dt_bf, u_bf, xdbl, Alog, Dpv, y_bf, st_end, dtsum);
  scan_b_k<<<1024, 512, 0, stream>>>(dt_bf, xz_bf, xdbl, Alog, st_end, dtsum, y_bf);

  // convert Wout into the (now dead) first half of Wpool
  cvt_bf16_k<<<16384, 256, 0, stream>>>(Wout, Wpool, 4194304);

  // 6) out = y @ Wout^T  [ob aliases xz_bf region]
  mfma_gemm_k<0, 1, 0><<<dim3(16, 16, 2), 256, 0, stream>>>(
      y_bf, (long)2048 * 4096, Wpool, (long)2048 * 4096, ob, (long)2048 * 2048,
      nullptr, 0L, nullptr, 0, 2048, 4096, 4096, 0);

  // 7) h2 = LN(h + o_fwd + flip(o_rev))
  add_ln_k<<<2048, 256, 0, stream>>>(h, ob, ob + (long)2048 * 2048, lng, lnb, h2);

  // 8) 31x31 same conv via MFMA Toeplitz -> dc [aliases u_bf region, dead]
  dec_conv31_k<<<dim3(32, 4, 8), 256, 0, stream>>>(h2, tb, dc);

  // 9) fused transposed conv -> rec
  convT_k<<<dim3(256, 8), 256, 0, stream>>>(dc, ctw, ctb, out);

  // 10) second output: x passthrough
  hipMemcpyAsync(out + 2097152, x, (size_t)2097152 * 4,
                 hipMemcpyDeviceToDevice, stream);
}

// Round 16
// 623.938 us; speedup vs baseline: 2.9958x; 2.9958x over previous
//
#include <hip/hip_runtime.h>
#include <hip/hip_bf16.h>
#include <math.h>

typedef unsigned short u16;
typedef __attribute__((ext_vector_type(8))) short bf16x8;
typedef __attribute__((ext_vector_type(4))) float f32x4;

__device__ __forceinline__ float b2f(u16 v) {
  unsigned u = ((unsigned)v) << 16;
  return __builtin_bit_cast(float, u);
}
__device__ __forceinline__ u16 f2b(float f) {
  unsigned u = __builtin_bit_cast(unsigned, f);
  unsigned r = u + 0x7fffu + ((u >> 16) & 1u);
  return (u16)(r >> 16);
}
__device__ __forceinline__ void gload_lds16(const u16* g, u16* l) {
  __builtin_amdgcn_global_load_lds(
      (const __attribute__((address_space(1))) void*)g,
      (__attribute__((address_space(3))) void*)l, 16, 0, 0);
}

// ---------------- fp32 -> bf16 convert ----------------
__global__ __launch_bounds__(256) void cvt_bf16_k(const float* __restrict__ s,
                                                  u16* __restrict__ d, int n4) {
  int i = blockIdx.x * 256 + threadIdx.x;
  if (i < n4) {
    float4 v = ((const float4*)s)[i];
    ushort4 o;
    o.x = f2b(v.x); o.y = f2b(v.y); o.z = f2b(v.z); o.w = f2b(v.w);
    ((ushort4*)d)[i] = o;
  }
}

// ---------------- Toeplitz expansion of 31x31 kernel ----------------
__global__ __launch_bounds__(256) void toeplitz_k(
    const float* __restrict__ kw, u16* __restrict__ tb)
{
  int i = blockIdx.x * 256 + threadIdx.x;
  if (i >= 31744) return;
  int k = i & 31, n = (i >> 5) & 15, h = (i >> 9) & 1, ki = i >> 10;
  int t = h * 32 + k - n;
  float v = (t >= 0 && t <= 30) ? kw[ki * 31 + t] : 0.f;
  tb[i] = f2b(v);
}

// ---------------- patchify + pos embed -> h fp32 + h_bf ----------------
__global__ __launch_bounds__(256) void patchify_k(
    const float* __restrict__ x, const int* __restrict__ mask,
    const float* __restrict__ pw, const float* __restrict__ pb,
    const float* __restrict__ pos, float* __restrict__ h, u16* __restrict__ hb)
{
  int g1 = blockIdx.x, b = blockIdx.y, tid = threadIdx.x;
  __shared__ float sX[64 * 17];
  __shared__ float sW[2048];
  for (int i = tid; i < 64 * 16; i += 256) {
    int r = i >> 4, c = i & 15;
    int gi = (b * 64 + r) * 4096 + g1 * 16 + c;
    sX[r * 17 + c] = mask[gi] ? 0.f : x[gi];
  }
  for (int i = tid; i < 2048; i += 256) sW[i] = pw[i];
  __syncthreads();
  for (int m = tid; m < 2048; m += 256) {
    int e = m >> 5, g0 = m & 31;
    float acc = pb[e];
    const float* w = &sW[e * 32];
#pragma unroll
    for (int kh = 0; kh < 2; ++kh)
#pragma unroll
      for (int kw = 0; kw < 16; ++kw)
        acc += sX[(2 * g0 + kh) * 17 + kw] * w[kh * 16 + kw];
    float v = acc + pos[g1 * 2048 + m];
    long o = ((long)b * 256 + g1) * 2048 + m;
    h[o] = v;
    hb[o] = f2b(v);
  }
}

// ========== 256x256x(BK=64) 8-wave MFMA GEMM for in_proj (R14 proven) =======
__global__ __launch_bounds__(512, 2) void gemm256_k(
    const u16* __restrict__ A0,               // h_bf (2048 x 2048)
    const u16* __restrict__ B0, long bStride, // Wip_bf (8192 x 2048) per dir
    u16* __restrict__ C0, long cStride,       // xz_bf (2048 x 8192) per dir
    const float* __restrict__ cw,             // conv weights (2,4096,4)
    const float* __restrict__ cb,             // conv bias (2,4096)
    u16* __restrict__ ub)                     // u_bf (2,8,256,4096)
{
  constexpr int K = 2048, N = 8192, LDA = 2048;
  __shared__ __align__(16) u16 lds[67584];
  u16* As = lds;
  u16* Bs = lds + 32768;
  const int dir = blockIdx.z;
  const u16* A = A0;
  const u16* B = B0 + (long)dir * bStride;
  u16* C = C0 + (long)dir * cStride;
  const int flip = dir;

  const int tid = threadIdx.x;
  const int wave = tid >> 6, lane = tid & 63;
  const int wr = wave >> 2, wc = wave & 3;
  const int bm = blockIdx.y * 256, bn = blockIdx.x * 256;
  const int lr = lane & 15, lq = lane >> 4;

  f32x4 acc[8][4];
#pragma unroll
  for (int i = 0; i < 8; ++i)
#pragma unroll
    for (int j = 0; j < 4; ++j) acc[i][j] = (f32x4){0.f, 0.f, 0.f, 0.f};

  auto stage = [&](int buf, int kt) {
    int k0 = kt << 6;
#pragma unroll
    for (int hf = 0; hf < 2; ++hf)
#pragma unroll
      for (int j = 0; j < 2; ++j) {
        int g = j * 512 + tid;
        int rl = hf * 128 + (g >> 3);
        int gr = (g & 7) ^ ((g >> 3) & 7);
        int ar = flip ? (bm + 255 - rl) : (bm + rl);
        gload_lds16(A + (long)ar * LDA + k0 + gr * 8,
                    &As[buf * 16384 + hf * 8192 + g * 8]);
        gload_lds16(B + (long)(bn + rl) * K + k0 + gr * 8,
                    &Bs[buf * 16384 + hf * 8192 + g * 8]);
      }
  };

  const int nk = K >> 6;
  stage(0, 0);
  for (int kt = 0; kt < nk; ++kt) {
    __builtin_amdgcn_s_barrier();
    __builtin_amdgcn_sched_barrier(0);
    if (kt + 1 < nk) {
      stage((kt + 1) & 1, kt + 1);
      asm volatile("s_waitcnt vmcnt(16)" ::: "memory");
    } else {
      asm volatile("s_waitcnt vmcnt(0)" ::: "memory");
    }
    __builtin_amdgcn_sched_barrier(0);
    __builtin_amdgcn_s_barrier();
    __builtin_amdgcn_sched_barrier(0);
    const int buf = kt & 1;
#pragma unroll
    for (int h = 0; h < 2; ++h) {
      bf16x8 av[8], bv[4];
#pragma unroll
      for (int i = 0; i < 8; ++i) {
        int row = wr * 128 + i * 16 + lr;
        av[i] = *(const bf16x8*)
            &As[buf * 16384 + ((row * 64 + h * 32 + lq * 8) ^ ((row & 7) << 3))];
      }
#pragma unroll
      for (int j = 0; j < 4; ++j) {
        int row = wc * 64 + j * 16 + lr;
        bv[j] = *(const bf16x8*)
            &Bs[buf * 16384 + ((row * 64 + h * 32 + lq * 8) ^ ((row & 7) << 3))];
      }
      __builtin_amdgcn_s_setprio(1);
#pragma unroll
      for (int i = 0; i < 8; ++i)
#pragma unroll
        for (int j = 0; j < 4; ++j)
          acc[i][j] = __builtin_amdgcn_mfma_f32_16x16x32_bf16(
              av[i], bv[j], acc[i][j], 0, 0, 0);
      __builtin_amdgcn_s_setprio(0);
    }
  }

  if (bn < 4096) {
    __syncthreads();
    u16* tile = lds;                 // [256][264] bf16
#pragma unroll
    for (int i = 0; i < 8; ++i) {
      int r0 = wr * 128 + i * 16 + lq * 4;
#pragma unroll
      for (int j = 0; j < 4; ++j) {
        int col = wc * 64 + j * 16 + lr;
        f32x4 v = acc[i][j];
#pragma unroll
        for (int r = 0; r < 4; ++r)
          tile[(r0 + r) * 264 + col] = f2b(v[r]);
      }
    }
    __syncthreads();
    const int rgrp = tid >> 5, c8 = tid & 31;
    const int d0 = bn + c8 * 8;
    float wv0[8], wv1[8], wv2[8], wv3[8], cbv[8];
#pragma unroll
    for (int e = 0; e < 8; ++e) {
      const float4 wq = *(const float4*)(cw + ((long)dir * 4096 + d0 + e) * 4);
      wv0[e] = wq.x; wv1[e] = wq.y; wv2[e] = wq.z; wv3[e] = wq.w;
      cbv[e] = cb[dir * 4096 + d0 + e];
    }
    const int l0 = rgrp * 16;
    float w0[8], w1[8], w2[8];
#pragma unroll
    for (int e = 0; e < 8; ++e) { w0[e] = 0.f; w1[e] = 0.f; w2[e] = 0.f; }
    if (rgrp > 0) {
      bf16x8 t0 = *(const bf16x8*)&tile[(l0 - 3) * 264 + c8 * 8];
      bf16x8 t1 = *(const bf16x8*)&tile[(l0 - 2) * 264 + c8 * 8];
      bf16x8 t2 = *(const bf16x8*)&tile[(l0 - 1) * 264 + c8 * 8];
#pragma unroll
      for (int e = 0; e < 8; ++e) {
        w0[e] = b2f((u16)t0[e]); w1[e] = b2f((u16)t1[e]); w2[e] = b2f((u16)t2[e]);
      }
    }
    long ubase = ((long)(dir * 8 + blockIdx.y) * 256 + l0) * 4096 + d0;
#pragma unroll
    for (int l = 0; l < 16; ++l) {
      bf16x8 t = *(const bf16x8*)&tile[(l0 + l) * 264 + c8 * 8];
      float cur[8];
#pragma unroll
      for (int e = 0; e < 8; ++e) cur[e] = b2f((u16)t[e]);
      bf16x8 ov;
#pragma unroll
      for (int e = 0; e < 8; ++e) {
        float a = cbv[e] + wv0[e] * w0[e] + wv1[e] * w1[e] + wv2[e] * w2[e] +
                  wv3[e] * cur[e];
        ov[e] = (short)f2b(a / (1.f + __expf(-a)));
      }
      *(bf16x8*)(ub + ubase + (long)l * 4096) = ov;
#pragma unroll
      for (int e = 0; e < 8; ++e) { w0[e] = w1[e]; w1[e] = w2[e]; w2[e] = cur[e]; }
    }
  } else {
#pragma unroll
    for (int i = 0; i < 8; ++i) {
      int r0 = bm + wr * 128 + i * 16 + lq * 4;
#pragma unroll
      for (int j = 0; j < 4; ++j) {
        int col = bn + wc * 64 + j * 16 + lr;
        f32x4 v = acc[i][j];
#pragma unroll
        for (int r = 0; r < 4; ++r)
          C[(long)(r0 + r) * N + col] = f2b(v[r]);
      }
    }
  }
}

// ========== out_proj: 256^2 coarse structure, split-K=2, fp32 partials ======
// grid (8, 8, 4): z = dir*2 + split. part[z] = y[dir][:, splitK] @ Wout^T.
__global__ __launch_bounds__(512, 2) void gemm256o_k(
    const u16* __restrict__ Y0,               // y_bf (2, 2048, 4096)
    const u16* __restrict__ W0,               // Wout_bf (2, 2048, 4096)
    float* __restrict__ part)                 // (4, 2048, 2048) fp32
{
  constexpr int LDK = 4096;
  __shared__ __align__(16) u16 lds[65536];
  u16* As = lds;
  u16* Bs = lds + 32768;
  const int dir = blockIdx.z >> 1, split = blockIdx.z & 1;
  const u16* A = Y0 + (long)dir * 2048 * 4096;
  const u16* B = W0 + (long)dir * 2048 * 4096;
  float* C = part + (long)blockIdx.z * 4194304;
  const int kbase = split << 11;              // 0 or 2048

  const int tid = threadIdx.x;
  const int wave = tid >> 6, lane = tid & 63;
  const int wr = wave >> 2, wc = wave & 3;
  const int bm = blockIdx.y * 256, bn = blockIdx.x * 256;
  const int lr = lane & 15, lq = lane >> 4;

  f32x4 acc[8][4];
#pragma unroll
  for (int i = 0; i < 8; ++i)
#pragma unroll
    for (int j = 0; j < 4; ++j) acc[i][j] = (f32x4){0.f, 0.f, 0.f, 0.f};

  auto stage = [&](int buf, int kt) {
    int k0 = kbase + (kt << 6);
#pragma unroll
    for (int hf = 0; hf < 2; ++hf)
#pragma unroll
      for (int j = 0; j < 2; ++j) {
        int g = j * 512 + tid;
        int rl = hf * 128 + (g >> 3);
        int gr = (g & 7) ^ ((g >> 3) & 7);
        gload_lds16(A + (long)(bm + rl) * LDK + k0 + gr * 8,
                    &As[buf * 16384 + hf * 8192 + g * 8]);
        gload_lds16(B + (long)(bn + rl) * LDK + k0 + gr * 8,
                    &Bs[buf * 16384 + hf * 8192 + g * 8]);
      }
  };

  const int nk = 32;                          // 2048 / 64
  stage(0, 0);
  for (int kt = 0; kt < nk; ++kt) {
    __builtin_amdgcn_s_barrier();
    __builtin_amdgcn_sched_barrier(0);
    if (kt + 1 < nk) {
      stage((kt + 1) & 1, kt + 1);
      asm volatile("s_waitcnt vmcnt(16)" ::: "memory");
    } else {
      asm volatile("s_waitcnt vmcnt(0)" ::: "memory");
    }
    __builtin_amdgcn_sched_barrier(0);
    __builtin_amdgcn_s_barrier();
    __builtin_amdgcn_sched_barrier(0);
    const int buf = kt & 1;
#pragma unroll
    for (int h = 0; h < 2; ++h) {
      bf16x8 av[8], bv[4];
#pragma unroll
      for (int i = 0; i < 8; ++i) {
        int row = wr * 128 + i * 16 + lr;
        av[i] = *(const bf16x8*)
            &As[buf * 16384 + ((row * 64 + h * 32 + lq * 8) ^ ((row & 7) << 3))];
      }
#pragma unroll
      for (int j = 0; j < 4; ++j) {
        int row = wc * 64 + j * 16 + lr;
        bv[j] = *(const bf16x8*)
            &Bs[buf * 16384 + ((row * 64 + h * 32 + lq * 8) ^ ((row & 7) << 3))];
      }
      __builtin_amdgcn_s_setprio(1);
#pragma unroll
      for (int i = 0; i < 8; ++i)
#pragma unroll
        for (int j = 0; j < 4; ++j)
          acc[i][j] = __builtin_amdgcn_mfma_f32_16x16x32_bf16(
              av[i], bv[j], acc[i][j], 0, 0, 0);
      __builtin_amdgcn_s_setprio(0);
    }
  }

#pragma unroll
  for (int i = 0; i < 8; ++i) {
    int r0 = bm + wr * 128 + i * 16 + lq * 4;
#pragma unroll
    for (int j = 0; j < 4; ++j) {
      int col = bn + wc * 64 + j * 16 + lr;
      f32x4 v = acc[i][j];
#pragma unroll
      for (int r = 0; r < 4; ++r)
        C[(long)(r0 + r) * 2048 + col] = v[r];
    }
  }
}

// ---------------- out_proj split-K reduce: ob = part[2d] + part[2d+1] -------
__global__ __launch_bounds__(256) void oproj_reduce_k(
    const float* __restrict__ part, float* __restrict__ ob)
{
  int i = blockIdx.x * 256 + threadIdx.x;   // over 2*1048576 float4
  if (i >= 2097152) return;
  int dir = i >> 20, rem = i & 1048575;
  const float4* p0 = (const float4*)(part + (long)(dir * 2) * 4194304) + rem;
  const float4* p1 = (const float4*)(part + (long)(dir * 2 + 1) * 4194304) + rem;
  float4 a = *p0, b = *p1;
  ((float4*)(ob + (long)dir * 4194304))[rem] =
      make_float4(a.x + b.x, a.y + b.y, a.z + b.z, a.w + b.w);
}

// ---------------- bf16 MFMA GEMM (128x128, m97 structure) ----------------
template <int EPI, int F32OUT, int BFOUT>
__global__ __launch_bounds__(256) void mfma_gemm_k(
    const u16* __restrict__ A0, long aStride,
    const u16* __restrict__ B0, long bStride,
    float* __restrict__ C0, long cStride,
    u16* __restrict__ Cb0, long cbStride,
    const float* __restrict__ bias0, int biasStride,
    int N, int K, int lda, int flipDir1)
{
  __shared__ __align__(16) u16 As[2][4096];
  __shared__ __align__(16) u16 Bs[2][4096];
  const int dir = blockIdx.z;
  const u16* A = A0 + (long)dir * aStride;
  const u16* B = B0 + (long)dir * bStride;
  float* C = F32OUT ? (C0 + (long)dir * cStride) : nullptr;
  u16* Cb = BFOUT ? (Cb0 + (long)dir * cbStride) : nullptr;
  const float* bias = (EPI == 1) ? (bias0 + (long)dir * biasStride) : nullptr;
  const int flip = flipDir1 && (dir == 1);

  const int tid = threadIdx.x;
  const int wave = tid >> 6, lane = tid & 63;
  const int wr = wave >> 1, wc = wave & 1;
  const int bm = blockIdx.y * 128, bn = blockIdx.x * 128;
  const int lr = lane & 15, lq = lane >> 4;

  f32x4 acc[4][4];
#pragma unroll
  for (int i = 0; i < 4; ++i)
#pragma unroll
    for (int j = 0; j < 4; ++j) acc[i][j] = (f32x4){0.f, 0.f, 0.f, 0.f};

  const int nk = K >> 5;

  auto stage = [&](int buf, int k0) {
#pragma unroll
    for (int iss = 0; iss < 2; ++iss) {
      int ob = wave * 2048 + iss * 1024 + lane * 16;
      int row = ob >> 6, kb = (ob >> 4) & 3;
      int rg = bm + row;
      rg = flip ? ((rg & ~255) | (255 - (rg & 255))) : rg;
      gload_lds16(A + (long)rg * lda + k0 + kb * 8,
                  &As[buf][wave * 1024 + iss * 512]);
      int rb = bn + row; rb = (rb < N) ? rb : (N - 1);
      gload_lds16(B + (long)rb * K + k0 + kb * 8,
                  &Bs[buf][wave * 1024 + iss * 512]);
    }
  };

  stage(0, 0);
  for (int kt = 0; kt < nk; ++kt) {
    __syncthreads();
    if (kt + 1 < nk) stage((kt + 1) & 1, (kt + 1) << 5);
    const int buf = kt & 1;
    bf16x8 av[4], bv[4];
#pragma unroll
    for (int i = 0; i < 4; ++i)
      av[i] = *(const bf16x8*)&As[buf][(wr * 64 + i * 16 + lr) * 32 + lq * 8];
#pragma unroll
    for (int j = 0; j < 4; ++j)
      bv[j] = *(const bf16x8*)&Bs[buf][(wc * 64 + j * 16 + lr) * 32 + lq * 8];
#pragma unroll
    for (int i = 0; i < 4; ++i)
#pragma unroll
      for (int j = 0; j < 4; ++j)
        acc[i][j] = __builtin_amdgcn_mfma_f32_16x16x32_bf16(av[i], bv[j],
                                                            acc[i][j], 0, 0, 0);
  }

#pragma unroll
  for (int i = 0; i < 4; ++i) {
    int r0 = bm + wr * 64 + i * 16 + lq * 4;
#pragma unroll
    for (int j = 0; j < 4; ++j) {
      int col = bn + wc * 64 + j * 16 + lr;
      if (col < N) {
        f32x4 v = acc[i][j];
#pragma unroll
        for (int r = 0; r < 4; ++r) {
          float xv = v[r];
          if (EPI == 1) {
            xv += bias[col];
            xv = (xv > 20.f) ? xv : log1pf(expf(xv));
          }
          if (F32OUT) C[(long)(r0 + r) * N + col] = xv;
          if (BFOUT) Cb[(long)(r0 + r) * N + col] = f2b(xv);
        }
      }
    }
  }
}

// ---------------- x_dbl split-K partial GEMM ----------------
__global__ __launch_bounds__(256) void xdbl_part_k(
    const u16* __restrict__ ubf, const u16* __restrict__ Wxbf,
    float* __restrict__ part)
{
  __shared__ __align__(16) u16 As[2][4096];
  __shared__ __align__(16) u16 Bs[2][4096];
  const int dir = blockIdx.z >> 2, split = blockIdx.z & 3;
  const u16* A = ubf + (long)dir * 2048 * 4096;
  const u16* B = Wxbf + (long)dir * 160 * 4096;
  float* C = part + (long)blockIdx.z * 327680;
  const int tid = threadIdx.x;
  const int wave = tid >> 6, lane = tid & 63;
  const int wr = wave >> 1, wc = wave & 1;
  const int bm = blockIdx.y * 128, bn = blockIdx.x * 128;
  const int lr = lane & 15, lq = lane >> 4;

  f32x4 acc[4][4];
#pragma unroll
  for (int i = 0; i < 4; ++i)
#pragma unroll
    for (int j = 0; j < 4; ++j) acc[i][j] = (f32x4){0.f, 0.f, 0.f, 0.f};

  auto stage = [&](int buf, int k0) {
#pragma unroll
    for (int iss = 0; iss < 2; ++iss) {
      int ob = wave * 2048 + iss * 1024 + lane * 16;
      int row = ob >> 6, kb = (ob >> 4) & 3;
      gload_lds16(A + (long)(bm + row) * 4096 + k0 + kb * 8,
                  &As[buf][wave * 1024 + iss * 512]);
      int rb = bn + row; rb = (rb < 160) ? rb : 159;
      gload_lds16(B + (long)rb * 4096 + k0 + kb * 8,
                  &Bs[buf][wave * 1024 + iss * 512]);
    }
  };

  const int kbase = split << 10;
  stage(0, kbase);
  for (int kt = 0; kt < 32; ++kt) {
    __syncthreads();
    if (kt + 1 < 32) stage((kt + 1) & 1, kbase + ((kt + 1) << 5));
    const int buf = kt & 1;
    bf16x8 av[4], bv[4];
#pragma unroll
    for (int i = 0; i < 4; ++i)
      av[i] = *(const bf16x8*)&As[buf][(wr * 64 + i * 16 + lr) * 32 + lq * 8];
#pragma unroll
    for (int j = 0; j < 4; ++j)
      bv[j] = *(const bf16x8*)&Bs[buf][(wc * 64 + j * 16 + lr) * 32 + lq * 8];
#pragma unroll
    for (int i = 0; i < 4; ++i)
#pragma unroll
      for (int j = 0; j < 4; ++j)
        acc[i][j] = __builtin_amdgcn_mfma_f32_16x16x32_bf16(av[i], bv[j],
                                                            acc[i][j], 0, 0, 0);
  }

#pragma unroll
  for (int i = 0; i < 4; ++i) {
    int r0 = bm + wr * 64 + i * 16 + lq * 4;
#pragma unroll
    for (int j = 0; j < 4; ++j) {
      int col = bn + wc * 64 + j * 16 + lr;
      if (col < 160) {
        f32x4 v = acc[i][j];
#pragma unroll
        for (int r = 0; r < 4; ++r)
          C[(long)(r0 + r) * 160 + col] = v[r];
      }
    }
  }
}

// ---------------- x_dbl split-K reduce -> fp32 + bf16 ----------------
__global__ __launch_bounds__(256) void xdbl_reduce_k(
    const float* __restrict__ part, float* __restrict__ xdbl,
    u16* __restrict__ xdbl_bf)
{
  int i = blockIdx.x * 256 + threadIdx.x;
  if (i >= 655360) return;
  int dir = i / 327680, rem = i - dir * 327680;
  long pb = (long)dir * 4 * 327680 + rem;
  float s = part[pb] + part[pb + 327680] + part[pb + 2 * 327680] +
            part[pb + 3 * 327680];
  xdbl[i] = s;
  xdbl_bf[i] = f2b(s);
}

// ---------------- scan pass A: per-chunk local scan (zero init) --------------
__global__ __launch_bounds__(256) void scan_a_k(
    const u16* __restrict__ dtbuf, const u16* __restrict__ ubuf,
    const float* __restrict__ xdbl, const float* __restrict__ A_log,
    const float* __restrict__ Dpv, u16* __restrict__ ypre,
    float* __restrict__ stend, float* __restrict__ dtsum)
{
  int blk = blockIdx.x;
  int dtile = blk & 15, c = (blk >> 4) & 7, b = (blk >> 7) & 7, dir = blk >> 10;
  int tid = threadIdx.x;
  int d = dtile * 256 + tid;
  int db = dir * 8 + b;

  __shared__ float sB[32][16], sC[32][16];
  long r160 = (long)db * 256 * 160;
  for (int i = tid; i < 1024; i += 256) {
    int l = i >> 5, s = i & 31;
    float v = xdbl[r160 + (long)(c * 32 + l) * 160 + 128 + s];
    if (s < 16) sB[l][s] = v; else sC[l][s - 16] = v;
  }
  __syncthreads();

  float A[16], st[16];
  const float4* ap = (const float4*)(A_log + ((long)dir * 4096 + d) * 16);
#pragma unroll
  for (int q = 0; q < 4; ++q) {
    float4 t = ap[q];
    A[q * 4 + 0] = -__expf(t.x); A[q * 4 + 1] = -__expf(t.y);
    A[q * 4 + 2] = -__expf(t.z); A[q * 4 + 3] = -__expf(t.w);
  }
#pragma unroll
  for (int s = 0; s < 16; ++s) st[s] = 0.f;
  float Dpd = Dpv[dir * 4096 + d];

  long base = (long)db * 256 * 4096 + (long)c * 32 * 4096 + d;
  float dts = 0.f;
  for (int i = 0; i < 32; ++i) {
    float dtv = b2f(dtbuf[base + (long)i * 4096]);
    float uv  = b2f(ubuf[base + (long)i * 4096]);
    dts += dtv;
    float du = dtv * uv;
    float y = 0.f;
#pragma unroll
    for (int s = 0; s < 16; ++s) {
      st[s] = st[s] * __expf(dtv * A[s]) + du * sB[i][s];
      y += st[s] * sC[i][s];
    }
    ypre[base + (long)i * 4096] = f2b(y + uv * Dpd);
  }
  long eb = ((long)(db * 8 + c) * 4096 + d) * 16;
  float4* ep = (float4*)(stend + eb);
#pragma unroll
  for (int q = 0; q < 4; ++q)
    ep[q] = make_float4(st[q * 4], st[q * 4 + 1], st[q * 4 + 2], st[q * 4 + 3]);
  dtsum[(long)(db * 8 + c) * 4096 + d] = dts;
}

// ---------------- scan pass B: chunk combine + correction + gating -----------
__global__ __launch_bounds__(512) void scan_b_k(
    const u16* __restrict__ dtbuf, const u16* __restrict__ xzbf,
    const float* __restrict__ xdbl, const float* __restrict__ A_log,
    const float* __restrict__ stend, const float* __restrict__ dtsum,
    u16* __restrict__ ybuf)
{
  int blk = blockIdx.x;
  int dtile = blk & 63, b = (blk >> 6) & 7, dir = blk >> 9;
  int tid = threadIdx.x;
  int c = tid >> 6, dd = tid & 63;
  int d0 = dtile * 64, d = d0 + dd;
  int db = dir * 8 + b;

  __shared__ float sEnd[8][64][17];
  __shared__ float sT[8][64];
  __shared__ float sC[256][16];

  long eBase = (long)db * 8 * 65536;
  for (int i = tid; i < 8192; i += 512) {
    int cc = i >> 10, rem = i & 1023, dd2 = rem >> 4, s = rem & 15;
    sEnd[cc][dd2][s] = stend[eBase + (long)cc * 65536 + (long)(d0 + dd2) * 16 + s];
  }
  {
    int cc = tid >> 6, dd2 = tid & 63;
    sT[cc][dd2] = dtsum[(long)(db * 8 + cc) * 4096 + d0 + dd2];
  }
  long r160 = (long)db * 256 * 160;
  for (int i = tid; i < 4096; i += 512) {
    int l = i >> 4, s = i & 15;
    sC[l][s] = xdbl[r160 + (long)l * 160 + 144 + s];
  }
  __syncthreads();

  float A[16];
  const float4* ap = (const float4*)(A_log + ((long)dir * 4096 + d) * 16);
#pragma unroll
  for (int q = 0; q < 4; ++q) {
    float4 t = ap[q];
    A[q * 4 + 0] = -__expf(t.x); A[q * 4 + 1] = -__expf(t.y);
    A[q * 4 + 2] = -__expf(t.z); A[q * 4 + 3] = -__expf(t.w);
  }
  float g[16];
#pragma unroll
  for (int s = 0; s < 16; ++s) g[s] = 0.f;
  for (int j = 0; j < c; ++j) {
    float Tj = sT[j][dd];
#pragma unroll
    for (int s = 0; s < 16; ++s)
      g[s] = g[s] * __expf(A[s] * Tj) + sEnd[j][dd][s];
  }

  long base  = (long)db * 256 * 4096 + (long)c * 32 * 4096 + d;
  long zbase = (long)db * 256 * 8192 + (long)c * 32 * 8192 + 4096 + d;
  float cum = 0.f;
  if (c == 0) {
    for (int i = 0; i < 32; ++i) {
      float yp = b2f(ybuf[base + (long)i * 4096]);
      float zv = b2f(xzbf[zbase + (long)i * 8192]);
      float y = yp * (zv / (1.f + __expf(-zv)));
      ybuf[base + (long)i * 4096] = f2b(y);
    }
  } else {
    for (int i = 0; i < 32; ++i) {
      float dtv = b2f(dtbuf[base + (long)i * 4096]);
      cum += dtv;
      float yp = b2f(ybuf[base + (long)i * 4096]);
      float corr = 0.f;
      const int l = c * 32 + i;
#pragma unroll
      for (int s = 0; s < 16; ++s)
        corr += sC[l][s] * __expf(A[s] * cum) * g[s];
      float zv = b2f(xzbf[zbase + (long)i * 8192]);
      float y = (yp + corr) * (zv / (1.f + __expf(-zv)));
      ybuf[base + (long)i * 4096] = f2b(y);
    }
  }
}

// ---------------- residual add (fwd + flipped rev) + LayerNorm ----------------
__global__ __launch_bounds__(256) void add_ln_k(
    const float* __restrict__ h, const float* __restrict__ o0,
    const float* __restrict__ o1, const float* __restrict__ g,
    const float* __restrict__ bta, float* __restrict__ h2)
{
  int row = blockIdx.x;
  int b = row >> 8, l = row & 255;
  long base = (long)row * 2048;
  long base1 = ((long)b * 256 + (255 - l)) * 2048;
  int t8 = threadIdx.x * 8;
  float v[8];
  float4 x0 = *(const float4*)(h + base + t8);
  float4 x1 = *(const float4*)(h + base + t8 + 4);
  float4 a0 = *(const float4*)(o0 + base + t8);
  float4 a1 = *(const float4*)(o0 + base + t8 + 4);
  float4 c0 = *(const float4*)(o1 + base1 + t8);
  float4 c1 = *(const float4*)(o1 + base1 + t8 + 4);
  v[0] = x0.x + a0.x + c0.x; v[1] = x0.y + a0.y + c0.y;
  v[2] = x0.z + a0.z + c0.z; v[3] = x0.w + a0.w + c0.w;
  v[4] = x1.x + a1.x + c1.x; v[5] = x1.y + a1.y + c1.y;
  v[6] = x1.z + a1.z + c1.z; v[7] = x1.w + a1.w + c1.w;
  float s = 0.f, ss = 0.f;
#pragma unroll
  for (int j = 0; j < 8; ++j) { s += v[j]; ss += v[j] * v[j]; }
#pragma unroll
  for (int off = 32; off >= 1; off >>= 1) {
    s += __shfl_xor(s, off, 64);
    ss += __shfl_xor(ss, off, 64);
  }
  __shared__ float red[8];
  int wid = threadIdx.x >> 6, lane = threadIdx.x & 63;
  if (lane == 0) { red[wid] = s; red[wid + 4] = ss; }
  __syncthreads();
  if (threadIdx.x == 0) {
    red[0] = red[0] + red[1] + red[2] + red[3];
    red[4] = red[4] + red[5] + red[6] + red[7];
  }
  __syncthreads();
  float mean = red[0] * (1.f / 2048.f);
  float var = red[4] * (1.f / 2048.f) - mean * mean;
  float inv = rsqrtf(var + 1e-5f);
  float o[8];
#pragma unroll
  for (int j = 0; j < 8; ++j)
    o[j] = (v[j] - mean) * inv * g[t8 + j] + bta[t8 + j];
  *(float4*)(h2 + base + t8) = make_float4(o[0], o[1], o[2], o[3]);
  *(float4*)(h2 + base + t8 + 4) = make_float4(o[4], o[5], o[6], o[7]);
}

// ---------------- 31x31 "same" conv via MFMA Toeplitz ----------------
__global__ __launch_bounds__(256) void dec_conv31_k(
    const float* __restrict__ h2, const u16* __restrict__ tb,
    float* __restrict__ dc)
{
  __shared__ __align__(16) u16 sIn[94 * 120];
  const int b = blockIdx.z;
  const int l0 = blockIdx.y * 64;
  const int m0 = blockIdx.x * 64;
  const int tid = threadIdx.x;
  const float* src = h2 + (long)b * 256 * 2048;
  for (int i = tid; i < 94 * 112; i += 256) {
    int r = i / 112, c = i - r * 112;
    int gl = l0 + r - 15, gm = m0 + c - 15;
    float v = 0.f;
    if (gl >= 0 && gl < 256 && gm >= 0 && gm < 2048)
      v = src[(long)gl * 2048 + gm];
    sIn[r * 120 + c] = f2b(v);
  }
  __syncthreads();
  const int wave = tid >> 6, lane = tid & 63;
  const int lr = lane & 15, lq = lane >> 4;

  f32x4 acc[4];
#pragma unroll
  for (int s = 0; s < 4; ++s) acc[s] = (f32x4){0.f, 0.f, 0.f, 0.f};

#pragma unroll 1
  for (int ki = 0; ki < 31; ++ki) {
    const u16* arow = &sIn[(wave * 16 + lr + ki) * 120];
#pragma unroll
    for (int h = 0; h < 2; ++h) {
      bf16x8 bv = *(const bf16x8*)&tb[((ki * 2 + h) * 16 + lr) * 32 + lq * 8];
#pragma unroll
      for (int ms = 0; ms < 4; ++ms) {
        bf16x8 av = *(const bf16x8*)&arow[ms * 16 + h * 32 + lq * 8];
        acc[ms] = __builtin_amdgcn_mfma_f32_16x16x32_bf16(av, bv, acc[ms], 0, 0, 0);
      }
    }
  }
#pragma unroll
  for (int ms = 0; ms < 4; ++ms) {
    f32x4 v = acc[ms];
#pragma unroll
    for (int r = 0; r < 4; ++r)
      dc[((long)b * 256 + l0 + wave * 16 + lq * 4 + r) * 2048 + m0 + ms * 16 + lr]
          = v[r];
  }
}

// ---------------- fused transposed conv (stride 2x16) ----------------
__global__ __launch_bounds__(256) void convT_k(
    const float* __restrict__ dc, const float* __restrict__ w,
    const float* __restrict__ wb, float* __restrict__ out)
{
  int j = blockIdx.x, b = blockIdx.y;
  __shared__ float sD[2048];
  __shared__ float sW[2048];
  int tid = threadIdx.x;
  const float* drow = dc + ((long)b * 256 + j) * 2048;
  for (int i = tid; i < 2048; i += 256) { sD[i] = drow[i]; sW[i] = w[i]; }
  __syncthreads();
  float cb = wb[0];
  int owlo = tid & 15, ohbase = tid >> 4;
#pragma unroll
  for (int q = 0; q < 4; ++q) {
    int oh = ohbase + q * 16;
    int i = oh >> 1, a = oh & 1;
    float acc = cb;
#pragma unroll 8
    for (int e = 0; e < 64; ++e)
      acc += sD[e * 32 + i] * sW[e * 32 + a * 16 + owlo];
    out[((long)b * 64 + oh) * 4096 + j * 16 + owlo] = acc;
  }
}

// ---------------- launcher ----------------
extern "C" void kernel_launch(void* const* d_in, const int* in_sizes, int n_in,
                              void* d_out, int out_size, void* d_ws, size_t ws_size,
                              hipStream_t stream)
{
  const float* x      = (const float*)d_in[0];
  const int*   mask   = (const int*)d_in[1];
  const float* proj_w = (const float*)d_in[2];
  const float* proj_b = (const float*)d_in[3];
  const float* pos    = (const float*)d_in[4];
  const float* Wip    = (const float*)d_in[5];   // (1,2,8192,2048)
  const float* convw  = (const float*)d_in[6];
  const float* convb  = (const float*)d_in[7];
  const float* Wx     = (const float*)d_in[8];   // (1,2,160,4096)
  const float* Wdt    = (const float*)d_in[9];   // (1,2,4096,128)
  const float* bdt    = (const float*)d_in[10];
  const float* Alog   = (const float*)d_in[11];
  const float* Dpv    = (const float*)d_in[12];
  const float* Wout   = (const float*)d_in[13];  // (1,2,2048,4096)
  const float* lng    = (const float*)d_in[14];
  const float* lnb    = (const float*)d_in[15];
  const float* dkw    = (const float*)d_in[16];  // (1,1,31,31)
  const float* ctw    = (const float*)d_in[17];
  const float* ctb    = (const float*)d_in[18];
  float* out = (float*)d_out;

  // workspace layout (bytes)
  char* p = (char*)d_ws;
  u16*   xz_bf   = (u16*)p;            // z-half used; later ob fp32 alias
  float* ob      = (float*)p;
  p += 67108864;
  u16*   u_bf    = (u16*)p;            // later dc alias
  float* dc      = (float*)p;
  p += 33554432;
  u16*   dt_bf   = (u16*)p; p += 67108864;     // also out_proj partials later
  float* xdbl    = (float*)p; p += 2621440;
  u16*   xdbl_bf = (u16*)p;  p += 1310720;
  float* h       = (float*)p; p += 16777216;
  u16*   h_bf    = (u16*)p;  p += 8388608;
  float* h2      = (float*)p; p += 16777216;   // also scan dtsum scratch
  u16*   y_bf    = (u16*)p;  p += 33554432;
  u16*   Wpool   = (u16*)p;  p += 67108864;    // Wip_bf; later Wout_bf (1st half)
  u16*   Wx_bf   = (u16*)p;  p += 2621440;
  u16*   Wdt_bf  = (u16*)p;  p += 2097152;
  u16*   tb      = (u16*)p;  p += 65536;       // Toeplitz tiles

  // scratch aliases (temporally disjoint):
  float* part    = (float*)(Wpool + 16777216); // x_dbl split-K partials
  float* st_end  = (float*)(Wpool + 16777216); // scan chunk end-states
  float* dtsum   = h2;                         // h2 not written until add_ln
  float* opart   = (float*)dt_bf;              // out_proj partials (dt dead)

  // weight converts + Toeplitz expansion
  cvt_bf16_k<<<32768, 256, 0, stream>>>(Wip, Wpool, 8388608);
  cvt_bf16_k<<<1280, 256, 0, stream>>>(Wx, Wx_bf, 327680);
  cvt_bf16_k<<<1024, 256, 0, stream>>>(Wdt, Wdt_bf, 262144);
  toeplitz_k<<<124, 256, 0, stream>>>(dkw, tb);

  // 1) patchify + pos embed
  patchify_k<<<dim3(256, 8), 256, 0, stream>>>(x, mask, proj_w, proj_b, pos, h, h_bf);

  // 2) in_proj + fused conv1d/SiLU epilogue (R14 proven)
  gemm256_k<<<dim3(32, 8, 2), 512, 0, stream>>>(
      h_bf, Wpool, (long)8192 * 2048, xz_bf, (long)2048 * 8192,
      convw, convb, u_bf);

  // 3) x_dbl = u @ Wx^T via split-K(4) + reduce (fp32 + bf16 mirror)
  xdbl_part_k<<<dim3(2, 16, 8), 256, 0, stream>>>(u_bf, Wx_bf, part);
  xdbl_reduce_k<<<2560, 256, 0, stream>>>(part, xdbl, xdbl_bf);

  // 4) dt = softplus(x_dbl[:, :128] @ Wdt^T + bdt) -> bf16
  mfma_gemm_k<1, 0, 1><<<dim3(32, 16, 2), 256, 0, stream>>>(
      xdbl_bf, (long)2048 * 160, Wdt_bf, (long)4096 * 128, nullptr, 0L,
      dt_bf, (long)2048 * 4096, bdt, 4096, 4096, 128, 160, 0);

  // 5) chunked selective scan
  scan_a_k<<<2048, 256, 0, stream>>>(dt_bf, u_bf, xdbl, Alog, Dpv, y_bf, st_end, dtsum);
  scan_b_k<<<1024, 512, 0, stream>>>(dt_bf, xz_bf, xdbl, Alog, st_end, dtsum, y_bf);

  // convert Wout into the (now dead) first half of Wpool
  cvt_bf16_k<<<16384, 256, 0, stream>>>(Wout, Wpool, 4194304);

  // 6) out_proj via 256^2 coarse split-K(2): partials into dead dt region
  gemm256o_k<<<dim3(8, 8, 4), 512, 0, stream>>>(y_bf, Wpool, opart);
  oproj_reduce_k<<<8192, 256, 0, stream>>>(opart, ob);

  // 7) h2 = LN(h + o_fwd + flip(o_rev))
  add_ln_k<<<2048, 256, 0, stream>>>(h, ob, ob + (long)2048 * 2048, lng, lnb, h2);

  // 8) 31x31 same conv via MFMA Toeplitz -> dc [aliases u_bf region, dead]
  dec_conv31_k<<<dim3(32, 4, 8), 256, 0, stream>>>(h2, tb, dc);

  // 9) fused transposed conv -> rec
  convT_k<<<dim3(256, 8), 256, 0, stream>>>(dc, ctw, ctb, out);

  // 10) second output: x passthrough
  hipMemcpyAsync(out + 2097152, x, (size_t)2097152 * 4,
                 hipMemcpyDeviceToDevice, stream);
}

// Round 17
// 616.554 us; speedup vs baseline: 3.0317x; 1.0120x over previous
//
#include <hip/hip_runtime.h>
#include <hip/hip_bf16.h>
#include <math.h>

typedef unsigned short u16;
typedef __attribute__((ext_vector_type(8))) short bf16x8;
typedef __attribute__((ext_vector_type(4))) float f32x4;

__device__ __forceinline__ float b2f(u16 v) {
  unsigned u = ((unsigned)v) << 16;
  return __builtin_bit_cast(float, u);
}
__device__ __forceinline__ u16 f2b(float f) {
  unsigned u = __builtin_bit_cast(unsigned, f);
  unsigned r = u + 0x7fffu + ((u >> 16) & 1u);
  return (u16)(r >> 16);
}
__device__ __forceinline__ void gload_lds16(const u16* g, u16* l) {
  __builtin_amdgcn_global_load_lds(
      (const __attribute__((address_space(1))) void*)g,
      (__attribute__((address_space(3))) void*)l, 16, 0, 0);
}

// ---------------- fp32 -> bf16 convert ----------------
__global__ __launch_bounds__(256) void cvt_bf16_k(const float* __restrict__ s,
                                                  u16* __restrict__ d, int n4) {
  int i = blockIdx.x * 256 + threadIdx.x;
  if (i < n4) {
    float4 v = ((const float4*)s)[i];
    ushort4 o;
    o.x = f2b(v.x); o.y = f2b(v.y); o.z = f2b(v.z); o.w = f2b(v.w);
    ((ushort4*)d)[i] = o;
  }
}

// ---------------- Toeplitz expansion of 31x31 kernel ----------------
__global__ __launch_bounds__(256) void toeplitz_k(
    const float* __restrict__ kw, u16* __restrict__ tb)
{
  int i = blockIdx.x * 256 + threadIdx.x;
  if (i >= 31744) return;
  int k = i & 31, n = (i >> 5) & 15, h = (i >> 9) & 1, ki = i >> 10;
  int t = h * 32 + k - n;
  float v = (t >= 0 && t <= 30) ? kw[ki * 31 + t] : 0.f;
  tb[i] = f2b(v);
}

// ---------------- patchify + pos embed -> h fp32 + h_bf ----------------
__global__ __launch_bounds__(256) void patchify_k(
    const float* __restrict__ x, const int* __restrict__ mask,
    const float* __restrict__ pw, const float* __restrict__ pb,
    const float* __restrict__ pos, float* __restrict__ h, u16* __restrict__ hb)
{
  int g1 = blockIdx.x, b = blockIdx.y, tid = threadIdx.x;
  __shared__ float sX[64 * 17];
  __shared__ float sW[2048];
  for (int i = tid; i < 64 * 16; i += 256) {
    int r = i >> 4, c = i & 15;
    int gi = (b * 64 + r) * 4096 + g1 * 16 + c;
    sX[r * 17 + c] = mask[gi] ? 0.f : x[gi];
  }
  for (int i = tid; i < 2048; i += 256) sW[i] = pw[i];
  __syncthreads();
  for (int m = tid; m < 2048; m += 256) {
    int e = m >> 5, g0 = m & 31;
    float acc = pb[e];
    const float* w = &sW[e * 32];
#pragma unroll
    for (int kh = 0; kh < 2; ++kh)
#pragma unroll
      for (int kw = 0; kw < 16; ++kw)
        acc += sX[(2 * g0 + kh) * 17 + kw] * w[kh * 16 + kw];
    float v = acc + pos[g1 * 2048 + m];
    long o = ((long)b * 256 + g1) * 2048 + m;
    h[o] = v;
    hb[o] = f2b(v);
  }
}

// ========== 256x256x(BK=32) 8-wave MFMA GEMM for in_proj ====================
// BK=32 + split conv epilogue -> 69.2 KB LDS; launch_bounds(512,2) lets the
// allocator keep ~128 VGPR (R15's (512,4) forced 64 -> spill disaster).
// At <=128 VGPR the HW can co-schedule 2 blocks/CU (16 waves).
__global__ __launch_bounds__(512, 2) void gemm256_k(
    const u16* __restrict__ A0,               // h_bf (2048 x 2048)
    const u16* __restrict__ B0, long bStride, // Wip_bf (8192 x 2048) per dir
    u16* __restrict__ C0, long cStride,       // xz_bf (2048 x 8192) per dir
    const float* __restrict__ cw,             // conv weights (2,4096,4)
    const float* __restrict__ cb,             // conv bias (2,4096)
    u16* __restrict__ ub)                     // u_bf (2,8,256,4096)
{
  constexpr int K = 2048, N = 8192, LDA = 2048;
  __shared__ __align__(16) u16 lds[34584];
  u16* As = lds;             // [2][8192]
  u16* Bs = lds + 16384;     // [2][8192]
  const int dir = blockIdx.z;
  const u16* A = A0;
  const u16* B = B0 + (long)dir * bStride;
  u16* C = C0 + (long)dir * cStride;
  const int flip = dir;

  const int tid = threadIdx.x;
  const int wave = tid >> 6, lane = tid & 63;
  const int wr = wave >> 2, wc = wave & 3;    // 2x4 wave grid; 128x64 C/wave
  const int bm = blockIdx.y * 256, bn = blockIdx.x * 256;
  const int lr = lane & 15, lq = lane >> 4;

  f32x4 acc[8][4];
#pragma unroll
  for (int i = 0; i < 8; ++i)
#pragma unroll
    for (int j = 0; j < 4; ++j) acc[i][j] = (f32x4){0.f, 0.f, 0.f, 0.f};

  auto stage = [&](int buf, int kt) {
    int k0 = kt << 5;
#pragma unroll
    for (int j = 0; j < 2; ++j) {
      int g = j * 512 + tid;               // granule 0..1023
      int row = g >> 2, sp = g & 3;
      int ss = sp ^ (row & 3) ^ (((row >> 2) & 1) << 1);
      int ar = flip ? (bm + 255 - row) : (bm + row);
      gload_lds16(A + (long)ar * LDA + k0 + ss * 8, &As[buf * 8192 + g * 8]);
      gload_lds16(B + (long)(bn + row) * K + k0 + ss * 8,
                  &Bs[buf * 8192 + g * 8]);
    }
  };

  const int nk = K >> 5;                     // 64 K-tiles
  stage(0, 0);
  for (int kt = 0; kt < nk; ++kt) {
    __builtin_amdgcn_s_barrier();
    __builtin_amdgcn_sched_barrier(0);
    if (kt + 1 < nk) {
      stage((kt + 1) & 1, kt + 1);
      asm volatile("s_waitcnt vmcnt(4)" ::: "memory");   // tile kt landed
    } else {
      asm volatile("s_waitcnt vmcnt(0)" ::: "memory");
    }
    __builtin_amdgcn_sched_barrier(0);
    __builtin_amdgcn_s_barrier();
    __builtin_amdgcn_sched_barrier(0);
    const int buf = kt & 1;
    bf16x8 av[8], bv[4];
#pragma unroll
    for (int i = 0; i < 8; ++i) {
      int R = wr * 128 + i * 16 + lr;
      int gp = lq ^ (R & 3) ^ (((R >> 2) & 1) << 1);
      av[i] = *(const bf16x8*)&As[buf * 8192 + R * 32 + gp * 8];
    }
#pragma unroll
    for (int j = 0; j < 4; ++j) {
      int R = wc * 64 + j * 16 + lr;
      int gp = lq ^ (R & 3) ^ (((R >> 2) & 1) << 1);
      bv[j] = *(const bf16x8*)&Bs[buf * 8192 + R * 32 + gp * 8];
    }
    __builtin_amdgcn_s_setprio(1);
#pragma unroll
    for (int i = 0; i < 8; ++i)
#pragma unroll
      for (int j = 0; j < 4; ++j)
        acc[i][j] = __builtin_amdgcn_mfma_f32_16x16x32_bf16(
            av[i], bv[j], acc[i][j], 0, 0, 0);
    __builtin_amdgcn_s_setprio(0);
  }

  if (bn < 4096) {
    // ---- fused conv1d + SiLU epilogue, two 128-row halves ----
    u16* tile = lds;                  // [128][264]
    u16* side = lds + 33792;          // [3][264]
    const int rgrp = tid >> 5, c8 = tid & 31;
    const int d0 = bn + c8 * 8;
    float wv0[8], wv1[8], wv2[8], wv3[8], cbv[8];
#pragma unroll
    for (int e = 0; e < 8; ++e) {
      const float4 wq = *(const float4*)(cw + ((long)dir * 4096 + d0 + e) * 4);
      wv0[e] = wq.x; wv1[e] = wq.y; wv2[e] = wq.z; wv3[e] = wq.w;
      cbv[e] = cb[dir * 4096 + d0 + e];
    }
    float w0[8], w1[8], w2[8];

    auto writeacc = [&]() {
#pragma unroll
      for (int i = 0; i < 8; ++i) {
        int r0 = i * 16 + lq * 4;     // local row in half
#pragma unroll
        for (int j = 0; j < 4; ++j) {
          int col = wc * 64 + j * 16 + lr;
          f32x4 v = acc[i][j];
#pragma unroll
          for (int r = 0; r < 4; ++r)
            tile[(r0 + r) * 264 + col] = f2b(v[r]);
        }
      }
    };

    auto convhalf = [&](int hh) {
      if (rgrp == 0) {
        if (hh == 0) {
#pragma unroll
          for (int e = 0; e < 8; ++e) { w0[e] = 0.f; w1[e] = 0.f; w2[e] = 0.f; }
        } else {
          bf16x8 t0 = *(const bf16x8*)&side[0 * 264 + c8 * 8];
          bf16x8 t1 = *(const bf16x8*)&side[1 * 264 + c8 * 8];
          bf16x8 t2 = *(const bf16x8*)&side[2 * 264 + c8 * 8];
#pragma unroll
          for (int e = 0; e < 8; ++e) {
            w0[e] = b2f((u16)t0[e]); w1[e] = b2f((u16)t1[e]);
            w2[e] = b2f((u16)t2[e]);
          }
        }
      } else {
        int lb = rgrp * 8;
        bf16x8 t0 = *(const bf16x8*)&tile[(lb - 3) * 264 + c8 * 8];
        bf16x8 t1 = *(const bf16x8*)&tile[(lb - 2) * 264 + c8 * 8];
        bf16x8 t2 = *(const bf16x8*)&tile[(lb - 1) * 264 + c8 * 8];
#pragma unroll
        for (int e = 0; e < 8; ++e) {
          w0[e] = b2f((u16)t0[e]); w1[e] = b2f((u16)t1[e]);
          w2[e] = b2f((u16)t2[e]);
        }
      }
      long ubase = ((long)(dir * 8 + blockIdx.y) * 256 + hh * 128 + rgrp * 8)
                       * 4096 + d0;
#pragma unroll
      for (int l = 0; l < 8; ++l) {
        bf16x8 t = *(const bf16x8*)&tile[(rgrp * 8 + l) * 264 + c8 * 8];
        float cur[8];
#pragma unroll
        for (int e = 0; e < 8; ++e) cur[e] = b2f((u16)t[e]);
        bf16x8 ov;
#pragma unroll
        for (int e = 0; e < 8; ++e) {
          float a = cbv[e] + wv0[e] * w0[e] + wv1[e] * w1[e] + wv2[e] * w2[e] +
                    wv3[e] * cur[e];
          ov[e] = (short)f2b(a / (1.f + __expf(-a)));
        }
        *(bf16x8*)(ub + ubase + (long)l * 4096) = ov;
#pragma unroll
        for (int e = 0; e < 8; ++e) { w0[e] = w1[e]; w1[e] = w2[e]; w2[e] = cur[e]; }
      }
    };

    __syncthreads();                  // K-loop LDS reads retired
    if (wr == 0) writeacc();          // rows 0..127
    __syncthreads();
    convhalf(0);
    if (tid < 96) {                   // save rows 125..127 for half-1 carry
      int rr = tid >> 5, cc = tid & 31;
      *(bf16x8*)&side[rr * 264 + cc * 8] =
          *(const bf16x8*)&tile[(125 + rr) * 264 + cc * 8];
    }
    __syncthreads();
    if (wr == 1) writeacc();          // rows 128..255 (local 0..127)
    __syncthreads();
    convhalf(1);
  } else {
    // ---- z half: plain C write ----
#pragma unroll
    for (int i = 0; i < 8; ++i) {
      int r0 = bm + wr * 128 + i * 16 + lq * 4;
#pragma unroll
      for (int j = 0; j < 4; ++j) {
        int col = bn + wc * 64 + j * 16 + lr;
        f32x4 v = acc[i][j];
#pragma unroll
        for (int r = 0; r < 4; ++r)
          C[(long)(r0 + r) * N + col] = f2b(v[r]);
      }
    }
  }
}

// ========== out_proj: 256^2 coarse structure, split-K=2, fp32 partials ======
__global__ __launch_bounds__(512, 2) void gemm256o_k(
    const u16* __restrict__ Y0,               // y_bf (2, 2048, 4096)
    const u16* __restrict__ W0,               // Wout_bf (2, 2048, 4096)
    float* __restrict__ part)                 // (4, 2048, 2048) fp32
{
  constexpr int LDK = 4096;
  __shared__ __align__(16) u16 lds[65536];
  u16* As = lds;
  u16* Bs = lds + 32768;
  const int dir = blockIdx.z >> 1, split = blockIdx.z & 1;
  const u16* A = Y0 + (long)dir * 2048 * 4096;
  const u16* B = W0 + (long)dir * 2048 * 4096;
  float* C = part + (long)blockIdx.z * 4194304;
  const int kbase = split << 11;              // 0 or 2048

  const int tid = threadIdx.x;
  const int wave = tid >> 6, lane = tid & 63;
  const int wr = wave >> 2, wc = wave & 3;
  const int bm = blockIdx.y * 256, bn = blockIdx.x * 256;
  const int lr = lane & 15, lq = lane >> 4;

  f32x4 acc[8][4];
#pragma unroll
  for (int i = 0; i < 8; ++i)
#pragma unroll
    for (int j = 0; j < 4; ++j) acc[i][j] = (f32x4){0.f, 0.f, 0.f, 0.f};

  auto stage = [&](int buf, int kt) {
    int k0 = kbase + (kt << 6);
#pragma unroll
    for (int hf = 0; hf < 2; ++hf)
#pragma unroll
      for (int j = 0; j < 2; ++j) {
        int g = j * 512 + tid;
        int rl = hf * 128 + (g >> 3);
        int gr = (g & 7) ^ ((g >> 3) & 7);
        gload_lds16(A + (long)(bm + rl) * LDK + k0 + gr * 8,
                    &As[buf * 16384 + hf * 8192 + g * 8]);
        gload_lds16(B + (long)(bn + rl) * LDK + k0 + gr * 8,
                    &Bs[buf * 16384 + hf * 8192 + g * 8]);
      }
  };

  const int nk = 32;                          // 2048 / 64
  stage(0, 0);
  for (int kt = 0; kt < nk; ++kt) {
    __builtin_amdgcn_s_barrier();
    __builtin_amdgcn_sched_barrier(0);
    if (kt + 1 < nk) {
      stage((kt + 1) & 1, kt + 1);
      asm volatile("s_waitcnt vmcnt(16)" ::: "memory");
    } else {
      asm volatile("s_waitcnt vmcnt(0)" ::: "memory");
    }
    __builtin_amdgcn_sched_barrier(0);
    __builtin_amdgcn_s_barrier();
    __builtin_amdgcn_sched_barrier(0);
    const int buf = kt & 1;
#pragma unroll
    for (int h = 0; h < 2; ++h) {
      bf16x8 av[8], bv[4];
#pragma unroll
      for (int i = 0; i < 8; ++i) {
        int row = wr * 128 + i * 16 + lr;
        av[i] = *(const bf16x8*)
            &As[buf * 16384 + ((row * 64 + h * 32 + lq * 8) ^ ((row & 7) << 3))];
      }
#pragma unroll
      for (int j = 0; j < 4; ++j) {
        int row = wc * 64 + j * 16 + lr;
        bv[j] = *(const bf16x8*)
            &Bs[buf * 16384 + ((row * 64 + h * 32 + lq * 8) ^ ((row & 7) << 3))];
      }
      __builtin_amdgcn_s_setprio(1);
#pragma unroll
      for (int i = 0; i < 8; ++i)
#pragma unroll
        for (int j = 0; j < 4; ++j)
          acc[i][j] = __builtin_amdgcn_mfma_f32_16x16x32_bf16(
              av[i], bv[j], acc[i][j], 0, 0, 0);
      __builtin_amdgcn_s_setprio(0);
    }
  }

#pragma unroll
  for (int i = 0; i < 8; ++i) {
    int r0 = bm + wr * 128 + i * 16 + lq * 4;
#pragma unroll
    for (int j = 0; j < 4; ++j) {
      int col = bn + wc * 64 + j * 16 + lr;
      f32x4 v = acc[i][j];
#pragma unroll
      for (int r = 0; r < 4; ++r)
        C[(long)(r0 + r) * 2048 + col] = v[r];
    }
  }
}

// ---------------- bf16 MFMA GEMM (128x128, m97 structure) ----------------
template <int EPI, int F32OUT, int BFOUT>
__global__ __launch_bounds__(256) void mfma_gemm_k(
    const u16* __restrict__ A0, long aStride,
    const u16* __restrict__ B0, long bStride,
    float* __restrict__ C0, long cStride,
    u16* __restrict__ Cb0, long cbStride,
    const float* __restrict__ bias0, int biasStride,
    int N, int K, int lda, int flipDir1)
{
  __shared__ __align__(16) u16 As[2][4096];
  __shared__ __align__(16) u16 Bs[2][4096];
  const int dir = blockIdx.z;
  const u16* A = A0 + (long)dir * aStride;
  const u16* B = B0 + (long)dir * bStride;
  float* C = F32OUT ? (C0 + (long)dir * cStride) : nullptr;
  u16* Cb = BFOUT ? (Cb0 + (long)dir * cbStride) : nullptr;
  const float* bias = (EPI == 1) ? (bias0 + (long)dir * biasStride) : nullptr;
  const int flip = flipDir1 && (dir == 1);

  const int tid = threadIdx.x;
  const int wave = tid >> 6, lane = tid & 63;
  const int wr = wave >> 1, wc = wave & 1;
  const int bm = blockIdx.y * 128, bn = blockIdx.x * 128;
  const int lr = lane & 15, lq = lane >> 4;

  f32x4 acc[4][4];
#pragma unroll
  for (int i = 0; i < 4; ++i)
#pragma unroll
    for (int j = 0; j < 4; ++j) acc[i][j] = (f32x4){0.f, 0.f, 0.f, 0.f};

  const int nk = K >> 5;

  auto stage = [&](int buf, int k0) {
#pragma unroll
    for (int iss = 0; iss < 2; ++iss) {
      int ob = wave * 2048 + iss * 1024 + lane * 16;
      int row = ob >> 6, kb = (ob >> 4) & 3;
      int rg = bm + row;
      rg = flip ? ((rg & ~255) | (255 - (rg & 255))) : rg;
      gload_lds16(A + (long)rg * lda + k0 + kb * 8,
                  &As[buf][wave * 1024 + iss * 512]);
      int rb = bn + row; rb = (rb < N) ? rb : (N - 1);
      gload_lds16(B + (long)rb * K + k0 + kb * 8,
                  &Bs[buf][wave * 1024 + iss * 512]);
    }
  };

  stage(0, 0);
  for (int kt = 0; kt < nk; ++kt) {
    __syncthreads();
    if (kt + 1 < nk) stage((kt + 1) & 1, (kt + 1) << 5);
    const int buf = kt & 1;
    bf16x8 av[4], bv[4];
#pragma unroll
    for (int i = 0; i < 4; ++i)
      av[i] = *(const bf16x8*)&As[buf][(wr * 64 + i * 16 + lr) * 32 + lq * 8];
#pragma unroll
    for (int j = 0; j < 4; ++j)
      bv[j] = *(const bf16x8*)&Bs[buf][(wc * 64 + j * 16 + lr) * 32 + lq * 8];
#pragma unroll
    for (int i = 0; i < 4; ++i)
#pragma unroll
      for (int j = 0; j < 4; ++j)
        acc[i][j] = __builtin_amdgcn_mfma_f32_16x16x32_bf16(av[i], bv[j],
                                                            acc[i][j], 0, 0, 0);
  }

#pragma unroll
  for (int i = 0; i < 4; ++i) {
    int r0 = bm + wr * 64 + i * 16 + lq * 4;
#pragma unroll
    for (int j = 0; j < 4; ++j) {
      int col = bn + wc * 64 + j * 16 + lr;
      if (col < N) {
        f32x4 v = acc[i][j];
#pragma unroll
        for (int r = 0; r < 4; ++r) {
          float xv = v[r];
          if (EPI == 1) {
            xv += bias[col];
            xv = (xv > 20.f) ? xv : log1pf(expf(xv));
          }
          if (F32OUT) C[(long)(r0 + r) * N + col] = xv;
          if (BFOUT) Cb[(long)(r0 + r) * N + col] = f2b(xv);
        }
      }
    }
  }
}

// ---------------- x_dbl split-K partial GEMM ----------------
__global__ __launch_bounds__(256) void xdbl_part_k(
    const u16* __restrict__ ubf, const u16* __restrict__ Wxbf,
    float* __restrict__ part)
{
  __shared__ __align__(16) u16 As[2][4096];
  __shared__ __align__(16) u16 Bs[2][4096];
  const int dir = blockIdx.z >> 2, split = blockIdx.z & 3;
  const u16* A = ubf + (long)dir * 2048 * 4096;
  const u16* B = Wxbf + (long)dir * 160 * 4096;
  float* C = part + (long)blockIdx.z * 327680;
  const int tid = threadIdx.x;
  const int wave = tid >> 6, lane = tid & 63;
  const int wr = wave >> 1, wc = wave & 1;
  const int bm = blockIdx.y * 128, bn = blockIdx.x * 128;
  const int lr = lane & 15, lq = lane >> 4;

  f32x4 acc[4][4];
#pragma unroll
  for (int i = 0; i < 4; ++i)
#pragma unroll
    for (int j = 0; j < 4; ++j) acc[i][j] = (f32x4){0.f, 0.f, 0.f, 0.f};

  auto stage = [&](int buf, int k0) {
#pragma unroll
    for (int iss = 0; iss < 2; ++iss) {
      int ob = wave * 2048 + iss * 1024 + lane * 16;
      int row = ob >> 6, kb = (ob >> 4) & 3;
      gload_lds16(A + (long)(bm + row) * 4096 + k0 + kb * 8,
                  &As[buf][wave * 1024 + iss * 512]);
      int rb = bn + row; rb = (rb < 160) ? rb : 159;
      gload_lds16(B + (long)rb * 4096 + k0 + kb * 8,
                  &Bs[buf][wave * 1024 + iss * 512]);
    }
  };

  const int kbase = split << 10;
  stage(0, kbase);
  for (int kt = 0; kt < 32; ++kt) {
    __syncthreads();
    if (kt + 1 < 32) stage((kt + 1) & 1, kbase + ((kt + 1) << 5));
    const int buf = kt & 1;
    bf16x8 av[4], bv[4];
#pragma unroll
    for (int i = 0; i < 4; ++i)
      av[i] = *(const bf16x8*)&As[buf][(wr * 64 + i * 16 + lr) * 32 + lq * 8];
#pragma unroll
    for (int j = 0; j < 4; ++j)
      bv[j] = *(const bf16x8*)&Bs[buf][(wc * 64 + j * 16 + lr) * 32 + lq * 8];
#pragma unroll
    for (int i = 0; i < 4; ++i)
#pragma unroll
      for (int j = 0; j < 4; ++j)
        acc[i][j] = __builtin_amdgcn_mfma_f32_16x16x32_bf16(av[i], bv[j],
                                                            acc[i][j], 0, 0, 0);
  }

#pragma unroll
  for (int i = 0; i < 4; ++i) {
    int r0 = bm + wr * 64 + i * 16 + lq * 4;
#pragma unroll
    for (int j = 0; j < 4; ++j) {
      int col = bn + wc * 64 + j * 16 + lr;
      if (col < 160) {
        f32x4 v = acc[i][j];
#pragma unroll
        for (int r = 0; r < 4; ++r)
          C[(long)(r0 + r) * 160 + col] = v[r];
      }
    }
  }
}

// ---------------- x_dbl split-K reduce -> fp32 + bf16 ----------------
__global__ __launch_bounds__(256) void xdbl_reduce_k(
    const float* __restrict__ part, float* __restrict__ xdbl,
    u16* __restrict__ xdbl_bf)
{
  int i = blockIdx.x * 256 + threadIdx.x;
  if (i >= 655360) return;
  int dir = i / 327680, rem = i - dir * 327680;
  long pb = (long)dir * 4 * 327680 + rem;
  float s = part[pb] + part[pb + 327680] + part[pb + 2 * 327680] +
            part[pb + 3 * 327680];
  xdbl[i] = s;
  xdbl_bf[i] = f2b(s);
}

// ---------------- scan pass A: per-chunk local scan (zero init) --------------
__global__ __launch_bounds__(256) void scan_a_k(
    const u16* __restrict__ dtbuf, const u16* __restrict__ ubuf,
    const float* __restrict__ xdbl, const float* __restrict__ A_log,
    const float* __restrict__ Dpv, u16* __restrict__ ypre,
    float* __restrict__ stend, float* __restrict__ dtsum)
{
  int blk = blockIdx.x;
  int dtile = blk & 15, c = (blk >> 4) & 7, b = (blk >> 7) & 7, dir = blk >> 10;
  int tid = threadIdx.x;
  int d = dtile * 256 + tid;
  int db = dir * 8 + b;

  __shared__ float sB[32][16], sC[32][16];
  long r160 = (long)db * 256 * 160;
  for (int i = tid; i < 1024; i += 256) {
    int l = i >> 5, s = i & 31;
    float v = xdbl[r160 + (long)(c * 32 + l) * 160 + 128 + s];
    if (s < 16) sB[l][s] = v; else sC[l][s - 16] = v;
  }
  __syncthreads();

  float A[16], st[16];
  const float4* ap = (const float4*)(A_log + ((long)dir * 4096 + d) * 16);
#pragma unroll
  for (int q = 0; q < 4; ++q) {
    float4 t = ap[q];
    A[q * 4 + 0] = -__expf(t.x); A[q * 4 + 1] = -__expf(t.y);
    A[q * 4 + 2] = -__expf(t.z); A[q * 4 + 3] = -__expf(t.w);
  }
#pragma unroll
  for (int s = 0; s < 16; ++s) st[s] = 0.f;
  float Dpd = Dpv[dir * 4096 + d];

  long base = (long)db * 256 * 4096 + (long)c * 32 * 4096 + d;
  float dts = 0.f;
  for (int i = 0; i < 32; ++i) {
    float dtv = b2f(dtbuf[base + (long)i * 4096]);
    float uv  = b2f(ubuf[base + (long)i * 4096]);
    dts += dtv;
    float du = dtv * uv;
    float y = 0.f;
#pragma unroll
    for (int s = 0; s < 16; ++s) {
      st[s] = st[s] * __expf(dtv * A[s]) + du * sB[i][s];
      y += st[s] * sC[i][s];
    }
    ypre[base + (long)i * 4096] = f2b(y + uv * Dpd);
  }
  long eb = ((long)(db * 8 + c) * 4096 + d) * 16;
  float4* ep = (float4*)(stend + eb);
#pragma unroll
  for (int q = 0; q < 4; ++q)
    ep[q] = make_float4(st[q * 4], st[q * 4 + 1], st[q * 4 + 2], st[q * 4 + 3]);
  dtsum[(long)(db * 8 + c) * 4096 + d] = dts;
}

// ---------------- scan pass B: chunk combine + correction + gating -----------
__global__ __launch_bounds__(512) void scan_b_k(
    const u16* __restrict__ dtbuf, const u16* __restrict__ xzbf,
    const float* __restrict__ xdbl, const float* __restrict__ A_log,
    const float* __restrict__ stend, const float* __restrict__ dtsum,
    u16* __restrict__ ybuf)
{
  int blk = blockIdx.x;
  int dtile = blk & 63, b = (blk >> 6) & 7, dir = blk >> 9;
  int tid = threadIdx.x;
  int c = tid >> 6, dd = tid & 63;
  int d0 = dtile * 64, d = d0 + dd;
  int db = dir * 8 + b;

  __shared__ float sEnd[8][64][17];
  __shared__ float sT[8][64];
  __shared__ float sC[256][16];

  long eBase = (long)db * 8 * 65536;
  for (int i = tid; i < 8192; i += 512) {
    int cc = i >> 10, rem = i & 1023, dd2 = rem >> 4, s = rem & 15;
    sEnd[cc][dd2][s] = stend[eBase + (long)cc * 65536 + (long)(d0 + dd2) * 16 + s];
  }
  {
    int cc = tid >> 6, dd2 = tid & 63;
    sT[cc][dd2] = dtsum[(long)(db * 8 + cc) * 4096 + d0 + dd2];
  }
  long r160 = (long)db * 256 * 160;
  for (int i = tid; i < 4096; i += 512) {
    int l = i >> 4, s = i & 15;
    sC[l][s] = xdbl[r160 + (long)l * 160 + 144 + s];
  }
  __syncthreads();

  float A[16];
  const float4* ap = (const float4*)(A_log + ((long)dir * 4096 + d) * 16);
#pragma unroll
  for (int q = 0; q < 4; ++q) {
    float4 t = ap[q];
    A[q * 4 + 0] = -__expf(t.x); A[q * 4 + 1] = -__expf(t.y);
    A[q * 4 + 2] = -__expf(t.z); A[q * 4 + 3] = -__expf(t.w);
  }
  float g[16];
#pragma unroll
  for (int s = 0; s < 16; ++s) g[s] = 0.f;
  for (int j = 0; j < c; ++j) {
    float Tj = sT[j][dd];
#pragma unroll
    for (int s = 0; s < 16; ++s)
      g[s] = g[s] * __expf(A[s] * Tj) + sEnd[j][dd][s];
  }

  long base  = (long)db * 256 * 4096 + (long)c * 32 * 4096 + d;
  long zbase = (long)db * 256 * 8192 + (long)c * 32 * 8192 + 4096 + d;
  float cum = 0.f;
  if (c == 0) {
    for (int i = 0; i < 32; ++i) {
      float yp = b2f(ybuf[base + (long)i * 4096]);
      float zv = b2f(xzbf[zbase + (long)i * 8192]);
      float y = yp * (zv / (1.f + __expf(-zv)));
      ybuf[base + (long)i * 4096] = f2b(y);
    }
  } else {
    for (int i = 0; i < 32; ++i) {
      float dtv = b2f(dtbuf[base + (long)i * 4096]);
      cum += dtv;
      float yp = b2f(ybuf[base + (long)i * 4096]);
      float corr = 0.f;
      const int l = c * 32 + i;
#pragma unroll
      for (int s = 0; s < 16; ++s)
        corr += sC[l][s] * __expf(A[s] * cum) * g[s];
      float zv = b2f(xzbf[zbase + (long)i * 8192]);
      float y = (yp + corr) * (zv / (1.f + __expf(-zv)));
      ybuf[base + (long)i * 4096] = f2b(y);
    }
  }
}

// ------- residual add (fwd + flipped rev, split-K partials) + LN -> bf16 ----
__global__ __launch_bounds__(256) void add_ln_k(
    const float* __restrict__ h, const float* __restrict__ op,
    const float* __restrict__ g, const float* __restrict__ bta,
    u16* __restrict__ h2b)
{
  int row = blockIdx.x;
  int b = row >> 8, l = row & 255;
  long base = (long)row * 2048;
  long base1 = ((long)b * 256 + (255 - l)) * 2048;
  int t8 = threadIdx.x * 8;
  const float* p0 = op;                       // dir0 split0
  const float* p1 = op + 4194304;             // dir0 split1
  const float* p2 = op + 2L * 4194304;        // dir1 split0
  const float* p3 = op + 3L * 4194304;
  float v[8];
  float4 x0 = *(const float4*)(h + base + t8);
  float4 x1 = *(const float4*)(h + base + t8 + 4);
  float4 a0 = *(const float4*)(p0 + base + t8);
  float4 a1 = *(const float4*)(p0 + base + t8 + 4);
  float4 b0 = *(const float4*)(p1 + base + t8);
  float4 b1 = *(const float4*)(p1 + base + t8 + 4);
  float4 c0 = *(const float4*)(p2 + base1 + t8);
  float4 c1 = *(const float4*)(p2 + base1 + t8 + 4);
  float4 d0 = *(const float4*)(p3 + base1 + t8);
  float4 d1 = *(const float4*)(p3 + base1 + t8 + 4);
  v[0] = x0.x + a0.x + b0.x + c0.x + d0.x;
  v[1] = x0.y + a0.y + b0.y + c0.y + d0.y;
  v[2] = x0.z + a0.z + b0.z + c0.z + d0.z;
  v[3] = x0.w + a0.w + b0.w + c0.w + d0.w;
  v[4] = x1.x + a1.x + b1.x + c1.x + d1.x;
  v[5] = x1.y + a1.y + b1.y + c1.y + d1.y;
  v[6] = x1.z + a1.z + b1.z + c1.z + d1.z;
  v[7] = x1.w + a1.w + b1.w + c1.w + d1.w;
  float s = 0.f, ss = 0.f;
#pragma unroll
  for (int j = 0; j < 8; ++j) { s += v[j]; ss += v[j] * v[j]; }
#pragma unroll
  for (int off = 32; off >= 1; off >>= 1) {
    s += __shfl_xor(s, off, 64);
    ss += __shfl_xor(ss, off, 64);
  }
  __shared__ float red[8];
  int wid = threadIdx.x >> 6, lane = threadIdx.x & 63;
  if (lane == 0) { red[wid] = s; red[wid + 4] = ss; }
  __syncthreads();
  if (threadIdx.x == 0) {
    red[0] = red[0] + red[1] + red[2] + red[3];
    red[4] = red[4] + red[5] + red[6] + red[7];
  }
  __syncthreads();
  float mean = red[0] * (1.f / 2048.f);
  float var = red[4] * (1.f / 2048.f) - mean * mean;
  float inv = rsqrtf(var + 1e-5f);
  bf16x8 o;
#pragma unroll
  for (int j = 0; j < 8; ++j)
    o[j] = (short)f2b((v[j] - mean) * inv * g[t8 + j] + bta[t8 + j]);
  *(bf16x8*)(h2b + base + t8) = o;
}

// ---------------- 31x31 "same" conv via MFMA Toeplitz (bf16 input) ----------
__global__ __launch_bounds__(256) void dec_conv31_k(
    const u16* __restrict__ h2b, const u16* __restrict__ tb,
    float* __restrict__ dc)
{
  __shared__ __align__(16) u16 sIn[94 * 120];
  const int b = blockIdx.z;
  const int l0 = blockIdx.y * 64;
  const int m0 = blockIdx.x * 64;
  const int tid = threadIdx.x;
  const u16* src = h2b + (long)b * 256 * 2048;
  for (int i = tid; i < 94 * 112; i += 256) {
    int r = i / 112, c = i - r * 112;
    int gl = l0 + r - 15, gm = m0 + c - 15;
    u16 v = 0;
    if (gl >= 0 && gl < 256 && gm >= 0 && gm < 2048)
      v = src[(long)gl * 2048 + gm];
    sIn[r * 120 + c] = v;
  }
  __syncthreads();
  const int wave = tid >> 6, lane = tid & 63;
  const int lr = lane & 15, lq = lane >> 4;

  f32x4 acc[4];
#pragma unroll
  for (int s = 0; s < 4; ++s) acc[s] = (f32x4){0.f, 0.f, 0.f, 0.f};

#pragma unroll 1
  for (int ki = 0; ki < 31; ++ki) {
    const u16* arow = &sIn[(wave * 16 + lr + ki) * 120];
#pragma unroll
    for (int h = 0; h < 2; ++h) {
      bf16x8 bv = *(const bf16x8*)&tb[((ki * 2 + h) * 16 + lr) * 32 + lq * 8];
#pragma unroll
      for (int ms = 0; ms < 4; ++ms) {
        bf16x8 av = *(const bf16x8*)&arow[ms * 16 + h * 32 + lq * 8];
        acc[ms] = __builtin_amdgcn_mfma_f32_16x16x32_bf16(av, bv, acc[ms], 0, 0, 0);
      }
    }
  }
#pragma unroll
  for (int ms = 0; ms < 4; ++ms) {
    f32x4 v = acc[ms];
#pragma unroll
    for (int r = 0; r < 4; ++r)
      dc[((long)b * 256 + l0 + wave * 16 + lq * 4 + r) * 2048 + m0 + ms * 16 + lr]
          = v[r];
  }
}

// ---------------- fused transposed conv (stride 2x16) ----------------
__global__ __launch_bounds__(256) void convT_k(
    const float* __restrict__ dc, const float* __restrict__ w,
    const float* __restrict__ wb, float* __restrict__ out)
{
  int j = blockIdx.x, b = blockIdx.y;
  __shared__ float sD[2048];
  __shared__ float sW[2048];
  int tid = threadIdx.x;
  const float* drow = dc + ((long)b * 256 + j) * 2048;
  for (int i = tid; i < 2048; i += 256) { sD[i] = drow[i]; sW[i] = w[i]; }
  __syncthreads();
  float cb = wb[0];
  int owlo = tid & 15, ohbase = tid >> 4;
#pragma unroll
  for (int q = 0; q < 4; ++q) {
    int oh = ohbase + q * 16;
    int i = oh >> 1, a = oh & 1;
    float acc = cb;
#pragma unroll 8
    for (int e = 0; e < 64; ++e)
      acc += sD[e * 32 + i] * sW[e * 32 + a * 16 + owlo];
    out[((long)b * 64 + oh) * 4096 + j * 16 + owlo] = acc;
  }
}

// ---------------- launcher ----------------
extern "C" void kernel_launch(void* const* d_in, const int* in_sizes, int n_in,
                              void* d_out, int out_size, void* d_ws, size_t ws_size,
                              hipStream_t stream)
{
  const float* x      = (const float*)d_in[0];
  const int*   mask   = (const int*)d_in[1];
  const float* proj_w = (const float*)d_in[2];
  const float* proj_b = (const float*)d_in[3];
  const float* pos    = (const float*)d_in[4];
  const float* Wip    = (const float*)d_in[5];   // (1,2,8192,2048)
  const float* convw  = (const float*)d_in[6];
  const float* convb  = (const float*)d_in[7];
  const float* Wx     = (const float*)d_in[8];   // (1,2,160,4096)
  const float* Wdt    = (const float*)d_in[9];   // (1,2,4096,128)
  const float* bdt    = (const float*)d_in[10];
  const float* Alog   = (const float*)d_in[11];
  const float* Dpv    = (const float*)d_in[12];
  const float* Wout   = (const float*)d_in[13];  // (1,2,2048,4096)
  const float* lng    = (const float*)d_in[14];
  const float* lnb    = (const float*)d_in[15];
  const float* dkw    = (const float*)d_in[16];  // (1,1,31,31)
  const float* ctw    = (const float*)d_in[17];
  const float* ctb    = (const float*)d_in[18];
  float* out = (float*)d_out;

  // workspace layout (bytes)
  char* p = (char*)d_ws;
  u16*   xz_bf   = (u16*)p;            // z-half used
  p += 67108864;
  u16*   u_bf    = (u16*)p;            // later dc alias
  float* dc      = (float*)p;
  p += 33554432;
  u16*   dt_bf   = (u16*)p; p += 67108864;     // also out_proj partials later
  float* xdbl    = (float*)p; p += 2621440;
  u16*   xdbl_bf = (u16*)p;  p += 1310720;
  float* h       = (float*)p; p += 16777216;
  u16*   h_bf    = (u16*)p;  p += 8388608;
  float* h2      = (float*)p; p += 16777216;   // used only as dtsum scratch
  u16*   y_bf    = (u16*)p;  p += 33554432;
  u16*   Wpool   = (u16*)p;  p += 67108864;    // Wip_bf; later Wout_bf (1st half)
  u16*   Wx_bf   = (u16*)p;  p += 2621440;
  u16*   Wdt_bf  = (u16*)p;  p += 2097152;
  u16*   tb      = (u16*)p;  p += 65536;       // Toeplitz tiles
  u16*   h2b     = (u16*)p;  p += 8388608;     // LN output, bf16

  // scratch aliases (temporally disjoint):
  float* part    = (float*)(Wpool + 16777216); // x_dbl split-K partials
  float* st_end  = (float*)(Wpool + 16777216); // scan chunk end-states
  float* dtsum   = h2;
  float* opart   = (float*)dt_bf;              // out_proj partials (dt dead)

  // weight converts + Toeplitz expansion
  cvt_bf16_k<<<32768, 256, 0, stream>>>(Wip, Wpool, 8388608);
  cvt_bf16_k<<<1280, 256, 0, stream>>>(Wx, Wx_bf, 327680);
  cvt_bf16_k<<<1024, 256, 0, stream>>>(Wdt, Wdt_bf, 262144);
  toeplitz_k<<<124, 256, 0, stream>>>(dkw, tb);

  // 1) patchify + pos embed
  patchify_k<<<dim3(256, 8), 256, 0, stream>>>(x, mask, proj_w, proj_b, pos, h, h_bf);

  // 2) in_proj + fused conv1d/SiLU epilogue (BK=32, bounds (512,2))
  gemm256_k<<<dim3(32, 8, 2), 512, 0, stream>>>(
      h_bf, Wpool, (long)8192 * 2048, xz_bf, (long)2048 * 8192,
      convw, convb, u_bf);

  // 3) x_dbl = u @ Wx^T via split-K(4) + reduce (fp32 + bf16 mirror)
  xdbl_part_k<<<dim3(2, 16, 8), 256, 0, stream>>>(u_bf, Wx_bf, part);
  xdbl_reduce_k<<<2560, 256, 0, stream>>>(part, xdbl, xdbl_bf);

  // 4) dt = softplus(x_dbl[:, :128] @ Wdt^T + bdt) -> bf16
  mfma_gemm_k<1, 0, 1><<<dim3(32, 16, 2), 256, 0, stream>>>(
      xdbl_bf, (long)2048 * 160, Wdt_bf, (long)4096 * 128, nullptr, 0L,
      dt_bf, (long)2048 * 4096, bdt, 4096, 4096, 128, 160, 0);

  // 5) chunked selective scan
  scan_a_k<<<2048, 256, 0, stream>>>(dt_bf, u_bf, xdbl, Alog, Dpv, y_bf, st_end, dtsum);
  scan_b_k<<<1024, 512, 0, stream>>>(dt_bf, xz_bf, xdbl, Alog, st_end, dtsum, y_bf);

  // convert Wout into the (now dead) first half of Wpool
  cvt_bf16_k<<<16384, 256, 0, stream>>>(Wout, Wpool, 4194304);

  // 6) out_proj via 256^2 coarse split-K(2): partials into dead dt region
  gemm256o_k<<<dim3(8, 8, 4), 512, 0, stream>>>(y_bf, Wpool, opart);

  // 7) h2b = LN(h + p0+p1 + flip(p2+p3))  [reduce fused, bf16 out]
  add_ln_k<<<2048, 256, 0, stream>>>(h, opart, lng, lnb, h2b);

  // 8) 31x31 same conv via MFMA Toeplitz (bf16 in) -> dc [u_bf dead]
  dec_conv31_k<<<dim3(32, 4, 8), 256, 0, stream>>>(h2b, tb, dc);

  // 9) fused transposed conv -> rec
  convT_k<<<dim3(256, 8), 256, 0, stream>>>(dc, ctw, ctb, out);

  // 10) second output: x passthrough
  hipMemcpyAsync(out + 2097152, x, (size_t)2097152 * 4,
                 hipMemcpyDeviceToDevice, stream);
}

// Round 18
// 593.459 us; speedup vs baseline: 3.1497x; 1.0389x over previous
//
#include <hip/hip_runtime.h>
#include <hip/hip_bf16.h>
#include <math.h>

typedef unsigned short u16;
typedef __attribute__((ext_vector_type(8))) short bf16x8;
typedef __attribute__((ext_vector_type(4))) float f32x4;

__device__ __forceinline__ float b2f(u16 v) {
  unsigned u = ((unsigned)v) << 16;
  return __builtin_bit_cast(float, u);
}
__device__ __forceinline__ u16 f2b(float f) {
  unsigned u = __builtin_bit_cast(unsigned, f);
  unsigned r = u + 0x7fffu + ((u >> 16) & 1u);
  return (u16)(r >> 16);
}
__device__ __forceinline__ void gload_lds16(const u16* g, u16* l) {
  __builtin_amdgcn_global_load_lds(
      (const __attribute__((address_space(1))) void*)g,
      (__attribute__((address_space(3))) void*)l, 16, 0, 0);
}

// ---------------- fp32 -> bf16 convert ----------------
__global__ __launch_bounds__(256) void cvt_bf16_k(const float* __restrict__ s,
                                                  u16* __restrict__ d, int n4) {
  int i = blockIdx.x * 256 + threadIdx.x;
  if (i < n4) {
    float4 v = ((const float4*)s)[i];
    ushort4 o;
    o.x = f2b(v.x); o.y = f2b(v.y); o.z = f2b(v.z); o.w = f2b(v.w);
    ((ushort4*)d)[i] = o;
  }
}

// ---------------- Toeplitz expansion of 31x31 kernel ----------------
__global__ __launch_bounds__(256) void toeplitz_k(
    const float* __restrict__ kw, u16* __restrict__ tb)
{
  int i = blockIdx.x * 256 + threadIdx.x;
  if (i >= 31744) return;
  int k = i & 31, n = (i >> 5) & 15, h = (i >> 9) & 1, ki = i >> 10;
  int t = h * 32 + k - n;
  float v = (t >= 0 && t <= 30) ? kw[ki * 31 + t] : 0.f;
  tb[i] = f2b(v);
}

// ---------------- patchify + pos embed -> h fp32 + h_bf ----------------
__global__ __launch_bounds__(256) void patchify_k(
    const float* __restrict__ x, const int* __restrict__ mask,
    const float* __restrict__ pw, const float* __restrict__ pb,
    const float* __restrict__ pos, float* __restrict__ h, u16* __restrict__ hb)
{
  int g1 = blockIdx.x, b = blockIdx.y, tid = threadIdx.x;
  __shared__ float sX[64 * 17];
  __shared__ float sW[2048];
  for (int i = tid; i < 64 * 16; i += 256) {
    int r = i >> 4, c = i & 15;
    int gi = (b * 64 + r) * 4096 + g1 * 16 + c;
    sX[r * 17 + c] = mask[gi] ? 0.f : x[gi];
  }
  for (int i = tid; i < 2048; i += 256) sW[i] = pw[i];
  __syncthreads();
  for (int m = tid; m < 2048; m += 256) {
    int e = m >> 5, g0 = m & 31;
    float acc = pb[e];
    const float* w = &sW[e * 32];
#pragma unroll
    for (int kh = 0; kh < 2; ++kh)
#pragma unroll
      for (int kw = 0; kw < 16; ++kw)
        acc += sX[(2 * g0 + kh) * 17 + kw] * w[kh * 16 + kw];
    float v = acc + pos[g1 * 2048 + m];
    long o = ((long)b * 256 + g1) * 2048 + m;
    h[o] = v;
    hb[o] = f2b(v);
  }
}

// ========== 256x256x(BK=64) 8-wave MFMA GEMM for in_proj (R16 proven) =======
__global__ __launch_bounds__(512, 2) void gemm256_k(
    const u16* __restrict__ A0,               // h_bf (2048 x 2048)
    const u16* __restrict__ B0, long bStride, // Wip_bf (8192 x 2048) per dir
    u16* __restrict__ C0, long cStride,       // xz_bf (2048 x 8192) per dir
    const float* __restrict__ cw,             // conv weights (2,4096,4)
    const float* __restrict__ cb,             // conv bias (2,4096)
    u16* __restrict__ ub)                     // u_bf (2,8,256,4096)
{
  constexpr int K = 2048, N = 8192, LDA = 2048;
  __shared__ __align__(16) u16 lds[67584];
  u16* As = lds;
  u16* Bs = lds + 32768;
  const int dir = blockIdx.z;
  const u16* A = A0;
  const u16* B = B0 + (long)dir * bStride;
  u16* C = C0 + (long)dir * cStride;
  const int flip = dir;

  const int tid = threadIdx.x;
  const int wave = tid >> 6, lane = tid & 63;
  const int wr = wave >> 2, wc = wave & 3;
  const int bm = blockIdx.y * 256, bn = blockIdx.x * 256;
  const int lr = lane & 15, lq = lane >> 4;

  f32x4 acc[8][4];
#pragma unroll
  for (int i = 0; i < 8; ++i)
#pragma unroll
    for (int j = 0; j < 4; ++j) acc[i][j] = (f32x4){0.f, 0.f, 0.f, 0.f};

  auto stage = [&](int buf, int kt) {
    int k0 = kt << 6;
#pragma unroll
    for (int hf = 0; hf < 2; ++hf)
#pragma unroll
      for (int j = 0; j < 2; ++j) {
        int g = j * 512 + tid;
        int rl = hf * 128 + (g >> 3);
        int gr = (g & 7) ^ ((g >> 3) & 7);
        int ar = flip ? (bm + 255 - rl) : (bm + rl);
        gload_lds16(A + (long)ar * LDA + k0 + gr * 8,
                    &As[buf * 16384 + hf * 8192 + g * 8]);
        gload_lds16(B + (long)(bn + rl) * K + k0 + gr * 8,
                    &Bs[buf * 16384 + hf * 8192 + g * 8]);
      }
  };

  const int nk = K >> 6;
  stage(0, 0);
  for (int kt = 0; kt < nk; ++kt) {
    __builtin_amdgcn_s_barrier();
    __builtin_amdgcn_sched_barrier(0);
    if (kt + 1 < nk) {
      stage((kt + 1) & 1, kt + 1);
      asm volatile("s_waitcnt vmcnt(16)" ::: "memory");
    } else {
      asm volatile("s_waitcnt vmcnt(0)" ::: "memory");
    }
    __builtin_amdgcn_sched_barrier(0);
    __builtin_amdgcn_s_barrier();
    __builtin_amdgcn_sched_barrier(0);
    const int buf = kt & 1;
#pragma unroll
    for (int h = 0; h < 2; ++h) {
      bf16x8 av[8], bv[4];
#pragma unroll
      for (int i = 0; i < 8; ++i) {
        int row = wr * 128 + i * 16 + lr;
        av[i] = *(const bf16x8*)
            &As[buf * 16384 + ((row * 64 + h * 32 + lq * 8) ^ ((row & 7) << 3))];
      }
#pragma unroll
      for (int j = 0; j < 4; ++j) {
        int row = wc * 64 + j * 16 + lr;
        bv[j] = *(const bf16x8*)
            &Bs[buf * 16384 + ((row * 64 + h * 32 + lq * 8) ^ ((row & 7) << 3))];
      }
      __builtin_amdgcn_s_setprio(1);
#pragma unroll
      for (int i = 0; i < 8; ++i)
#pragma unroll
        for (int j = 0; j < 4; ++j)
          acc[i][j] = __builtin_amdgcn_mfma_f32_16x16x32_bf16(
              av[i], bv[j], acc[i][j], 0, 0, 0);
      __builtin_amdgcn_s_setprio(0);
    }
  }

  if (bn < 4096) {
    __syncthreads();
    u16* tile = lds;                 // [256][264] bf16
#pragma unroll
    for (int i = 0; i < 8; ++i) {
      int r0 = wr * 128 + i * 16 + lq * 4;
#pragma unroll
      for (int j = 0; j < 4; ++j) {
        int col = wc * 64 + j * 16 + lr;
        f32x4 v = acc[i][j];
#pragma unroll
        for (int r = 0; r < 4; ++r)
          tile[(r0 + r) * 264 + col] = f2b(v[r]);
      }
    }
    __syncthreads();
    const int rgrp = tid >> 5, c8 = tid & 31;
    const int d0 = bn + c8 * 8;
    float wv0[8], wv1[8], wv2[8], wv3[8], cbv[8];
#pragma unroll
    for (int e = 0; e < 8; ++e) {
      const float4 wq = *(const float4*)(cw + ((long)dir * 4096 + d0 + e) * 4);
      wv0[e] = wq.x; wv1[e] = wq.y; wv2[e] = wq.z; wv3[e] = wq.w;
      cbv[e] = cb[dir * 4096 + d0 + e];
    }
    const int l0 = rgrp * 16;
    float w0[8], w1[8], w2[8];
#pragma unroll
    for (int e = 0; e < 8; ++e) { w0[e] = 0.f; w1[e] = 0.f; w2[e] = 0.f; }
    if (rgrp > 0) {
      bf16x8 t0 = *(const bf16x8*)&tile[(l0 - 3) * 264 + c8 * 8];
      bf16x8 t1 = *(const bf16x8*)&tile[(l0 - 2) * 264 + c8 * 8];
      bf16x8 t2 = *(const bf16x8*)&tile[(l0 - 1) * 264 + c8 * 8];
#pragma unroll
      for (int e = 0; e < 8; ++e) {
        w0[e] = b2f((u16)t0[e]); w1[e] = b2f((u16)t1[e]); w2[e] = b2f((u16)t2[e]);
      }
    }
    long ubase = ((long)(dir * 8 + blockIdx.y) * 256 + l0) * 4096 + d0;
#pragma unroll
    for (int l = 0; l < 16; ++l) {
      bf16x8 t = *(const bf16x8*)&tile[(l0 + l) * 264 + c8 * 8];
      float cur[8];
#pragma unroll
      for (int e = 0; e < 8; ++e) cur[e] = b2f((u16)t[e]);
      bf16x8 ov;
#pragma unroll
      for (int e = 0; e < 8; ++e) {
        float a = cbv[e] + wv0[e] * w0[e] + wv1[e] * w1[e] + wv2[e] * w2[e] +
                  wv3[e] * cur[e];
        ov[e] = (short)f2b(a / (1.f + __expf(-a)));
      }
      *(bf16x8*)(ub + ubase + (long)l * 4096) = ov;
#pragma unroll
      for (int e = 0; e < 8; ++e) { w0[e] = w1[e]; w1[e] = w2[e]; w2[e] = cur[e]; }
    }
  } else {
#pragma unroll
    for (int i = 0; i < 8; ++i) {
      int r0 = bm + wr * 128 + i * 16 + lq * 4;
#pragma unroll
      for (int j = 0; j < 4; ++j) {
        int col = bn + wc * 64 + j * 16 + lr;
        f32x4 v = acc[i][j];
#pragma unroll
        for (int r = 0; r < 4; ++r)
          C[(long)(r0 + r) * N + col] = f2b(v[r]);
      }
    }
  }
}

// ========== out_proj: 256^2 coarse structure, split-K=2, bf16 partials ======
__global__ __launch_bounds__(512, 2) void gemm256o_k(
    const u16* __restrict__ Y0,               // y_bf (2, 2048, 4096)
    const u16* __restrict__ W0,               // Wout_bf (2, 2048, 4096)
    u16* __restrict__ part)                   // (4, 2048, 2048) bf16
{
  constexpr int LDK = 4096;
  __shared__ __align__(16) u16 lds[65536];
  u16* As = lds;
  u16* Bs = lds + 32768;
  const int dir = blockIdx.z >> 1, split = blockIdx.z & 1;
  const u16* A = Y0 + (long)dir * 2048 * 4096;
  const u16* B = W0 + (long)dir * 2048 * 4096;
  u16* C = part + (long)blockIdx.z * 4194304;
  const int kbase = split << 11;              // 0 or 2048

  const int tid = threadIdx.x;
  const int wave = tid >> 6, lane = tid & 63;
  const int wr = wave >> 2, wc = wave & 3;
  const int bm = blockIdx.y * 256, bn = blockIdx.x * 256;
  const int lr = lane & 15, lq = lane >> 4;

  f32x4 acc[8][4];
#pragma unroll
  for (int i = 0; i < 8; ++i)
#pragma unroll
    for (int j = 0; j < 4; ++j) acc[i][j] = (f32x4){0.f, 0.f, 0.f, 0.f};

  auto stage = [&](int buf, int kt) {
    int k0 = kbase + (kt << 6);
#pragma unroll
    for (int hf = 0; hf < 2; ++hf)
#pragma unroll
      for (int j = 0; j < 2; ++j) {
        int g = j * 512 + tid;
        int rl = hf * 128 + (g >> 3);
        int gr = (g & 7) ^ ((g >> 3) & 7);
        gload_lds16(A + (long)(bm + rl) * LDK + k0 + gr * 8,
                    &As[buf * 16384 + hf * 8192 + g * 8]);
        gload_lds16(B + (long)(bn + rl) * LDK + k0 + gr * 8,
                    &Bs[buf * 16384 + hf * 8192 + g * 8]);
      }
  };

  const int nk = 32;                          // 2048 / 64
  stage(0, 0);
  for (int kt = 0; kt < nk; ++kt) {
    __builtin_amdgcn_s_barrier();
    __builtin_amdgcn_sched_barrier(0);
    if (kt + 1 < nk) {
      stage((kt + 1) & 1, kt + 1);
      asm volatile("s_waitcnt vmcnt(16)" ::: "memory");
    } else {
      asm volatile("s_waitcnt vmcnt(0)" ::: "memory");
    }
    __builtin_amdgcn_sched_barrier(0);
    __builtin_amdgcn_s_barrier();
    __builtin_amdgcn_sched_barrier(0);
    const int buf = kt & 1;
#pragma unroll
    for (int h = 0; h < 2; ++h) {
      bf16x8 av[8], bv[4];
#pragma unroll
      for (int i = 0; i < 8; ++i) {
        int row = wr * 128 + i * 16 + lr;
        av[i] = *(const bf16x8*)
            &As[buf * 16384 + ((row * 64 + h * 32 + lq * 8) ^ ((row & 7) << 3))];
      }
#pragma unroll
      for (int j = 0; j < 4; ++j) {
        int row = wc * 64 + j * 16 + lr;
        bv[j] = *(const bf16x8*)
            &Bs[buf * 16384 + ((row * 64 + h * 32 + lq * 8) ^ ((row & 7) << 3))];
      }
      __builtin_amdgcn_s_setprio(1);
#pragma unroll
      for (int i = 0; i < 8; ++i)
#pragma unroll
        for (int j = 0; j < 4; ++j)
          acc[i][j] = __builtin_amdgcn_mfma_f32_16x16x32_bf16(
              av[i], bv[j], acc[i][j], 0, 0, 0);
      __builtin_amdgcn_s_setprio(0);
    }
  }

#pragma unroll
  for (int i = 0; i < 8; ++i) {
    int r0 = bm + wr * 128 + i * 16 + lq * 4;
#pragma unroll
    for (int j = 0; j < 4; ++j) {
      int col = bn + wc * 64 + j * 16 + lr;
      f32x4 v = acc[i][j];
#pragma unroll
      for (int r = 0; r < 4; ++r)
        C[(long)(r0 + r) * 2048 + col] = f2b(v[r]);
    }
  }
}

// ---------------- bf16 MFMA GEMM (128x128, m97 structure) ----------------
template <int EPI, int F32OUT, int BFOUT>
__global__ __launch_bounds__(256) void mfma_gemm_k(
    const u16* __restrict__ A0, long aStride,
    const u16* __restrict__ B0, long bStride,
    float* __restrict__ C0, long cStride,
    u16* __restrict__ Cb0, long cbStride,
    const float* __restrict__ bias0, int biasStride,
    int N, int K, int lda, int flipDir1)
{
  __shared__ __align__(16) u16 As[2][4096];
  __shared__ __align__(16) u16 Bs[2][4096];
  const int dir = blockIdx.z;
  const u16* A = A0 + (long)dir * aStride;
  const u16* B = B0 + (long)dir * bStride;
  float* C = F32OUT ? (C0 + (long)dir * cStride) : nullptr;
  u16* Cb = BFOUT ? (Cb0 + (long)dir * cbStride) : nullptr;
  const float* bias = (EPI == 1) ? (bias0 + (long)dir * biasStride) : nullptr;
  const int flip = flipDir1 && (dir == 1);

  const int tid = threadIdx.x;
  const int wave = tid >> 6, lane = tid & 63;
  const int wr = wave >> 1, wc = wave & 1;
  const int bm = blockIdx.y * 128, bn = blockIdx.x * 128;
  const int lr = lane & 15, lq = lane >> 4;

  f32x4 acc[4][4];
#pragma unroll
  for (int i = 0; i < 4; ++i)
#pragma unroll
    for (int j = 0; j < 4; ++j) acc[i][j] = (f32x4){0.f, 0.f, 0.f, 0.f};

  const int nk = K >> 5;

  auto stage = [&](int buf, int k0) {
#pragma unroll
    for (int iss = 0; iss < 2; ++iss) {
      int ob = wave * 2048 + iss * 1024 + lane * 16;
      int row = ob >> 6, kb = (ob >> 4) & 3;
      int rg = bm + row;
      rg = flip ? ((rg & ~255) | (255 - (rg & 255))) : rg;
      gload_lds16(A + (long)rg * lda + k0 + kb * 8,
                  &As[buf][wave * 1024 + iss * 512]);
      int rb = bn + row; rb = (rb < N) ? rb : (N - 1);
      gload_lds16(B + (long)rb * K + k0 + kb * 8,
                  &Bs[buf][wave * 1024 + iss * 512]);
    }
  };

  stage(0, 0);
  for (int kt = 0; kt < nk; ++kt) {
    __syncthreads();
    if (kt + 1 < nk) stage((kt + 1) & 1, (kt + 1) << 5);
    const int buf = kt & 1;
    bf16x8 av[4], bv[4];
#pragma unroll
    for (int i = 0; i < 4; ++i)
      av[i] = *(const bf16x8*)&As[buf][(wr * 64 + i * 16 + lr) * 32 + lq * 8];
#pragma unroll
    for (int j = 0; j < 4; ++j)
      bv[j] = *(const bf16x8*)&Bs[buf][(wc * 64 + j * 16 + lr) * 32 + lq * 8];
#pragma unroll
    for (int i = 0; i < 4; ++i)
#pragma unroll
      for (int j = 0; j < 4; ++j)
        acc[i][j] = __builtin_amdgcn_mfma_f32_16x16x32_bf16(av[i], bv[j],
                                                            acc[i][j], 0, 0, 0);
  }

#pragma unroll
  for (int i = 0; i < 4; ++i) {
    int r0 = bm + wr * 64 + i * 16 + lq * 4;
#pragma unroll
    for (int j = 0; j < 4; ++j) {
      int col = bn + wc * 64 + j * 16 + lr;
      if (col < N) {
        f32x4 v = acc[i][j];
#pragma unroll
        for (int r = 0; r < 4; ++r) {
          float xv = v[r];
          if (EPI == 1) {
            xv += bias[col];
            xv = (xv > 20.f) ? xv : log1pf(expf(xv));
          }
          if (F32OUT) C[(long)(r0 + r) * N + col] = xv;
          if (BFOUT) Cb[(long)(r0 + r) * N + col] = f2b(xv);
        }
      }
    }
  }
}

// ---------------- x_dbl split-K partial GEMM ----------------
__global__ __launch_bounds__(256) void xdbl_part_k(
    const u16* __restrict__ ubf, const u16* __restrict__ Wxbf,
    float* __restrict__ part)
{
  __shared__ __align__(16) u16 As[2][4096];
  __shared__ __align__(16) u16 Bs[2][4096];
  const int dir = blockIdx.z >> 2, split = blockIdx.z & 3;
  const u16* A = ubf + (long)dir * 2048 * 4096;
  const u16* B = Wxbf + (long)dir * 160 * 4096;
  float* C = part + (long)blockIdx.z * 327680;
  const int tid = threadIdx.x;
  const int wave = tid >> 6, lane = tid & 63;
  const int wr = wave >> 1, wc = wave & 1;
  const int bm = blockIdx.y * 128, bn = blockIdx.x * 128;
  const int lr = lane & 15, lq = lane >> 4;

  f32x4 acc[4][4];
#pragma unroll
  for (int i = 0; i < 4; ++i)
#pragma unroll
    for (int j = 0; j < 4; ++j) acc[i][j] = (f32x4){0.f, 0.f, 0.f, 0.f};

  auto stage = [&](int buf, int k0) {
#pragma unroll
    for (int iss = 0; iss < 2; ++iss) {
      int ob = wave * 2048 + iss * 1024 + lane * 16;
      int row = ob >> 6, kb = (ob >> 4) & 3;
      gload_lds16(A + (long)(bm + row) * 4096 + k0 + kb * 8,
                  &As[buf][wave * 1024 + iss * 512]);
      int rb = bn + row; rb = (rb < 160) ? rb : 159;
      gload_lds16(B + (long)rb * 4096 + k0 + kb * 8,
                  &Bs[buf][wave * 1024 + iss * 512]);
    }
  };

  const int kbase = split << 10;
  stage(0, kbase);
  for (int kt = 0; kt < 32; ++kt) {
    __syncthreads();
    if (kt + 1 < 32) stage((kt + 1) & 1, kbase + ((kt + 1) << 5));
    const int buf = kt & 1;
    bf16x8 av[4], bv[4];
#pragma unroll
    for (int i = 0; i < 4; ++i)
      av[i] = *(const bf16x8*)&As[buf][(wr * 64 + i * 16 + lr) * 32 + lq * 8];
#pragma unroll
    for (int j = 0; j < 4; ++j)
      bv[j] = *(const bf16x8*)&Bs[buf][(wc * 64 + j * 16 + lr) * 32 + lq * 8];
#pragma unroll
    for (int i = 0; i < 4; ++i)
#pragma unroll
      for (int j = 0; j < 4; ++j)
        acc[i][j] = __builtin_amdgcn_mfma_f32_16x16x32_bf16(av[i], bv[j],
                                                            acc[i][j], 0, 0, 0);
  }

#pragma unroll
  for (int i = 0; i < 4; ++i) {
    int r0 = bm + wr * 64 + i * 16 + lq * 4;
#pragma unroll
    for (int j = 0; j < 4; ++j) {
      int col = bn + wc * 64 + j * 16 + lr;
      if (col < 160) {
        f32x4 v = acc[i][j];
#pragma unroll
        for (int r = 0; r < 4; ++r)
          C[(long)(r0 + r) * 160 + col] = v[r];
      }
    }
  }
}

// ---------------- x_dbl split-K reduce -> fp32 + bf16 ----------------
__global__ __launch_bounds__(256) void xdbl_reduce_k(
    const float* __restrict__ part, float* __restrict__ xdbl,
    u16* __restrict__ xdbl_bf)
{
  int i = blockIdx.x * 256 + threadIdx.x;
  if (i >= 655360) return;
  int dir = i / 327680, rem = i - dir * 327680;
  long pb = (long)dir * 4 * 327680 + rem;
  float s = part[pb] + part[pb + 327680] + part[pb + 2 * 327680] +
            part[pb + 3 * 327680];
  xdbl[i] = s;
  xdbl_bf[i] = f2b(s);
}

// ---------------- scan pass A: per-chunk local scan (zero init) --------------
__global__ __launch_bounds__(256) void scan_a_k(
    const u16* __restrict__ dtbuf, const u16* __restrict__ ubuf,
    const float* __restrict__ xdbl, const float* __restrict__ A_log,
    const float* __restrict__ Dpv, u16* __restrict__ ypre,
    float* __restrict__ stend, float* __restrict__ dtsum)
{
  int blk = blockIdx.x;
  int dtile = blk & 15, c = (blk >> 4) & 7, b = (blk >> 7) & 7, dir = blk >> 10;
  int tid = threadIdx.x;
  int d = dtile * 256 + tid;
  int db = dir * 8 + b;

  __shared__ float sB[32][16], sC[32][16];
  long r160 = (long)db * 256 * 160;
  for (int i = tid; i < 1024; i += 256) {
    int l = i >> 5, s = i & 31;
    float v = xdbl[r160 + (long)(c * 32 + l) * 160 + 128 + s];
    if (s < 16) sB[l][s] = v; else sC[l][s - 16] = v;
  }
  __syncthreads();

  float A[16], st[16];
  const float4* ap = (const float4*)(A_log + ((long)dir * 4096 + d) * 16);
#pragma unroll
  for (int q = 0; q < 4; ++q) {
    float4 t = ap[q];
    A[q * 4 + 0] = -__expf(t.x); A[q * 4 + 1] = -__expf(t.y);
    A[q * 4 + 2] = -__expf(t.z); A[q * 4 + 3] = -__expf(t.w);
  }
#pragma unroll
  for (int s = 0; s < 16; ++s) st[s] = 0.f;
  float Dpd = Dpv[dir * 4096 + d];

  long base = (long)db * 256 * 4096 + (long)c * 32 * 4096 + d;
  float dts = 0.f;
  for (int i = 0; i < 32; ++i) {
    float dtv = b2f(dtbuf[base + (long)i * 4096]);
    float uv  = b2f(ubuf[base + (long)i * 4096]);
    dts += dtv;
    float du = dtv * uv;
    float y = 0.f;
#pragma unroll
    for (int s = 0; s < 16; ++s) {
      st[s] = st[s] * __expf(dtv * A[s]) + du * sB[i][s];
      y += st[s] * sC[i][s];
    }
    ypre[base + (long)i * 4096] = f2b(y + uv * Dpd);
  }
  long eb = ((long)(db * 8 + c) * 4096 + d) * 16;
  float4* ep = (float4*)(stend + eb);
#pragma unroll
  for (int q = 0; q < 4; ++q)
    ep[q] = make_float4(st[q * 4], st[q * 4 + 1], st[q * 4 + 2], st[q * 4 + 3]);
  dtsum[(long)(db * 8 + c) * 4096 + d] = dts;
}

// ---------------- scan pass B: chunk combine + correction + gating -----------
__global__ __launch_bounds__(512) void scan_b_k(
    const u16* __restrict__ dtbuf, const u16* __restrict__ xzbf,
    const float* __restrict__ xdbl, const float* __restrict__ A_log,
    const float* __restrict__ stend, const float* __restrict__ dtsum,
    u16* __restrict__ ybuf)
{
  int blk = blockIdx.x;
  int dtile = blk & 63, b = (blk >> 6) & 7, dir = blk >> 9;
  int tid = threadIdx.x;
  int c = tid >> 6, dd = tid & 63;
  int d0 = dtile * 64, d = d0 + dd;
  int db = dir * 8 + b;

  __shared__ float sEnd[8][64][17];
  __shared__ float sT[8][64];
  __shared__ float sC[256][16];

  long eBase = (long)db * 8 * 65536;
  for (int i = tid; i < 8192; i += 512) {
    int cc = i >> 10, rem = i & 1023, dd2 = rem >> 4, s = rem & 15;
    sEnd[cc][dd2][s] = stend[eBase + (long)cc * 65536 + (long)(d0 + dd2) * 16 + s];
  }
  {
    int cc = tid >> 6, dd2 = tid & 63;
    sT[cc][dd2] = dtsum[(long)(db * 8 + cc) * 4096 + d0 + dd2];
  }
  long r160 = (long)db * 256 * 160;
  for (int i = tid; i < 4096; i += 512) {
    int l = i >> 4, s = i & 15;
    sC[l][s] = xdbl[r160 + (long)l * 160 + 144 + s];
  }
  __syncthreads();

  float A[16];
  const float4* ap = (const float4*)(A_log + ((long)dir * 4096 + d) * 16);
#pragma unroll
  for (int q = 0; q < 4; ++q) {
    float4 t = ap[q];
    A[q * 4 + 0] = -__expf(t.x); A[q * 4 + 1] = -__expf(t.y);
    A[q * 4 + 2] = -__expf(t.z); A[q * 4 + 3] = -__expf(t.w);
  }
  float g[16];
#pragma unroll
  for (int s = 0; s < 16; ++s) g[s] = 0.f;
  for (int j = 0; j < c; ++j) {
    float Tj = sT[j][dd];
#pragma unroll
    for (int s = 0; s < 16; ++s)
      g[s] = g[s] * __expf(A[s] * Tj) + sEnd[j][dd][s];
  }

  long base  = (long)db * 256 * 4096 + (long)c * 32 * 4096 + d;
  long zbase = (long)db * 256 * 8192 + (long)c * 32 * 8192 + 4096 + d;
  float cum = 0.f;
  if (c == 0) {
    for (int i = 0; i < 32; ++i) {
      float yp = b2f(ybuf[base + (long)i * 4096]);
      float zv = b2f(xzbf[zbase + (long)i * 8192]);
      float y = yp * (zv / (1.f + __expf(-zv)));
      ybuf[base + (long)i * 4096] = f2b(y);
    }
  } else {
    for (int i = 0; i < 32; ++i) {
      float dtv = b2f(dtbuf[base + (long)i * 4096]);
      cum += dtv;
      float yp = b2f(ybuf[base + (long)i * 4096]);
      float corr = 0.f;
      const int l = c * 32 + i;
#pragma unroll
      for (int s = 0; s < 16; ++s)
        corr += sC[l][s] * __expf(A[s] * cum) * g[s];
      float zv = b2f(xzbf[zbase + (long)i * 8192]);
      float y = (yp + corr) * (zv / (1.f + __expf(-zv)));
      ybuf[base + (long)i * 4096] = f2b(y);
    }
  }
}

// ------- residual add (fwd + flipped rev, bf16 partials) + LN -> bf16 -------
__global__ __launch_bounds__(256) void add_ln_k(
    const float* __restrict__ h, const u16* __restrict__ op,
    const float* __restrict__ g, const float* __restrict__ bta,
    u16* __restrict__ h2b)
{
  int row = blockIdx.x;
  int b = row >> 8, l = row & 255;
  long base = (long)row * 2048;
  long base1 = ((long)b * 256 + (255 - l)) * 2048;
  int t8 = threadIdx.x * 8;
  const u16* p0 = op;                       // dir0 split0
  const u16* p1 = op + 4194304;             // dir0 split1
  const u16* p2 = op + 2L * 4194304;        // dir1 split0
  const u16* p3 = op + 3L * 4194304;
  float v[8];
  float4 x0 = *(const float4*)(h + base + t8);
  float4 x1 = *(const float4*)(h + base + t8 + 4);
  bf16x8 a8 = *(const bf16x8*)(p0 + base + t8);
  bf16x8 b8 = *(const bf16x8*)(p1 + base + t8);
  bf16x8 c8v = *(const bf16x8*)(p2 + base1 + t8);
  bf16x8 d8 = *(const bf16x8*)(p3 + base1 + t8);
  const float* xp = (const float*)&x0;
  float xv[8] = {x0.x, x0.y, x0.z, x0.w, x1.x, x1.y, x1.z, x1.w};
  (void)xp;
#pragma unroll
  for (int j = 0; j < 8; ++j)
    v[j] = xv[j] + b2f((u16)a8[j]) + b2f((u16)b8[j]) + b2f((u16)c8v[j]) +
           b2f((u16)d8[j]);
  float s = 0.f, ss = 0.f;
#pragma unroll
  for (int j = 0; j < 8; ++j) { s += v[j]; ss += v[j] * v[j]; }
#pragma unroll
  for (int off = 32; off >= 1; off >>= 1) {
    s += __shfl_xor(s, off, 64);
    ss += __shfl_xor(ss, off, 64);
  }
  __shared__ float red[8];
  int wid = threadIdx.x >> 6, lane = threadIdx.x & 63;
  if (lane == 0) { red[wid] = s; red[wid + 4] = ss; }
  __syncthreads();
  if (threadIdx.x == 0) {
    red[0] = red[0] + red[1] + red[2] + red[3];
    red[4] = red[4] + red[5] + red[6] + red[7];
  }
  __syncthreads();
  float mean = red[0] * (1.f / 2048.f);
  float var = red[4] * (1.f / 2048.f) - mean * mean;
  float inv = rsqrtf(var + 1e-5f);
  bf16x8 o;
#pragma unroll
  for (int j = 0; j < 8; ++j)
    o[j] = (short)f2b((v[j] - mean) * inv * g[t8 + j] + bta[t8 + j]);
  *(bf16x8*)(h2b + base + t8) = o;
}

// ---------------- 31x31 "same" conv via MFMA Toeplitz (bf16 input) ----------
__global__ __launch_bounds__(256) void dec_conv31_k(
    const u16* __restrict__ h2b, const u16* __restrict__ tb,
    float* __restrict__ dc)
{
  __shared__ __align__(16) u16 sIn[94 * 120];
  const int b = blockIdx.z;
  const int l0 = blockIdx.y * 64;
  const int m0 = blockIdx.x * 64;
  const int tid = threadIdx.x;
  const u16* src = h2b + (long)b * 256 * 2048;
  for (int i = tid; i < 94 * 112; i += 256) {
    int r = i / 112, c = i - r * 112;
    int gl = l0 + r - 15, gm = m0 + c - 15;
    u16 v = 0;
    if (gl >= 0 && gl < 256 && gm >= 0 && gm < 2048)
      v = src[(long)gl * 2048 + gm];
    sIn[r * 120 + c] = v;
  }
  __syncthreads();
  const int wave = tid >> 6, lane = tid & 63;
  const int lr = lane & 15, lq = lane >> 4;

  f32x4 acc[4];
#pragma unroll
  for (int s = 0; s < 4; ++s) acc[s] = (f32x4){0.f, 0.f, 0.f, 0.f};

#pragma unroll 1
  for (int ki = 0; ki < 31; ++ki) {
    const u16* arow = &sIn[(wave * 16 + lr + ki) * 120];
#pragma unroll
    for (int h = 0; h < 2; ++h) {
      bf16x8 bv = *(const bf16x8*)&tb[((ki * 2 + h) * 16 + lr) * 32 + lq * 8];
#pragma unroll
      for (int ms = 0; ms < 4; ++ms) {
        bf16x8 av = *(const bf16x8*)&arow[ms * 16 + h * 32 + lq * 8];
        acc[ms] = __builtin_amdgcn_mfma_f32_16x16x32_bf16(av, bv, acc[ms], 0, 0, 0);
      }
    }
  }
#pragma unroll
  for (int ms = 0; ms < 4; ++ms) {
    f32x4 v = acc[ms];
#pragma unroll
    for (int r = 0; r < 4; ++r)
      dc[((long)b * 256 + l0 + wave * 16 + lq * 4 + r) * 2048 + m0 + ms * 16 + lr]
          = v[r];
  }
}

// ---------------- fused transposed conv (stride 2x16) ----------------
__global__ __launch_bounds__(256) void convT_k(
    const float* __restrict__ dc, const float* __restrict__ w,
    const float* __restrict__ wb, float* __restrict__ out)
{
  int j = blockIdx.x, b = blockIdx.y;
  __shared__ float sD[2048];
  __shared__ float sW[2048];
  int tid = threadIdx.x;
  const float* drow = dc + ((long)b * 256 + j) * 2048;
  for (int i = tid; i < 2048; i += 256) { sD[i] = drow[i]; sW[i] = w[i]; }
  __syncthreads();
  float cb = wb[0];
  int owlo = tid & 15, ohbase = tid >> 4;
#pragma unroll
  for (int q = 0; q < 4; ++q) {
    int oh = ohbase + q * 16;
    int i = oh >> 1, a = oh & 1;
    float acc = cb;
#pragma unroll 8
    for (int e = 0; e < 64; ++e)
      acc += sD[e * 32 + i] * sW[e * 32 + a * 16 + owlo];
    out[((long)b * 64 + oh) * 4096 + j * 16 + owlo] = acc;
  }
}

// ---------------- launcher ----------------
extern "C" void kernel_launch(void* const* d_in, const int* in_sizes, int n_in,
                              void* d_out, int out_size, void* d_ws, size_t ws_size,
                              hipStream_t stream)
{
  const float* x      = (const float*)d_in[0];
  const int*   mask   = (const int*)d_in[1];
  const float* proj_w = (const float*)d_in[2];
  const float* proj_b = (const float*)d_in[3];
  const float* pos    = (const float*)d_in[4];
  const float* Wip    = (const float*)d_in[5];   // (1,2,8192,2048)
  const float* convw  = (const float*)d_in[6];
  const float* convb  = (const float*)d_in[7];
  const float* Wx     = (const float*)d_in[8];   // (1,2,160,4096)
  const float* Wdt    = (const float*)d_in[9];   // (1,2,4096,128)
  const float* bdt    = (const float*)d_in[10];
  const float* Alog   = (const float*)d_in[11];
  const float* Dpv    = (const float*)d_in[12];
  const float* Wout   = (const float*)d_in[13];  // (1,2,2048,4096)
  const float* lng    = (const float*)d_in[14];
  const float* lnb    = (const float*)d_in[15];
  const float* dkw    = (const float*)d_in[16];  // (1,1,31,31)
  const float* ctw    = (const float*)d_in[17];
  const float* ctb    = (const float*)d_in[18];
  float* out = (float*)d_out;

  // workspace layout (bytes)
  char* p = (char*)d_ws;
  u16*   xz_bf   = (u16*)p;            // z-half used
  p += 67108864;
  u16*   u_bf    = (u16*)p;            // later dc alias
  float* dc      = (float*)p;
  p += 33554432;
  u16*   dt_bf   = (u16*)p; p += 67108864;     // also out_proj partials later
  float* xdbl    = (float*)p; p += 2621440;
  u16*   xdbl_bf = (u16*)p;  p += 1310720;
  float* h       = (float*)p; p += 16777216;
  u16*   h_bf    = (u16*)p;  p += 8388608;
  float* h2      = (float*)p; p += 16777216;   // used only as dtsum scratch
  u16*   y_bf    = (u16*)p;  p += 33554432;
  u16*   Wpool   = (u16*)p;  p += 67108864;    // Wip_bf; later Wout_bf (1st half)
  u16*   Wx_bf   = (u16*)p;  p += 2621440;
  u16*   Wdt_bf  = (u16*)p;  p += 2097152;
  u16*   tb      = (u16*)p;  p += 65536;       // Toeplitz tiles
  u16*   h2b     = (u16*)p;  p += 8388608;     // LN output, bf16

  // scratch aliases (temporally disjoint):
  float* part    = (float*)(Wpool + 16777216); // x_dbl split-K partials
  float* st_end  = (float*)(Wpool + 16777216); // scan chunk end-states
  float* dtsum   = h2;
  u16*   opart   = dt_bf;                      // out_proj bf16 partials (dt dead)

  // weight converts + Toeplitz expansion
  cvt_bf16_k<<<32768, 256, 0, stream>>>(Wip, Wpool, 8388608);
  cvt_bf16_k<<<1280, 256, 0, stream>>>(Wx, Wx_bf, 327680);
  cvt_bf16_k<<<1024, 256, 0, stream>>>(Wdt, Wdt_bf, 262144);
  toeplitz_k<<<124, 256, 0, stream>>>(dkw, tb);

  // 1) patchify + pos embed
  patchify_k<<<dim3(256, 8), 256, 0, stream>>>(x, mask, proj_w, proj_b, pos, h, h_bf);

  // 2) in_proj + fused conv1d/SiLU epilogue (R16 BK=64 proven)
  gemm256_k<<<dim3(32, 8, 2), 512, 0, stream>>>(
      h_bf, Wpool, (long)8192 * 2048, xz_bf, (long)2048 * 8192,
      convw, convb, u_bf);

  // 3) x_dbl = u @ Wx^T via split-K(4) + reduce (fp32 + bf16 mirror)
  xdbl_part_k<<<dim3(2, 16, 8), 256, 0, stream>>>(u_bf, Wx_bf, part);
  xdbl_reduce_k<<<2560, 256, 0, stream>>>(part, xdbl, xdbl_bf);

  // 4) dt = softplus(x_dbl[:, :128] @ Wdt^T + bdt) -> bf16
  mfma_gemm_k<1, 0, 1><<<dim3(32, 16, 2), 256, 0, stream>>>(
      xdbl_bf, (long)2048 * 160, Wdt_bf, (long)4096 * 128, nullptr, 0L,
      dt_bf, (long)2048 * 4096, bdt, 4096, 4096, 128, 160, 0);

  // 5) chunked selective scan
  scan_a_k<<<2048, 256, 0, stream>>>(dt_bf, u_bf, xdbl, Alog, Dpv, y_bf, st_end, dtsum);
  scan_b_k<<<1024, 512, 0, stream>>>(dt_bf, xz_bf, xdbl, Alog, st_end, dtsum, y_bf);

  // convert Wout into the (now dead) first half of Wpool
  cvt_bf16_k<<<16384, 256, 0, stream>>>(Wout, Wpool, 4194304);

  // 6) out_proj via 256^2 coarse split-K(2): bf16 partials into dead dt region
  gemm256o_k<<<dim3(8, 8, 4), 512, 0, stream>>>(y_bf, Wpool, opart);

  // 7) h2b = LN(h + p0+p1 + flip(p2+p3))  [bf16 partials, bf16 out]
  add_ln_k<<<2048, 256, 0, stream>>>(h, opart, lng, lnb, h2b);

  // 8) 31x31 same conv via MFMA Toeplitz (bf16 in) -> dc [u_bf dead]
  dec_conv31_k<<<dim3(32, 4, 8), 256, 0, stream>>>(h2b, tb, dc);

  // 9) fused transposed conv -> rec
  convT_k<<<dim3(256, 8), 256, 0, stream>>>(dc, ctw, ctb, out);

  // 10) second output: x passthrough
  hipMemcpyAsync(out + 2097152, x, (size_t)2097152 * 4,
                 hipMemcpyDeviceToDevice, stream);
}

// Round 19
// 580.690 us; speedup vs baseline: 3.2190x; 1.0220x over previous
//
#include <hip/hip_runtime.h>
#include <hip/hip_bf16.h>
#include <math.h>

typedef unsigned short u16;
typedef __attribute__((ext_vector_type(8))) short bf16x8;
typedef __attribute__((ext_vector_type(4))) float f32x4;

__device__ __forceinline__ float b2f(u16 v) {
  unsigned u = ((unsigned)v) << 16;
  return __builtin_bit_cast(float, u);
}
__device__ __forceinline__ u16 f2b(float f) {
  unsigned u = __builtin_bit_cast(unsigned, f);
  unsigned r = u + 0x7fffu + ((u >> 16) & 1u);
  return (u16)(r >> 16);
}
__device__ __forceinline__ void gload_lds16(const u16* g, u16* l) {
  __builtin_amdgcn_global_load_lds(
      (const __attribute__((address_space(1))) void*)g,
      (__attribute__((address_space(3))) void*)l, 16, 0, 0);
}

// ---------------- fp32 -> bf16 convert (large weights) ----------------
__global__ __launch_bounds__(256) void cvt_bf16_k(const float* __restrict__ s,
                                                  u16* __restrict__ d, int n4) {
  int i = blockIdx.x * 256 + threadIdx.x;
  if (i < n4) {
    float4 v = ((const float4*)s)[i];
    ushort4 o;
    o.x = f2b(v.x); o.y = f2b(v.y); o.z = f2b(v.z); o.w = f2b(v.w);
    ((ushort4*)d)[i] = o;
  }
}

// ------- merged prep: cvt Wx (327680 f4) + cvt Wdt (262144 f4) + Toeplitz ---
__global__ __launch_bounds__(256) void prep_k(
    const float* __restrict__ Wx, u16* __restrict__ Wxb,
    const float* __restrict__ Wdt, u16* __restrict__ Wdtb,
    const float* __restrict__ kw, u16* __restrict__ tb)
{
  int i = blockIdx.x * 256 + threadIdx.x;
  if (i < 327680) {
    float4 v = ((const float4*)Wx)[i];
    ushort4 o;
    o.x = f2b(v.x); o.y = f2b(v.y); o.z = f2b(v.z); o.w = f2b(v.w);
    ((ushort4*)Wxb)[i] = o;
  } else if (i < 589824) {
    int j = i - 327680;
    float4 v = ((const float4*)Wdt)[j];
    ushort4 o;
    o.x = f2b(v.x); o.y = f2b(v.y); o.z = f2b(v.z); o.w = f2b(v.w);
    ((ushort4*)Wdtb)[j] = o;
  } else {
    int j = i - 589824;
    if (j < 31744) {
      int k = j & 31, n = (j >> 5) & 15, hh = (j >> 9) & 1, ki = j >> 10;
      int t = hh * 32 + k - n;
      float v = (t >= 0 && t <= 30) ? kw[ki * 31 + t] : 0.f;
      tb[j] = f2b(v);
    }
  }
}

// ---------------- patchify + pos embed -> h_bf only ----------------
__global__ __launch_bounds__(256) void patchify_k(
    const float* __restrict__ x, const int* __restrict__ mask,
    const float* __restrict__ pw, const float* __restrict__ pb,
    const float* __restrict__ pos, u16* __restrict__ hb)
{
  int g1 = blockIdx.x, b = blockIdx.y, tid = threadIdx.x;
  __shared__ float sX[64 * 17];
  __shared__ float sW[2048];
  for (int i = tid; i < 64 * 16; i += 256) {
    int r = i >> 4, c = i & 15;
    int gi = (b * 64 + r) * 4096 + g1 * 16 + c;
    sX[r * 17 + c] = mask[gi] ? 0.f : x[gi];
  }
  for (int i = tid; i < 2048; i += 256) sW[i] = pw[i];
  __syncthreads();
  for (int m = tid; m < 2048; m += 256) {
    int e = m >> 5, g0 = m & 31;
    float acc = pb[e];
    const float* w = &sW[e * 32];
#pragma unroll
    for (int kh = 0; kh < 2; ++kh)
#pragma unroll
      for (int kw = 0; kw < 16; ++kw)
        acc += sX[(2 * g0 + kh) * 17 + kw] * w[kh * 16 + kw];
    float v = acc + pos[g1 * 2048 + m];
    hb[((long)b * 256 + g1) * 2048 + m] = f2b(v);
  }
}

// ========== 256x256x(BK=64) 8-wave MFMA GEMM for in_proj, XCD swizzle =======
__global__ __launch_bounds__(512, 2) void gemm256_k(
    const u16* __restrict__ A0,               // h_bf (2048 x 2048)
    const u16* __restrict__ B0, long bStride, // Wip_bf (8192 x 2048) per dir
    u16* __restrict__ C0, long cStride,       // xz_bf (2048 x 8192) per dir
    const float* __restrict__ cw,             // conv weights (2,4096,4)
    const float* __restrict__ cb,             // conv bias (2,4096)
    u16* __restrict__ ub)                     // u_bf (2,8,256,4096)
{
  constexpr int K = 2048, N = 8192, LDA = 2048;
  __shared__ __align__(16) u16 lds[67584];
  u16* As = lds;
  u16* Bs = lds + 32768;
  // XCD swizzle: 512 blocks, bijective (512 % 8 == 0)
  const int lin = (int)(blockIdx.z * 256 + blockIdx.y * 32 + blockIdx.x);
  const int swz = (lin & 7) * 64 + (lin >> 3);
  const int nbx = swz & 31, nby = (swz >> 5) & 7, dir = swz >> 8;
  const u16* A = A0;
  const u16* B = B0 + (long)dir * bStride;
  u16* C = C0 + (long)dir * cStride;
  const int flip = dir;

  const int tid = threadIdx.x;
  const int wave = tid >> 6, lane = tid & 63;
  const int wr = wave >> 2, wc = wave & 3;
  const int bm = nby * 256, bn = nbx * 256;
  const int lr = lane & 15, lq = lane >> 4;

  f32x4 acc[8][4];
#pragma unroll
  for (int i = 0; i < 8; ++i)
#pragma unroll
    for (int j = 0; j < 4; ++j) acc[i][j] = (f32x4){0.f, 0.f, 0.f, 0.f};

  auto stage = [&](int buf, int kt) {
    int k0 = kt << 6;
#pragma unroll
    for (int hf = 0; hf < 2; ++hf)
#pragma unroll
      for (int j = 0; j < 2; ++j) {
        int g = j * 512 + tid;
        int rl = hf * 128 + (g >> 3);
        int gr = (g & 7) ^ ((g >> 3) & 7);
        int ar = flip ? (bm + 255 - rl) : (bm + rl);
        gload_lds16(A + (long)ar * LDA + k0 + gr * 8,
                    &As[buf * 16384 + hf * 8192 + g * 8]);
        gload_lds16(B + (long)(bn + rl) * K + k0 + gr * 8,
                    &Bs[buf * 16384 + hf * 8192 + g * 8]);
      }
  };

  const int nk = K >> 6;
  stage(0, 0);
  for (int kt = 0; kt < nk; ++kt) {
    __builtin_amdgcn_s_barrier();
    __builtin_amdgcn_sched_barrier(0);
    if (kt + 1 < nk) {
      stage((kt + 1) & 1, kt + 1);
      asm volatile("s_waitcnt vmcnt(16)" ::: "memory");
    } else {
      asm volatile("s_waitcnt vmcnt(0)" ::: "memory");
    }
    __builtin_amdgcn_sched_barrier(0);
    __builtin_amdgcn_s_barrier();
    __builtin_amdgcn_sched_barrier(0);
    const int buf = kt & 1;
#pragma unroll
    for (int h = 0; h < 2; ++h) {
      bf16x8 av[8], bv[4];
#pragma unroll
      for (int i = 0; i < 8; ++i) {
        int row = wr * 128 + i * 16 + lr;
        av[i] = *(const bf16x8*)
            &As[buf * 16384 + ((row * 64 + h * 32 + lq * 8) ^ ((row & 7) << 3))];
      }
#pragma unroll
      for (int j = 0; j < 4; ++j) {
        int row = wc * 64 + j * 16 + lr;
        bv[j] = *(const bf16x8*)
            &Bs[buf * 16384 + ((row * 64 + h * 32 + lq * 8) ^ ((row & 7) << 3))];
      }
      __builtin_amdgcn_s_setprio(1);
#pragma unroll
      for (int i = 0; i < 8; ++i)
#pragma unroll
        for (int j = 0; j < 4; ++j)
          acc[i][j] = __builtin_amdgcn_mfma_f32_16x16x32_bf16(
              av[i], bv[j], acc[i][j], 0, 0, 0);
      __builtin_amdgcn_s_setprio(0);
    }
  }

  if (bn < 4096) {
    __syncthreads();
    u16* tile = lds;                 // [256][264] bf16
#pragma unroll
    for (int i = 0; i < 8; ++i) {
      int r0 = wr * 128 + i * 16 + lq * 4;
#pragma unroll
      for (int j = 0; j < 4; ++j) {
        int col = wc * 64 + j * 16 + lr;
        f32x4 v = acc[i][j];
#pragma unroll
        for (int r = 0; r < 4; ++r)
          tile[(r0 + r) * 264 + col] = f2b(v[r]);
      }
    }
    __syncthreads();
    const int rgrp = tid >> 5, c8 = tid & 31;
    const int d0 = bn + c8 * 8;
    float wv0[8], wv1[8], wv2[8], wv3[8], cbv[8];
#pragma unroll
    for (int e = 0; e < 8; ++e) {
      const float4 wq = *(const float4*)(cw + ((long)dir * 4096 + d0 + e) * 4);
      wv0[e] = wq.x; wv1[e] = wq.y; wv2[e] = wq.z; wv3[e] = wq.w;
      cbv[e] = cb[dir * 4096 + d0 + e];
    }
    const int l0 = rgrp * 16;
    float w0[8], w1[8], w2[8];
#pragma unroll
    for (int e = 0; e < 8; ++e) { w0[e] = 0.f; w1[e] = 0.f; w2[e] = 0.f; }
    if (rgrp > 0) {
      bf16x8 t0 = *(const bf16x8*)&tile[(l0 - 3) * 264 + c8 * 8];
      bf16x8 t1 = *(const bf16x8*)&tile[(l0 - 2) * 264 + c8 * 8];
      bf16x8 t2 = *(const bf16x8*)&tile[(l0 - 1) * 264 + c8 * 8];
#pragma unroll
      for (int e = 0; e < 8; ++e) {
        w0[e] = b2f((u16)t0[e]); w1[e] = b2f((u16)t1[e]); w2[e] = b2f((u16)t2[e]);
      }
    }
    long ubase = ((long)(dir * 8 + nby) * 256 + l0) * 4096 + d0;
#pragma unroll
    for (int l = 0; l < 16; ++l) {
      bf16x8 t = *(const bf16x8*)&tile[(l0 + l) * 264 + c8 * 8];
      float cur[8];
#pragma unroll
      for (int e = 0; e < 8; ++e) cur[e] = b2f((u16)t[e]);
      bf16x8 ov;
#pragma unroll
      for (int e = 0; e < 8; ++e) {
        float a = cbv[e] + wv0[e] * w0[e] + wv1[e] * w1[e] + wv2[e] * w2[e] +
                  wv3[e] * cur[e];
        ov[e] = (short)f2b(a / (1.f + __expf(-a)));
      }
      *(bf16x8*)(ub + ubase + (long)l * 4096) = ov;
#pragma unroll
      for (int e = 0; e < 8; ++e) { w0[e] = w1[e]; w1[e] = w2[e]; w2[e] = cur[e]; }
    }
  } else {
#pragma unroll
    for (int i = 0; i < 8; ++i) {
      int r0 = bm + wr * 128 + i * 16 + lq * 4;
#pragma unroll
      for (int j = 0; j < 4; ++j) {
        int col = bn + wc * 64 + j * 16 + lr;
        f32x4 v = acc[i][j];
#pragma unroll
        for (int r = 0; r < 4; ++r)
          C[(long)(r0 + r) * N + col] = f2b(v[r]);
      }
    }
  }
}

// ========== out_proj: 256^2, split-K=2, bf16 partials, XCD swizzle ==========
__global__ __launch_bounds__(512, 2) void gemm256o_k(
    const u16* __restrict__ Y0,               // y_bf (2, 2048, 4096)
    const u16* __restrict__ W0,               // Wout_bf (2, 2048, 4096)
    u16* __restrict__ part)                   // (4, 2048, 2048) bf16
{
  constexpr int LDK = 4096;
  __shared__ __align__(16) u16 lds[65536];
  u16* As = lds;
  u16* Bs = lds + 32768;
  // XCD swizzle: 256 blocks
  const int lin = (int)(blockIdx.z * 64 + blockIdx.y * 8 + blockIdx.x);
  const int swz = (lin & 7) * 32 + (lin >> 3);
  const int nbx = swz & 7, nby = (swz >> 3) & 7, nz = swz >> 6;
  const int dir = nz >> 1, split = nz & 1;
  const u16* A = Y0 + (long)dir * 2048 * 4096;
  const u16* B = W0 + (long)dir * 2048 * 4096;
  u16* C = part + (long)nz * 4194304;
  const int kbase = split << 11;              // 0 or 2048

  const int tid = threadIdx.x;
  const int wave = tid >> 6, lane = tid & 63;
  const int wr = wave >> 2, wc = wave & 3;
  const int bm = nby * 256, bn = nbx * 256;
  const int lr = lane & 15, lq = lane >> 4;

  f32x4 acc[8][4];
#pragma unroll
  for (int i = 0; i < 8; ++i)
#pragma unroll
    for (int j = 0; j < 4; ++j) acc[i][j] = (f32x4){0.f, 0.f, 0.f, 0.f};

  auto stage = [&](int buf, int kt) {
    int k0 = kbase + (kt << 6);
#pragma unroll
    for (int hf = 0; hf < 2; ++hf)
#pragma unroll
      for (int j = 0; j < 2; ++j) {
        int g = j * 512 + tid;
        int rl = hf * 128 + (g >> 3);
        int gr = (g & 7) ^ ((g >> 3) & 7);
        gload_lds16(A + (long)(bm + rl) * LDK + k0 + gr * 8,
                    &As[buf * 16384 + hf * 8192 + g * 8]);
        gload_lds16(B + (long)(bn + rl) * LDK + k0 + gr * 8,
                    &Bs[buf * 16384 + hf * 8192 + g * 8]);
      }
  };

  const int nk = 32;                          // 2048 / 64
  stage(0, 0);
  for (int kt = 0; kt < nk; ++kt) {
    __builtin_amdgcn_s_barrier();
    __builtin_amdgcn_sched_barrier(0);
    if (kt + 1 < nk) {
      stage((kt + 1) & 1, kt + 1);
      asm volatile("s_waitcnt vmcnt(16)" ::: "memory");
    } else {
      asm volatile("s_waitcnt vmcnt(0)" ::: "memory");
    }
    __builtin_amdgcn_sched_barrier(0);
    __builtin_amdgcn_s_barrier();
    __builtin_amdgcn_sched_barrier(0);
    const int buf = kt & 1;
#pragma unroll
    for (int h = 0; h < 2; ++h) {
      bf16x8 av[8], bv[4];
#pragma unroll
      for (int i = 0; i < 8; ++i) {
        int row = wr * 128 + i * 16 + lr;
        av[i] = *(const bf16x8*)
            &As[buf * 16384 + ((row * 64 + h * 32 + lq * 8) ^ ((row & 7) << 3))];
      }
#pragma unroll
      for (int j = 0; j < 4; ++j) {
        int row = wc * 64 + j * 16 + lr;
        bv[j] = *(const bf16x8*)
            &Bs[buf * 16384 + ((row * 64 + h * 32 + lq * 8) ^ ((row & 7) << 3))];
      }
      __builtin_amdgcn_s_setprio(1);
#pragma unroll
      for (int i = 0; i < 8; ++i)
#pragma unroll
        for (int j = 0; j < 4; ++j)
          acc[i][j] = __builtin_amdgcn_mfma_f32_16x16x32_bf16(
              av[i], bv[j], acc[i][j], 0, 0, 0);
      __builtin_amdgcn_s_setprio(0);
    }
  }

#pragma unroll
  for (int i = 0; i < 8; ++i) {
    int r0 = bm + wr * 128 + i * 16 + lq * 4;
#pragma unroll
    for (int j = 0; j < 4; ++j) {
      int col = bn + wc * 64 + j * 16 + lr;
      f32x4 v = acc[i][j];
#pragma unroll
      for (int r = 0; r < 4; ++r)
        C[(long)(r0 + r) * 2048 + col] = f2b(v[r]);
    }
  }
}

// ---------------- bf16 MFMA GEMM (128x128, m97 structure) ----------------
template <int EPI, int F32OUT, int BFOUT>
__global__ __launch_bounds__(256) void mfma_gemm_k(
    const u16* __restrict__ A0, long aStride,
    const u16* __restrict__ B0, long bStride,
    float* __restrict__ C0, long cStride,
    u16* __restrict__ Cb0, long cbStride,
    const float* __restrict__ bias0, int biasStride,
    int N, int K, int lda, int flipDir1)
{
  __shared__ __align__(16) u16 As[2][4096];
  __shared__ __align__(16) u16 Bs[2][4096];
  const int dir = blockIdx.z;
  const u16* A = A0 + (long)dir * aStride;
  const u16* B = B0 + (long)dir * bStride;
  float* C = F32OUT ? (C0 + (long)dir * cStride) : nullptr;
  u16* Cb = BFOUT ? (Cb0 + (long)dir * cbStride) : nullptr;
  const float* bias = (EPI == 1) ? (bias0 + (long)dir * biasStride) : nullptr;
  const int flip = flipDir1 && (dir == 1);

  const int tid = threadIdx.x;
  const int wave = tid >> 6, lane = tid & 63;
  const int wr = wave >> 1, wc = wave & 1;
  const int bm = blockIdx.y * 128, bn = blockIdx.x * 128;
  const int lr = lane & 15, lq = lane >> 4;

  f32x4 acc[4][4];
#pragma unroll
  for (int i = 0; i < 4; ++i)
#pragma unroll
    for (int j = 0; j < 4; ++j) acc[i][j] = (f32x4){0.f, 0.f, 0.f, 0.f};

  const int nk = K >> 5;

  auto stage = [&](int buf, int k0) {
#pragma unroll
    for (int iss = 0; iss < 2; ++iss) {
      int ob = wave * 2048 + iss * 1024 + lane * 16;
      int row = ob >> 6, kb = (ob >> 4) & 3;
      int rg = bm + row;
      rg = flip ? ((rg & ~255) | (255 - (rg & 255))) : rg;
      gload_lds16(A + (long)rg * lda + k0 + kb * 8,
                  &As[buf][wave * 1024 + iss * 512]);
      int rb = bn + row; rb = (rb < N) ? rb : (N - 1);
      gload_lds16(B + (long)rb * K + k0 + kb * 8,
                  &Bs[buf][wave * 1024 + iss * 512]);
    }
  };

  stage(0, 0);
  for (int kt = 0; kt < nk; ++kt) {
    __syncthreads();
    if (kt + 1 < nk) stage((kt + 1) & 1, (kt + 1) << 5);
    const int buf = kt & 1;
    bf16x8 av[4], bv[4];
#pragma unroll
    for (int i = 0; i < 4; ++i)
      av[i] = *(const bf16x8*)&As[buf][(wr * 64 + i * 16 + lr) * 32 + lq * 8];
#pragma unroll
    for (int j = 0; j < 4; ++j)
      bv[j] = *(const bf16x8*)&Bs[buf][(wc * 64 + j * 16 + lr) * 32 + lq * 8];
#pragma unroll
    for (int i = 0; i < 4; ++i)
#pragma unroll
      for (int j = 0; j < 4; ++j)
        acc[i][j] = __builtin_amdgcn_mfma_f32_16x16x32_bf16(av[i], bv[j],
                                                            acc[i][j], 0, 0, 0);
  }

#pragma unroll
  for (int i = 0; i < 4; ++i) {
    int r0 = bm + wr * 64 + i * 16 + lq * 4;
#pragma unroll
    for (int j = 0; j < 4; ++j) {
      int col = bn + wc * 64 + j * 16 + lr;
      if (col < N) {
        f32x4 v = acc[i][j];
#pragma unroll
        for (int r = 0; r < 4; ++r) {
          float xv = v[r];
          if (EPI == 1) {
            xv += bias[col];
            xv = (xv > 20.f) ? xv : log1pf(expf(xv));
          }
          if (F32OUT) C[(long)(r0 + r) * N + col] = xv;
          if (BFOUT) Cb[(long)(r0 + r) * N + col] = f2b(xv);
        }
      }
    }
  }
}

// ---------------- x_dbl split-K partial GEMM ----------------
__global__ __launch_bounds__(256) void xdbl_part_k(
    const u16* __restrict__ ubf, const u16* __restrict__ Wxbf,
    float* __restrict__ part)
{
  __shared__ __align__(16) u16 As[2][4096];
  __shared__ __align__(16) u16 Bs[2][4096];
  const int dir = blockIdx.z >> 2, split = blockIdx.z & 3;
  const u16* A = ubf + (long)dir * 2048 * 4096;
  const u16* B = Wxbf + (long)dir * 160 * 4096;
  float* C = part + (long)blockIdx.z * 327680;
  const int tid = threadIdx.x;
  const int wave = tid >> 6, lane = tid & 63;
  const int wr = wave >> 1, wc = wave & 1;
  const int bm = blockIdx.y * 128, bn = blockIdx.x * 128;
  const int lr = lane & 15, lq = lane >> 4;

  f32x4 acc[4][4];
#pragma unroll
  for (int i = 0; i < 4; ++i)
#pragma unroll
    for (int j = 0; j < 4; ++j) acc[i][j] = (f32x4){0.f, 0.f, 0.f, 0.f};

  auto stage = [&](int buf, int k0) {
#pragma unroll
    for (int iss = 0; iss < 2; ++iss) {
      int ob = wave * 2048 + iss * 1024 + lane * 16;
      int row = ob >> 6, kb = (ob >> 4) & 3;
      gload_lds16(A + (long)(bm + row) * 4096 + k0 + kb * 8,
                  &As[buf][wave * 1024 + iss * 512]);
      int rb = bn + row; rb = (rb < 160) ? rb : 159;
      gload_lds16(B + (long)rb * 4096 + k0 + kb * 8,
                  &Bs[buf][wave * 1024 + iss * 512]);
    }
  };

  const int kbase = split << 10;
  stage(0, kbase);
  for (int kt = 0; kt < 32; ++kt) {
    __syncthreads();
    if (kt + 1 < 32) stage((kt + 1) & 1, kbase + ((kt + 1) << 5));
    const int buf = kt & 1;
    bf16x8 av[4], bv[4];
#pragma unroll
    for (int i = 0; i < 4; ++i)
      av[i] = *(const bf16x8*)&As[buf][(wr * 64 + i * 16 + lr) * 32 + lq * 8];
#pragma unroll
    for (int j = 0; j < 4; ++j)
      bv[j] = *(const bf16x8*)&Bs[buf][(wc * 64 + j * 16 + lr) * 32 + lq * 8];
#pragma unroll
    for (int i = 0; i < 4; ++i)
#pragma unroll
      for (int j = 0; j < 4; ++j)
        acc[i][j] = __builtin_amdgcn_mfma_f32_16x16x32_bf16(av[i], bv[j],
                                                            acc[i][j], 0, 0, 0);
  }

#pragma unroll
  for (int i = 0; i < 4; ++i) {
    int r0 = bm + wr * 64 + i * 16 + lq * 4;
#pragma unroll
    for (int j = 0; j < 4; ++j) {
      int col = bn + wc * 64 + j * 16 + lr;
      if (col < 160) {
        f32x4 v = acc[i][j];
#pragma unroll
        for (int r = 0; r < 4; ++r)
          C[(long)(r0 + r) * 160 + col] = v[r];
      }
    }
  }
}

// ---------------- x_dbl split-K reduce -> fp32 + bf16 ----------------
__global__ __launch_bounds__(256) void xdbl_reduce_k(
    const float* __restrict__ part, float* __restrict__ xdbl,
    u16* __restrict__ xdbl_bf)
{
  int i = blockIdx.x * 256 + threadIdx.x;
  if (i >= 655360) return;
  int dir = i / 327680, rem = i - dir * 327680;
  long pb = (long)dir * 4 * 327680 + rem;
  float s = part[pb] + part[pb + 327680] + part[pb + 2 * 327680] +
            part[pb + 3 * 327680];
  xdbl[i] = s;
  xdbl_bf[i] = f2b(s);
}

// ---------------- scan pass A: per-chunk local scan (zero init) --------------
__global__ __launch_bounds__(256) void scan_a_k(
    const u16* __restrict__ dtbuf, const u16* __restrict__ ubuf,
    const float* __restrict__ xdbl, const float* __restrict__ A_log,
    const float* __restrict__ Dpv, u16* __restrict__ ypre,
    float* __restrict__ stend, float* __restrict__ dtsum)
{
  int blk = blockIdx.x;
  int dtile = blk & 15, c = (blk >> 4) & 7, b = (blk >> 7) & 7, dir = blk >> 10;
  int tid = threadIdx.x;
  int d = dtile * 256 + tid;
  int db = dir * 8 + b;

  __shared__ float sB[32][16], sC[32][16];
  long r160 = (long)db * 256 * 160;
  for (int i = tid; i < 1024; i += 256) {
    int l = i >> 5, s = i & 31;
    float v = xdbl[r160 + (long)(c * 32 + l) * 160 + 128 + s];
    if (s < 16) sB[l][s] = v; else sC[l][s - 16] = v;
  }
  __syncthreads();

  float A[16], st[16];
  const float4* ap = (const float4*)(A_log + ((long)dir * 4096 + d) * 16);
#pragma unroll
  for (int q = 0; q < 4; ++q) {
    float4 t = ap[q];
    A[q * 4 + 0] = -__expf(t.x); A[q * 4 + 1] = -__expf(t.y);
    A[q * 4 + 2] = -__expf(t.z); A[q * 4 + 3] = -__expf(t.w);
  }
#pragma unroll
  for (int s = 0; s < 16; ++s) st[s] = 0.f;
  float Dpd = Dpv[dir * 4096 + d];

  long base = (long)db * 256 * 4096 + (long)c * 32 * 4096 + d;
  float dts = 0.f;
  for (int i = 0; i < 32; ++i) {
    float dtv = b2f(dtbuf[base + (long)i * 4096]);
    float uv  = b2f(ubuf[base + (long)i * 4096]);
    dts += dtv;
    float du = dtv * uv;
    float y = 0.f;
#pragma unroll
    for (int s = 0; s < 16; ++s) {
      st[s] = st[s] * __expf(dtv * A[s]) + du * sB[i][s];
      y += st[s] * sC[i][s];
    }
    ypre[base + (long)i * 4096] = f2b(y + uv * Dpd);
  }
  long eb = ((long)(db * 8 + c) * 4096 + d) * 16;
  float4* ep = (float4*)(stend + eb);
#pragma unroll
  for (int q = 0; q < 4; ++q)
    ep[q] = make_float4(st[q * 4], st[q * 4 + 1], st[q * 4 + 2], st[q * 4 + 3]);
  dtsum[(long)(db * 8 + c) * 4096 + d] = dts;
}

// ---------------- scan pass B: chunk combine + correction + gating -----------
__global__ __launch_bounds__(512) void scan_b_k(
    const u16* __restrict__ dtbuf, const u16* __restrict__ xzbf,
    const float* __restrict__ xdbl, const float* __restrict__ A_log,
    const float* __restrict__ stend, const float* __restrict__ dtsum,
    u16* __restrict__ ybuf)
{
  int blk = blockIdx.x;
  int dtile = blk & 63, b = (blk >> 6) & 7, dir = blk >> 9;
  int tid = threadIdx.x;
  int c = tid >> 6, dd = tid & 63;
  int d0 = dtile * 64, d = d0 + dd;
  int db = dir * 8 + b;

  __shared__ float sEnd[8][64][17];
  __shared__ float sT[8][64];
  __shared__ float sC[256][16];

  long eBase = (long)db * 8 * 65536;
  for (int i = tid; i < 8192; i += 512) {
    int cc = i >> 10, rem = i & 1023, dd2 = rem >> 4, s = rem & 15;
    sEnd[cc][dd2][s] = stend[eBase + (long)cc * 65536 + (long)(d0 + dd2) * 16 + s];
  }
  {
    int cc = tid >> 6, dd2 = tid & 63;
    sT[cc][dd2] = dtsum[(long)(db * 8 + cc) * 4096 + d0 + dd2];
  }
  long r160 = (long)db * 256 * 160;
  for (int i = tid; i < 4096; i += 512) {
    int l = i >> 4, s = i & 15;
    sC[l][s] = xdbl[r160 + (long)l * 160 + 144 + s];
  }
  __syncthreads();

  float A[16];
  const float4* ap = (const float4*)(A_log + ((long)dir * 4096 + d) * 16);
#pragma unroll
  for (int q = 0; q < 4; ++q) {
    float4 t = ap[q];
    A[q * 4 + 0] = -__expf(t.x); A[q * 4 + 1] = -__expf(t.y);
    A[q * 4 + 2] = -__expf(t.z); A[q * 4 + 3] = -__expf(t.w);
  }
  float g[16];
#pragma unroll
  for (int s = 0; s < 16; ++s) g[s] = 0.f;
  for (int j = 0; j < c; ++j) {
    float Tj = sT[j][dd];
#pragma unroll
    for (int s = 0; s < 16; ++s)
      g[s] = g[s] * __expf(A[s] * Tj) + sEnd[j][dd][s];
  }

  long base  = (long)db * 256 * 4096 + (long)c * 32 * 4096 + d;
  long zbase = (long)db * 256 * 8192 + (long)c * 32 * 8192 + 4096 + d;
  float cum = 0.f;
  if (c == 0) {
    for (int i = 0; i < 32; ++i) {
      float yp = b2f(ybuf[base + (long)i * 4096]);
      float zv = b2f(xzbf[zbase + (long)i * 8192]);
      float y = yp * (zv / (1.f + __expf(-zv)));
      ybuf[base + (long)i * 4096] = f2b(y);
    }
  } else {
    for (int i = 0; i < 32; ++i) {
      float dtv = b2f(dtbuf[base + (long)i * 4096]);
      cum += dtv;
      float yp = b2f(ybuf[base + (long)i * 4096]);
      float corr = 0.f;
      const int l = c * 32 + i;
#pragma unroll
      for (int s = 0; s < 16; ++s)
        corr += sC[l][s] * __expf(A[s] * cum) * g[s];
      float zv = b2f(xzbf[zbase + (long)i * 8192]);
      float y = (yp + corr) * (zv / (1.f + __expf(-zv)));
      ybuf[base + (long)i * 4096] = f2b(y);
    }
  }
}

// ------- residual add (bf16 h + bf16 partials) + LN -> bf16 -------
__global__ __launch_bounds__(256) void add_ln_k(
    const u16* __restrict__ hb, const u16* __restrict__ op,
    const float* __restrict__ g, const float* __restrict__ bta,
    u16* __restrict__ h2b)
{
  int row = blockIdx.x;
  int b = row >> 8, l = row & 255;
  long base = (long)row * 2048;
  long base1 = ((long)b * 256 + (255 - l)) * 2048;
  int t8 = threadIdx.x * 8;
  const u16* p0 = op;                       // dir0 split0
  const u16* p1 = op + 4194304;             // dir0 split1
  const u16* p2 = op + 2L * 4194304;        // dir1 split0
  const u16* p3 = op + 3L * 4194304;
  float v[8];
  bf16x8 x8 = *(const bf16x8*)(hb + base + t8);
  bf16x8 a8 = *(const bf16x8*)(p0 + base + t8);
  bf16x8 b8 = *(const bf16x8*)(p1 + base + t8);
  bf16x8 c8v = *(const bf16x8*)(p2 + base1 + t8);
  bf16x8 d8 = *(const bf16x8*)(p3 + base1 + t8);
#pragma unroll
  for (int j = 0; j < 8; ++j)
    v[j] = b2f((u16)x8[j]) + b2f((u16)a8[j]) + b2f((u16)b8[j]) +
           b2f((u16)c8v[j]) + b2f((u16)d8[j]);
  float s = 0.f, ss = 0.f;
#pragma unroll
  for (int j = 0; j < 8; ++j) { s += v[j]; ss += v[j] * v[j]; }
#pragma unroll
  for (int off = 32; off >= 1; off >>= 1) {
    s += __shfl_xor(s, off, 64);
    ss += __shfl_xor(ss, off, 64);
  }
  __shared__ float red[8];
  int wid = threadIdx.x >> 6, lane = threadIdx.x & 63;
  if (lane == 0) { red[wid] = s; red[wid + 4] = ss; }
  __syncthreads();
  if (threadIdx.x == 0) {
    red[0] = red[0] + red[1] + red[2] + red[3];
    red[4] = red[4] + red[5] + red[6] + red[7];
  }
  __syncthreads();
  float mean = red[0] * (1.f / 2048.f);
  float var = red[4] * (1.f / 2048.f) - mean * mean;
  float inv = rsqrtf(var + 1e-5f);
  bf16x8 o;
#pragma unroll
  for (int j = 0; j < 8; ++j)
    o[j] = (short)f2b((v[j] - mean) * inv * g[t8 + j] + bta[t8 + j]);
  *(bf16x8*)(h2b + base + t8) = o;
}

// ---------------- 31x31 "same" conv via MFMA Toeplitz (bf16 in/out) ---------
__global__ __launch_bounds__(256) void dec_conv31_k(
    const u16* __restrict__ h2b, const u16* __restrict__ tb,
    u16* __restrict__ dc)
{
  __shared__ __align__(16) u16 sIn[94 * 120];
  const int b = blockIdx.z;
  const int l0 = blockIdx.y * 64;
  const int m0 = blockIdx.x * 64;
  const int tid = threadIdx.x;
  const u16* src = h2b + (long)b * 256 * 2048;
  for (int i = tid; i < 94 * 112; i += 256) {
    int r = i / 112, c = i - r * 112;
    int gl = l0 + r - 15, gm = m0 + c - 15;
    u16 v = 0;
    if (gl >= 0 && gl < 256 && gm >= 0 && gm < 2048)
      v = src[(long)gl * 2048 + gm];
    sIn[r * 120 + c] = v;
  }
  __syncthreads();
  const int wave = tid >> 6, lane = tid & 63;
  const int lr = lane & 15, lq = lane >> 4;

  f32x4 acc[4];
#pragma unroll
  for (int s = 0; s < 4; ++s) acc[s] = (f32x4){0.f, 0.f, 0.f, 0.f};

#pragma unroll 1
  for (int ki = 0; ki < 31; ++ki) {
    const u16* arow = &sIn[(wave * 16 + lr + ki) * 120];
#pragma unroll
    for (int h = 0; h < 2; ++h) {
      bf16x8 bv = *(const bf16x8*)&tb[((ki * 2 + h) * 16 + lr) * 32 + lq * 8];
#pragma unroll
      for (int ms = 0; ms < 4; ++ms) {
        bf16x8 av = *(const bf16x8*)&arow[ms * 16 + h * 32 + lq * 8];
        acc[ms] = __builtin_amdgcn_mfma_f32_16x16x32_bf16(av, bv, acc[ms], 0, 0, 0);
      }
    }
  }
#pragma unroll
  for (int ms = 0; ms < 4; ++ms) {
    f32x4 v = acc[ms];
#pragma unroll
    for (int r = 0; r < 4; ++r)
      dc[((long)b * 256 + l0 + wave * 16 + lq * 4 + r) * 2048 + m0 + ms * 16 + lr]
          = f2b(v[r]);
  }
}

// ---------------- fused transposed conv (stride 2x16), bf16 input ----------
__global__ __launch_bounds__(256) void convT_k(
    const u16* __restrict__ dc, const float* __restrict__ w,
    const float* __restrict__ wb, float* __restrict__ out)
{
  int j = blockIdx.x, b = blockIdx.y;
  __shared__ float sD[2048];
  __shared__ float sW[2048];
  int tid = threadIdx.x;
  const u16* drow = dc + ((long)b * 256 + j) * 2048;
  for (int i = tid; i < 2048; i += 256) { sD[i] = b2f(drow[i]); sW[i] = w[i]; }
  __syncthreads();
  float cb = wb[0];
  int owlo = tid & 15, ohbase = tid >> 4;
#pragma unroll
  for (int q = 0; q < 4; ++q) {
    int oh = ohbase + q * 16;
    int i = oh >> 1, a = oh & 1;
    float acc = cb;
#pragma unroll 8
    for (int e = 0; e < 64; ++e)
      acc += sD[e * 32 + i] * sW[e * 32 + a * 16 + owlo];
    out[((long)b * 64 + oh) * 4096 + j * 16 + owlo] = acc;
  }
}

// ---------------- launcher ----------------
extern "C" void kernel_launch(void* const* d_in, const int* in_sizes, int n_in,
                              void* d_out, int out_size, void* d_ws, size_t ws_size,
                              hipStream_t stream)
{
  const float* x      = (const float*)d_in[0];
  const int*   mask   = (const int*)d_in[1];
  const float* proj_w = (const float*)d_in[2];
  const float* proj_b = (const float*)d_in[3];
  const float* pos    = (const float*)d_in[4];
  const float* Wip    = (const float*)d_in[5];   // (1,2,8192,2048)
  const float* convw  = (const float*)d_in[6];
  const float* convb  = (const float*)d_in[7];
  const float* Wx     = (const float*)d_in[8];   // (1,2,160,4096)
  const float* Wdt    = (const float*)d_in[9];   // (1,2,4096,128)
  const float* bdt    = (const float*)d_in[10];
  const float* Alog   = (const float*)d_in[11];
  const float* Dpv    = (const float*)d_in[12];
  const float* Wout   = (const float*)d_in[13];  // (1,2,2048,4096)
  const float* lng    = (const float*)d_in[14];
  const float* lnb    = (const float*)d_in[15];
  const float* dkw    = (const float*)d_in[16];  // (1,1,31,31)
  const float* ctw    = (const float*)d_in[17];
  const float* ctb    = (const float*)d_in[18];
  float* out = (float*)d_out;

  // workspace layout (bytes)
  char* p = (char*)d_ws;
  u16*   xz_bf   = (u16*)p;            // z-half used
  p += 67108864;
  u16*   u_bf    = (u16*)p;            // later dc alias (bf16)
  u16*   dc      = (u16*)p;
  p += 33554432;
  u16*   dt_bf   = (u16*)p; p += 67108864;     // also out_proj partials later
  float* xdbl    = (float*)p; p += 2621440;
  u16*   xdbl_bf = (u16*)p;  p += 1310720;
  u16*   h_bf    = (u16*)p;  p += 8388608;
  float* h2      = (float*)p; p += 16777216;   // used only as dtsum scratch
  u16*   y_bf    = (u16*)p;  p += 33554432;
  u16*   Wpool   = (u16*)p;  p += 67108864;    // Wip_bf; later Wout_bf (1st half)
  u16*   Wx_bf   = (u16*)p;  p += 2621440;
  u16*   Wdt_bf  = (u16*)p;  p += 2097152;
  u16*   tb      = (u16*)p;  p += 65536;       // Toeplitz tiles
  u16*   h2b     = (u16*)p;  p += 8388608;     // LN output, bf16

  // scratch aliases (temporally disjoint):
  float* part    = (float*)(Wpool + 16777216); // x_dbl split-K partials
  float* st_end  = (float*)(Wpool + 16777216); // scan chunk end-states
  float* dtsum   = h2;
  u16*   opart   = dt_bf;                      // out_proj bf16 partials (dt dead)

  // weight converts + merged small prep
  cvt_bf16_k<<<32768, 256, 0, stream>>>(Wip, Wpool, 8388608);
  prep_k<<<2428, 256, 0, stream>>>(Wx, Wx_bf, Wdt, Wdt_bf, dkw, tb);

  // 1) patchify + pos embed (bf16 only)
  patchify_k<<<dim3(256, 8), 256, 0, stream>>>(x, mask, proj_w, proj_b, pos, h_bf);

  // 2) in_proj + fused conv1d/SiLU epilogue (XCD swizzle)
  gemm256_k<<<dim3(32, 8, 2), 512, 0, stream>>>(
      h_bf, Wpool, (long)8192 * 2048, xz_bf, (long)2048 * 8192,
      convw, convb, u_bf);

  // 3) x_dbl = u @ Wx^T via split-K(4) + reduce (fp32 + bf16 mirror)
  xdbl_part_k<<<dim3(2, 16, 8), 256, 0, stream>>>(u_bf, Wx_bf, part);
  xdbl_reduce_k<<<2560, 256, 0, stream>>>(part, xdbl, xdbl_bf);

  // 4) dt = softplus(x_dbl[:, :128] @ Wdt^T + bdt) -> bf16
  mfma_gemm_k<1, 0, 1><<<dim3(32, 16, 2), 256, 0, stream>>>(
      xdbl_bf, (long)2048 * 160, Wdt_bf, (long)4096 * 128, nullptr, 0L,
      dt_bf, (long)2048 * 4096, bdt, 4096, 4096, 128, 160, 0);

  // 5) chunked selective scan
  scan_a_k<<<2048, 256, 0, stream>>>(dt_bf, u_bf, xdbl, Alog, Dpv, y_bf, st_end, dtsum);
  scan_b_k<<<1024, 512, 0, stream>>>(dt_bf, xz_bf, xdbl, Alog, st_end, dtsum, y_bf);

  // convert Wout into the (now dead) first half of Wpool
  cvt_bf16_k<<<16384, 256, 0, stream>>>(Wout, Wpool, 4194304);

  // 6) out_proj via 256^2 split-K(2), bf16 partials, XCD swizzle
  gemm256o_k<<<dim3(8, 8, 4), 512, 0, stream>>>(y_bf, Wpool, opart);

  // 7) h2b = LN(h_bf + p0+p1 + flip(p2+p3))
  add_ln_k<<<2048, 256, 0, stream>>>(h_bf, opart, lng, lnb, h2b);

  // 8) 31x31 same conv via MFMA Toeplitz (bf16 in/out) -> dc [u_bf dead]
  dec_conv31_k<<<dim3(32, 4, 8), 256, 0, stream>>>(h2b, tb, dc);

  // 9) fused transposed conv (bf16 in) -> rec
  convT_k<<<dim3(256, 8), 256, 0, stream>>>(dc, ctw, ctb, out);

  // 10) second output: x passthrough
  hipMemcpyAsync(out + 2097152, x, (size_t)2097152 * 4,
                 hipMemcpyDeviceToDevice, stream);
}

// Round 20
// 577.442 us; speedup vs baseline: 3.2371x; 1.0056x over previous
//
#include <hip/hip_runtime.h>
#include <hip/hip_bf16.h>
#include <math.h>

typedef unsigned short u16;
typedef __attribute__((ext_vector_type(8))) short bf16x8;
typedef __attribute__((ext_vector_type(4))) float f32x4;

__device__ __forceinline__ float b2f(u16 v) {
  unsigned u = ((unsigned)v) << 16;
  return __builtin_bit_cast(float, u);
}
__device__ __forceinline__ u16 f2b(float f) {
  unsigned u = __builtin_bit_cast(unsigned, f);
  unsigned r = u + 0x7fffu + ((u >> 16) & 1u);
  return (u16)(r >> 16);
}
__device__ __forceinline__ void gload_lds16(const u16* g, u16* l) {
  __builtin_amdgcn_global_load_lds(
      (const __attribute__((address_space(1))) void*)g,
      (__attribute__((address_space(3))) void*)l, 16, 0, 0);
}

// ---------------- fp32 -> bf16 convert (large weights) ----------------
__global__ __launch_bounds__(256) void cvt_bf16_k(const float* __restrict__ s,
                                                  u16* __restrict__ d, int n4) {
  int i = blockIdx.x * 256 + threadIdx.x;
  if (i < n4) {
    float4 v = ((const float4*)s)[i];
    ushort4 o;
    o.x = f2b(v.x); o.y = f2b(v.y); o.z = f2b(v.z); o.w = f2b(v.w);
    ((ushort4*)d)[i] = o;
  }
}

// ------- merged prep: cvt Wx + cvt Wdt + Toeplitz ---------------------------
__global__ __launch_bounds__(256) void prep_k(
    const float* __restrict__ Wx, u16* __restrict__ Wxb,
    const float* __restrict__ Wdt, u16* __restrict__ Wdtb,
    const float* __restrict__ kw, u16* __restrict__ tb)
{
  int i = blockIdx.x * 256 + threadIdx.x;
  if (i < 327680) {
    float4 v = ((const float4*)Wx)[i];
    ushort4 o;
    o.x = f2b(v.x); o.y = f2b(v.y); o.z = f2b(v.z); o.w = f2b(v.w);
    ((ushort4*)Wxb)[i] = o;
  } else if (i < 589824) {
    int j = i - 327680;
    float4 v = ((const float4*)Wdt)[j];
    ushort4 o;
    o.x = f2b(v.x); o.y = f2b(v.y); o.z = f2b(v.z); o.w = f2b(v.w);
    ((ushort4*)Wdtb)[j] = o;
  } else {
    int j = i - 589824;
    if (j < 31744) {
      int k = j & 31, n = (j >> 5) & 15, hh = (j >> 9) & 1, ki = j >> 10;
      int t = hh * 32 + k - n;
      float v = (t >= 0 && t <= 30) ? kw[ki * 31 + t] : 0.f;
      tb[j] = f2b(v);
    }
  }
}

// ---------------- patchify + pos embed -> h_bf only ----------------
__global__ __launch_bounds__(256) void patchify_k(
    const float* __restrict__ x, const int* __restrict__ mask,
    const float* __restrict__ pw, const float* __restrict__ pb,
    const float* __restrict__ pos, u16* __restrict__ hb)
{
  int g1 = blockIdx.x, b = blockIdx.y, tid = threadIdx.x;
  __shared__ float sX[64 * 17];
  __shared__ float sW[2048];
  for (int i = tid; i < 64 * 16; i += 256) {
    int r = i >> 4, c = i & 15;
    int gi = (b * 64 + r) * 4096 + g1 * 16 + c;
    sX[r * 17 + c] = mask[gi] ? 0.f : x[gi];
  }
  for (int i = tid; i < 2048; i += 256) sW[i] = pw[i];
  __syncthreads();
  for (int m = tid; m < 2048; m += 256) {
    int e = m >> 5, g0 = m & 31;
    float acc = pb[e];
    const float* w = &sW[e * 32];
#pragma unroll
    for (int kh = 0; kh < 2; ++kh)
#pragma unroll
      for (int kw = 0; kw < 16; ++kw)
        acc += sX[(2 * g0 + kh) * 17 + kw] * w[kh * 16 + kw];
    float v = acc + pos[g1 * 2048 + m];
    hb[((long)b * 256 + g1) * 2048 + m] = f2b(v);
  }
}

// ========== 256x256x(BK=64) 8-wave MFMA GEMM for in_proj, XCD swizzle =======
__global__ __launch_bounds__(512, 2) void gemm256_k(
    const u16* __restrict__ A0,               // h_bf (2048 x 2048)
    const u16* __restrict__ B0, long bStride, // Wip_bf (8192 x 2048) per dir
    u16* __restrict__ C0, long cStride,       // xz_bf (2048 x 8192) per dir
    const float* __restrict__ cw,             // conv weights (2,4096,4)
    const float* __restrict__ cb,             // conv bias (2,4096)
    u16* __restrict__ ub)                     // u_bf (2,8,256,4096)
{
  constexpr int K = 2048, N = 8192, LDA = 2048;
  __shared__ __align__(16) u16 lds[67584];
  u16* As = lds;
  u16* Bs = lds + 32768;
  const int lin = (int)(blockIdx.z * 256 + blockIdx.y * 32 + blockIdx.x);
  const int swz = (lin & 7) * 64 + (lin >> 3);
  const int nbx = swz & 31, nby = (swz >> 5) & 7, dir = swz >> 8;
  const u16* A = A0;
  const u16* B = B0 + (long)dir * bStride;
  u16* C = C0 + (long)dir * cStride;
  const int flip = dir;

  const int tid = threadIdx.x;
  const int wave = tid >> 6, lane = tid & 63;
  const int wr = wave >> 2, wc = wave & 3;
  const int bm = nby * 256, bn = nbx * 256;
  const int lr = lane & 15, lq = lane >> 4;

  f32x4 acc[8][4];
#pragma unroll
  for (int i = 0; i < 8; ++i)
#pragma unroll
    for (int j = 0; j < 4; ++j) acc[i][j] = (f32x4){0.f, 0.f, 0.f, 0.f};

  auto stage = [&](int buf, int kt) {
    int k0 = kt << 6;
#pragma unroll
    for (int hf = 0; hf < 2; ++hf)
#pragma unroll
      for (int j = 0; j < 2; ++j) {
        int g = j * 512 + tid;
        int rl = hf * 128 + (g >> 3);
        int gr = (g & 7) ^ ((g >> 3) & 7);
        int ar = flip ? (bm + 255 - rl) : (bm + rl);
        gload_lds16(A + (long)ar * LDA + k0 + gr * 8,
                    &As[buf * 16384 + hf * 8192 + g * 8]);
        gload_lds16(B + (long)(bn + rl) * K + k0 + gr * 8,
                    &Bs[buf * 16384 + hf * 8192 + g * 8]);
      }
  };

  const int nk = K >> 6;
  stage(0, 0);
  for (int kt = 0; kt < nk; ++kt) {
    __builtin_amdgcn_s_barrier();
    __builtin_amdgcn_sched_barrier(0);
    if (kt + 1 < nk) {
      stage((kt + 1) & 1, kt + 1);
      asm volatile("s_waitcnt vmcnt(16)" ::: "memory");
    } else {
      asm volatile("s_waitcnt vmcnt(0)" ::: "memory");
    }
    __builtin_amdgcn_sched_barrier(0);
    __builtin_amdgcn_s_barrier();
    __builtin_amdgcn_sched_barrier(0);
    const int buf = kt & 1;
#pragma unroll
    for (int h = 0; h < 2; ++h) {
      bf16x8 av[8], bv[4];
#pragma unroll
      for (int i = 0; i < 8; ++i) {
        int row = wr * 128 + i * 16 + lr;
        av[i] = *(const bf16x8*)
            &As[buf * 16384 + ((row * 64 + h * 32 + lq * 8) ^ ((row & 7) << 3))];
      }
#pragma unroll
      for (int j = 0; j < 4; ++j) {
        int row = wc * 64 + j * 16 + lr;
        bv[j] = *(const bf16x8*)
            &Bs[buf * 16384 + ((row * 64 + h * 32 + lq * 8) ^ ((row & 7) << 3))];
      }
      __builtin_amdgcn_s_setprio(1);
#pragma unroll
      for (int i = 0; i < 8; ++i)
#pragma unroll
        for (int j = 0; j < 4; ++j)
          acc[i][j] = __builtin_amdgcn_mfma_f32_16x16x32_bf16(
              av[i], bv[j], acc[i][j], 0, 0, 0);
      __builtin_amdgcn_s_setprio(0);
    }
  }

  if (bn < 4096) {
    __syncthreads();
    u16* tile = lds;                 // [256][264] bf16
#pragma unroll
    for (int i = 0; i < 8; ++i) {
      int r0 = wr * 128 + i * 16 + lq * 4;
#pragma unroll
      for (int j = 0; j < 4; ++j) {
        int col = wc * 64 + j * 16 + lr;
        f32x4 v = acc[i][j];
#pragma unroll
        for (int r = 0; r < 4; ++r)
          tile[(r0 + r) * 264 + col] = f2b(v[r]);
      }
    }
    __syncthreads();
    const int rgrp = tid >> 5, c8 = tid & 31;
    const int d0 = bn + c8 * 8;
    float wv0[8], wv1[8], wv2[8], wv3[8], cbv[8];
#pragma unroll
    for (int e = 0; e < 8; ++e) {
      const float4 wq = *(const float4*)(cw + ((long)dir * 4096 + d0 + e) * 4);
      wv0[e] = wq.x; wv1[e] = wq.y; wv2[e] = wq.z; wv3[e] = wq.w;
      cbv[e] = cb[dir * 4096 + d0 + e];
    }
    const int l0 = rgrp * 16;
    float w0[8], w1[8], w2[8];
#pragma unroll
    for (int e = 0; e < 8; ++e) { w0[e] = 0.f; w1[e] = 0.f; w2[e] = 0.f; }
    if (rgrp > 0) {
      bf16x8 t0 = *(const bf16x8*)&tile[(l0 - 3) * 264 + c8 * 8];
      bf16x8 t1 = *(const bf16x8*)&tile[(l0 - 2) * 264 + c8 * 8];
      bf16x8 t2 = *(const bf16x8*)&tile[(l0 - 1) * 264 + c8 * 8];
#pragma unroll
      for (int e = 0; e < 8; ++e) {
        w0[e] = b2f((u16)t0[e]); w1[e] = b2f((u16)t1[e]); w2[e] = b2f((u16)t2[e]);
      }
    }
    long ubase = ((long)(dir * 8 + nby) * 256 + l0) * 4096 + d0;
#pragma unroll
    for (int l = 0; l < 16; ++l) {
      bf16x8 t = *(const bf16x8*)&tile[(l0 + l) * 264 + c8 * 8];
      float cur[8];
#pragma unroll
      for (int e = 0; e < 8; ++e) cur[e] = b2f((u16)t[e]);
      bf16x8 ov;
#pragma unroll
      for (int e = 0; e < 8; ++e) {
        float a = cbv[e] + wv0[e] * w0[e] + wv1[e] * w1[e] + wv2[e] * w2[e] +
                  wv3[e] * cur[e];
        ov[e] = (short)f2b(a / (1.f + __expf(-a)));
      }
      *(bf16x8*)(ub + ubase + (long)l * 4096) = ov;
#pragma unroll
      for (int e = 0; e < 8; ++e) { w0[e] = w1[e]; w1[e] = w2[e]; w2[e] = cur[e]; }
    }
  } else {
#pragma unroll
    for (int i = 0; i < 8; ++i) {
      int r0 = bm + wr * 128 + i * 16 + lq * 4;
#pragma unroll
      for (int j = 0; j < 4; ++j) {
        int col = bn + wc * 64 + j * 16 + lr;
        f32x4 v = acc[i][j];
#pragma unroll
        for (int r = 0; r < 4; ++r)
          C[(long)(r0 + r) * N + col] = f2b(v[r]);
      }
    }
  }
}

// ========== out_proj: 256^2, split-K=2, bf16 partials, XCD swizzle ==========
__global__ __launch_bounds__(512, 2) void gemm256o_k(
    const u16* __restrict__ Y0,               // y_bf (2, 2048, 4096)
    const u16* __restrict__ W0,               // Wout_bf (2, 2048, 4096)
    u16* __restrict__ part)                   // (4, 2048, 2048) bf16
{
  constexpr int LDK = 4096;
  __shared__ __align__(16) u16 lds[65536];
  u16* As = lds;
  u16* Bs = lds + 32768;
  const int lin = (int)(blockIdx.z * 64 + blockIdx.y * 8 + blockIdx.x);
  const int swz = (lin & 7) * 32 + (lin >> 3);
  const int nbx = swz & 7, nby = (swz >> 3) & 7, nz = swz >> 6;
  const int dir = nz >> 1, split = nz & 1;
  const u16* A = Y0 + (long)dir * 2048 * 4096;
  const u16* B = W0 + (long)dir * 2048 * 4096;
  u16* C = part + (long)nz * 4194304;
  const int kbase = split << 11;

  const int tid = threadIdx.x;
  const int wave = tid >> 6, lane = tid & 63;
  const int wr = wave >> 2, wc = wave & 3;
  const int bm = nby * 256, bn = nbx * 256;
  const int lr = lane & 15, lq = lane >> 4;

  f32x4 acc[8][4];
#pragma unroll
  for (int i = 0; i < 8; ++i)
#pragma unroll
    for (int j = 0; j < 4; ++j) acc[i][j] = (f32x4){0.f, 0.f, 0.f, 0.f};

  auto stage = [&](int buf, int kt) {
    int k0 = kbase + (kt << 6);
#pragma unroll
    for (int hf = 0; hf < 2; ++hf)
#pragma unroll
      for (int j = 0; j < 2; ++j) {
        int g = j * 512 + tid;
        int rl = hf * 128 + (g >> 3);
        int gr = (g & 7) ^ ((g >> 3) & 7);
        gload_lds16(A + (long)(bm + rl) * LDK + k0 + gr * 8,
                    &As[buf * 16384 + hf * 8192 + g * 8]);
        gload_lds16(B + (long)(bn + rl) * LDK + k0 + gr * 8,
                    &Bs[buf * 16384 + hf * 8192 + g * 8]);
      }
  };

  const int nk = 32;
  stage(0, 0);
  for (int kt = 0; kt < nk; ++kt) {
    __builtin_amdgcn_s_barrier();
    __builtin_amdgcn_sched_barrier(0);
    if (kt + 1 < nk) {
      stage((kt + 1) & 1, kt + 1);
      asm volatile("s_waitcnt vmcnt(16)" ::: "memory");
    } else {
      asm volatile("s_waitcnt vmcnt(0)" ::: "memory");
    }
    __builtin_amdgcn_sched_barrier(0);
    __builtin_amdgcn_s_barrier();
    __builtin_amdgcn_sched_barrier(0);
    const int buf = kt & 1;
#pragma unroll
    for (int h = 0; h < 2; ++h) {
      bf16x8 av[8], bv[4];
#pragma unroll
      for (int i = 0; i < 8; ++i) {
        int row = wr * 128 + i * 16 + lr;
        av[i] = *(const bf16x8*)
            &As[buf * 16384 + ((row * 64 + h * 32 + lq * 8) ^ ((row & 7) << 3))];
      }
#pragma unroll
      for (int j = 0; j < 4; ++j) {
        int row = wc * 64 + j * 16 + lr;
        bv[j] = *(const bf16x8*)
            &Bs[buf * 16384 + ((row * 64 + h * 32 + lq * 8) ^ ((row & 7) << 3))];
      }
      __builtin_amdgcn_s_setprio(1);
#pragma unroll
      for (int i = 0; i < 8; ++i)
#pragma unroll
        for (int j = 0; j < 4; ++j)
          acc[i][j] = __builtin_amdgcn_mfma_f32_16x16x32_bf16(
              av[i], bv[j], acc[i][j], 0, 0, 0);
      __builtin_amdgcn_s_setprio(0);
    }
  }

#pragma unroll
  for (int i = 0; i < 8; ++i) {
    int r0 = bm + wr * 128 + i * 16 + lq * 4;
#pragma unroll
    for (int j = 0; j < 4; ++j) {
      int col = bn + wc * 64 + j * 16 + lr;
      f32x4 v = acc[i][j];
#pragma unroll
      for (int r = 0; r < 4; ++r)
        C[(long)(r0 + r) * 2048 + col] = f2b(v[r]);
    }
  }
}

// ---------------- bf16 MFMA GEMM (128x128, m97 structure) ----------------
template <int EPI, int F32OUT, int BFOUT>
__global__ __launch_bounds__(256) void mfma_gemm_k(
    const u16* __restrict__ A0, long aStride,
    const u16* __restrict__ B0, long bStride,
    float* __restrict__ C0, long cStride,
    u16* __restrict__ Cb0, long cbStride,
    const float* __restrict__ bias0, int biasStride,
    int N, int K, int lda, int flipDir1)
{
  __shared__ __align__(16) u16 As[2][4096];
  __shared__ __align__(16) u16 Bs[2][4096];
  const int dir = blockIdx.z;
  const u16* A = A0 + (long)dir * aStride;
  const u16* B = B0 + (long)dir * bStride;
  float* C = F32OUT ? (C0 + (long)dir * cStride) : nullptr;
  u16* Cb = BFOUT ? (Cb0 + (long)dir * cbStride) : nullptr;
  const float* bias = (EPI == 1) ? (bias0 + (long)dir * biasStride) : nullptr;
  const int flip = flipDir1 && (dir == 1);

  const int tid = threadIdx.x;
  const int wave = tid >> 6, lane = tid & 63;
  const int wr = wave >> 1, wc = wave & 1;
  const int bm = blockIdx.y * 128, bn = blockIdx.x * 128;
  const int lr = lane & 15, lq = lane >> 4;

  f32x4 acc[4][4];
#pragma unroll
  for (int i = 0; i < 4; ++i)
#pragma unroll
    for (int j = 0; j < 4; ++j) acc[i][j] = (f32x4){0.f, 0.f, 0.f, 0.f};

  const int nk = K >> 5;

  auto stage = [&](int buf, int k0) {
#pragma unroll
    for (int iss = 0; iss < 2; ++iss) {
      int ob = wave * 2048 + iss * 1024 + lane * 16;
      int row = ob >> 6, kb = (ob >> 4) & 3;
      int rg = bm + row;
      rg = flip ? ((rg & ~255) | (255 - (rg & 255))) : rg;
      gload_lds16(A + (long)rg * lda + k0 + kb * 8,
                  &As[buf][wave * 1024 + iss * 512]);
      int rb = bn + row; rb = (rb < N) ? rb : (N - 1);
      gload_lds16(B + (long)rb * K + k0 + kb * 8,
                  &Bs[buf][wave * 1024 + iss * 512]);
    }
  };

  stage(0, 0);
  for (int kt = 0; kt < nk; ++kt) {
    __syncthreads();
    if (kt + 1 < nk) stage((kt + 1) & 1, (kt + 1) << 5);
    const int buf = kt & 1;
    bf16x8 av[4], bv[4];
#pragma unroll
    for (int i = 0; i < 4; ++i)
      av[i] = *(const bf16x8*)&As[buf][(wr * 64 + i * 16 + lr) * 32 + lq * 8];
#pragma unroll
    for (int j = 0; j < 4; ++j)
      bv[j] = *(const bf16x8*)&Bs[buf][(wc * 64 + j * 16 + lr) * 32 + lq * 8];
#pragma unroll
    for (int i = 0; i < 4; ++i)
#pragma unroll
      for (int j = 0; j < 4; ++j)
        acc[i][j] = __builtin_amdgcn_mfma_f32_16x16x32_bf16(av[i], bv[j],
                                                            acc[i][j], 0, 0, 0);
  }

#pragma unroll
  for (int i = 0; i < 4; ++i) {
    int r0 = bm + wr * 64 + i * 16 + lq * 4;
#pragma unroll
    for (int j = 0; j < 4; ++j) {
      int col = bn + wc * 64 + j * 16 + lr;
      if (col < N) {
        f32x4 v = acc[i][j];
#pragma unroll
        for (int r = 0; r < 4; ++r) {
          float xv = v[r];
          if (EPI == 1) {
            xv += bias[col];
            xv = (xv > 20.f) ? xv : log1pf(expf(xv));
          }
          if (F32OUT) C[(long)(r0 + r) * N + col] = xv;
          if (BFOUT) Cb[(long)(r0 + r) * N + col] = f2b(xv);
        }
      }
    }
  }
}

// ---------------- x_dbl split-K partial GEMM ----------------
__global__ __launch_bounds__(256) void xdbl_part_k(
    const u16* __restrict__ ubf, const u16* __restrict__ Wxbf,
    float* __restrict__ part)
{
  __shared__ __align__(16) u16 As[2][4096];
  __shared__ __align__(16) u16 Bs[2][4096];
  const int dir = blockIdx.z >> 2, split = blockIdx.z & 3;
  const u16* A = ubf + (long)dir * 2048 * 4096;
  const u16* B = Wxbf + (long)dir * 160 * 4096;
  float* C = part + (long)blockIdx.z * 327680;
  const int tid = threadIdx.x;
  const int wave = tid >> 6, lane = tid & 63;
  const int wr = wave >> 1, wc = wave & 1;
  const int bm = blockIdx.y * 128, bn = blockIdx.x * 128;
  const int lr = lane & 15, lq = lane >> 4;

  f32x4 acc[4][4];
#pragma unroll
  for (int i = 0; i < 4; ++i)
#pragma unroll
    for (int j = 0; j < 4; ++j) acc[i][j] = (f32x4){0.f, 0.f, 0.f, 0.f};

  auto stage = [&](int buf, int k0) {
#pragma unroll
    for (int iss = 0; iss < 2; ++iss) {
      int ob = wave * 2048 + iss * 1024 + lane * 16;
      int row = ob >> 6, kb = (ob >> 4) & 3;
      gload_lds16(A + (long)(bm + row) * 4096 + k0 + kb * 8,
                  &As[buf][wave * 1024 + iss * 512]);
      int rb = bn + row; rb = (rb < 160) ? rb : 159;
      gload_lds16(B + (long)rb * 4096 + k0 + kb * 8,
                  &Bs[buf][wave * 1024 + iss * 512]);
    }
  };

  const int kbase = split << 10;
  stage(0, kbase);
  for (int kt = 0; kt < 32; ++kt) {
    __syncthreads();
    if (kt + 1 < 32) stage((kt + 1) & 1, kbase + ((kt + 1) << 5));
    const int buf = kt & 1;
    bf16x8 av[4], bv[4];
#pragma unroll
    for (int i = 0; i < 4; ++i)
      av[i] = *(const bf16x8*)&As[buf][(wr * 64 + i * 16 + lr) * 32 + lq * 8];
#pragma unroll
    for (int j = 0; j < 4; ++j)
      bv[j] = *(const bf16x8*)&Bs[buf][(wc * 64 + j * 16 + lr) * 32 + lq * 8];
#pragma unroll
    for (int i = 0; i < 4; ++i)
#pragma unroll
      for (int j = 0; j < 4; ++j)
        acc[i][j] = __builtin_amdgcn_mfma_f32_16x16x32_bf16(av[i], bv[j],
                                                            acc[i][j], 0, 0, 0);
  }

#pragma unroll
  for (int i = 0; i < 4; ++i) {
    int r0 = bm + wr * 64 + i * 16 + lq * 4;
#pragma unroll
    for (int j = 0; j < 4; ++j) {
      int col = bn + wc * 64 + j * 16 + lr;
      if (col < 160) {
        f32x4 v = acc[i][j];
#pragma unroll
        for (int r = 0; r < 4; ++r)
          C[(long)(r0 + r) * 160 + col] = v[r];
      }
    }
  }
}

// ---------------- x_dbl split-K reduce -> fp32 + bf16 ----------------
__global__ __launch_bounds__(256) void xdbl_reduce_k(
    const float* __restrict__ part, float* __restrict__ xdbl,
    u16* __restrict__ xdbl_bf)
{
  int i = blockIdx.x * 256 + threadIdx.x;
  if (i >= 655360) return;
  int dir = i / 327680, rem = i - dir * 327680;
  long pb = (long)dir * 4 * 327680 + rem;
  float s = part[pb] + part[pb + 327680] + part[pb + 2 * 327680] +
            part[pb + 3 * 327680];
  xdbl[i] = s;
  xdbl_bf[i] = f2b(s);
}

// ---------------- scan pass A: per-chunk local scan (bf16 end-states) -------
__global__ __launch_bounds__(256) void scan_a_k(
    const u16* __restrict__ dtbuf, const u16* __restrict__ ubuf,
    const float* __restrict__ xdbl, const float* __restrict__ A_log,
    const float* __restrict__ Dpv, u16* __restrict__ ypre,
    u16* __restrict__ stend, float* __restrict__ dtsum)
{
  int blk = blockIdx.x;
  int dtile = blk & 15, c = (blk >> 4) & 7, b = (blk >> 7) & 7, dir = blk >> 10;
  int tid = threadIdx.x;
  int d = dtile * 256 + tid;
  int db = dir * 8 + b;

  __shared__ float sB[32][16], sC[32][16];
  long r160 = (long)db * 256 * 160;
  for (int i = tid; i < 1024; i += 256) {
    int l = i >> 5, s = i & 31;
    float v = xdbl[r160 + (long)(c * 32 + l) * 160 + 128 + s];
    if (s < 16) sB[l][s] = v; else sC[l][s - 16] = v;
  }
  __syncthreads();

  float A[16], st[16];
  const float4* ap = (const float4*)(A_log + ((long)dir * 4096 + d) * 16);
#pragma unroll
  for (int q = 0; q < 4; ++q) {
    float4 t = ap[q];
    A[q * 4 + 0] = -__expf(t.x); A[q * 4 + 1] = -__expf(t.y);
    A[q * 4 + 2] = -__expf(t.z); A[q * 4 + 3] = -__expf(t.w);
  }
#pragma unroll
  for (int s = 0; s < 16; ++s) st[s] = 0.f;
  float Dpd = Dpv[dir * 4096 + d];

  long base = (long)db * 256 * 4096 + (long)c * 32 * 4096 + d;
  float dts = 0.f;
  for (int i = 0; i < 32; ++i) {
    float dtv = b2f(dtbuf[base + (long)i * 4096]);
    float uv  = b2f(ubuf[base + (long)i * 4096]);
    dts += dtv;
    float du = dtv * uv;
    float y = 0.f;
#pragma unroll
    for (int s = 0; s < 16; ++s) {
      st[s] = st[s] * __expf(dtv * A[s]) + du * sB[i][s];
      y += st[s] * sC[i][s];
    }
    ypre[base + (long)i * 4096] = f2b(y + uv * Dpd);
  }
  long eb = ((long)(db * 8 + c) * 4096 + d) * 16;
  bf16x8 e0, e1;
#pragma unroll
  for (int s = 0; s < 8; ++s) { e0[s] = (short)f2b(st[s]); e1[s] = (short)f2b(st[8 + s]); }
  *(bf16x8*)(stend + eb) = e0;
  *(bf16x8*)(stend + eb + 8) = e1;
  dtsum[(long)(db * 8 + c) * 4096 + d] = dts;
}

// ---------------- scan pass B: chunk combine + correction + gating -----------
__global__ __launch_bounds__(512) void scan_b_k(
    const u16* __restrict__ dtbuf, const u16* __restrict__ xzbf,
    const float* __restrict__ xdbl, const float* __restrict__ A_log,
    const u16* __restrict__ stend, const float* __restrict__ dtsum,
    u16* __restrict__ ybuf)
{
  int blk = blockIdx.x;
  int dtile = blk & 63, b = (blk >> 6) & 7, dir = blk >> 9;
  int tid = threadIdx.x;
  int c = tid >> 6, dd = tid & 63;
  int d0 = dtile * 64, d = d0 + dd;
  int db = dir * 8 + b;

  __shared__ float sEnd[8][64][17];
  __shared__ float sT[8][64];
  __shared__ float sC[256][16];

  long eBase = (long)db * 8 * 65536;
  for (int i = tid; i < 8192; i += 512) {
    int cc = i >> 10, rem = i & 1023, dd2 = rem >> 4, s = rem & 15;
    sEnd[cc][dd2][s] =
        b2f(stend[eBase + (long)cc * 65536 + (long)(d0 + dd2) * 16 + s]);
  }
  {
    int cc = tid >> 6, dd2 = tid & 63;
    sT[cc][dd2] = dtsum[(long)(db * 8 + cc) * 4096 + d0 + dd2];
  }
  long r160 = (long)db * 256 * 160;
  for (int i = tid; i < 4096; i += 512) {
    int l = i >> 4, s = i & 15;
    sC[l][s] = xdbl[r160 + (long)l * 160 + 144 + s];
  }
  __syncthreads();

  float A[16];
  const float4* ap = (const float4*)(A_log + ((long)dir * 4096 + d) * 16);
#pragma unroll
  for (int q = 0; q < 4; ++q) {
    float4 t = ap[q];
    A[q * 4 + 0] = -__expf(t.x); A[q * 4 + 1] = -__expf(t.y);
    A[q * 4 + 2] = -__expf(t.z); A[q * 4 + 3] = -__expf(t.w);
  }
  float g[16];
#pragma unroll
  for (int s = 0; s < 16; ++s) g[s] = 0.f;
  for (int j = 0; j < c; ++j) {
    float Tj = sT[j][dd];
#pragma unroll
    for (int s = 0; s < 16; ++s)
      g[s] = g[s] * __expf(A[s] * Tj) + sEnd[j][dd][s];
  }

  long base  = (long)db * 256 * 4096 + (long)c * 32 * 4096 + d;
  long zbase = (long)db * 256 * 8192 + (long)c * 32 * 8192 + 4096 + d;
  float cum = 0.f;
  if (c == 0) {
    for (int i = 0; i < 32; ++i) {
      float yp = b2f(ybuf[base + (long)i * 4096]);
      float zv = b2f(xzbf[zbase + (long)i * 8192]);
      float y = yp * (zv / (1.f + __expf(-zv)));
      ybuf[base + (long)i * 4096] = f2b(y);
    }
  } else {
    for (int i = 0; i < 32; ++i) {
      float dtv = b2f(dtbuf[base + (long)i * 4096]);
      cum += dtv;
      float yp = b2f(ybuf[base + (long)i * 4096]);
      float corr = 0.f;
      const int l = c * 32 + i;
#pragma unroll
      for (int s = 0; s < 16; ++s)
        corr += sC[l][s] * __expf(A[s] * cum) * g[s];
      float zv = b2f(xzbf[zbase + (long)i * 8192]);
      float y = (yp + corr) * (zv / (1.f + __expf(-zv)));
      ybuf[base + (long)i * 4096] = f2b(y);
    }
  }
}

// ------- residual add (bf16 h + bf16 partials) + LN -> bf16 -------
__global__ __launch_bounds__(256) void add_ln_k(
    const u16* __restrict__ hb, const u16* __restrict__ op,
    const float* __restrict__ g, const float* __restrict__ bta,
    u16* __restrict__ h2b)
{
  int row = blockIdx.x;
  int b = row >> 8, l = row & 255;
  long base = (long)row * 2048;
  long base1 = ((long)b * 256 + (255 - l)) * 2048;
  int t8 = threadIdx.x * 8;
  const u16* p0 = op;
  const u16* p1 = op + 4194304;
  const u16* p2 = op + 2L * 4194304;
  const u16* p3 = op + 3L * 4194304;
  float v[8];
  bf16x8 x8 = *(const bf16x8*)(hb + base + t8);
  bf16x8 a8 = *(const bf16x8*)(p0 + base + t8);
  bf16x8 b8 = *(const bf16x8*)(p1 + base + t8);
  bf16x8 c8v = *(const bf16x8*)(p2 + base1 + t8);
  bf16x8 d8 = *(const bf16x8*)(p3 + base1 + t8);
#pragma unroll
  for (int j = 0; j < 8; ++j)
    v[j] = b2f((u16)x8[j]) + b2f((u16)a8[j]) + b2f((u16)b8[j]) +
           b2f((u16)c8v[j]) + b2f((u16)d8[j]);
  float s = 0.f, ss = 0.f;
#pragma unroll
  for (int j = 0; j < 8; ++j) { s += v[j]; ss += v[j] * v[j]; }
#pragma unroll
  for (int off = 32; off >= 1; off >>= 1) {
    s += __shfl_xor(s, off, 64);
    ss += __shfl_xor(ss, off, 64);
  }
  __shared__ float red[8];
  int wid = threadIdx.x >> 6, lane = threadIdx.x & 63;
  if (lane == 0) { red[wid] = s; red[wid + 4] = ss; }
  __syncthreads();
  if (threadIdx.x == 0) {
    red[0] = red[0] + red[1] + red[2] + red[3];
    red[4] = red[4] + red[5] + red[6] + red[7];
  }
  __syncthreads();
  float mean = red[0] * (1.f / 2048.f);
  float var = red[4] * (1.f / 2048.f) - mean * mean;
  float inv = rsqrtf(var + 1e-5f);
  bf16x8 o;
#pragma unroll
  for (int j = 0; j < 8; ++j)
    o[j] = (short)f2b((v[j] - mean) * inv * g[t8 + j] + bta[t8 + j]);
  *(bf16x8*)(h2b + base + t8) = o;
}

// ---------------- 31x31 "same" conv via MFMA Toeplitz (bf16 in/out) ---------
__global__ __launch_bounds__(256) void dec_conv31_k(
    const u16* __restrict__ h2b, const u16* __restrict__ tb,
    u16* __restrict__ dc)
{
  __shared__ __align__(16) u16 sIn[94 * 120];
  const int b = blockIdx.z;
  const int l0 = blockIdx.y * 64;
  const int m0 = blockIdx.x * 64;
  const int tid = threadIdx.x;
  const u16* src = h2b + (long)b * 256 * 2048;
  for (int i = tid; i < 94 * 112; i += 256) {
    int r = i / 112, c = i - r * 112;
    int gl = l0 + r - 15, gm = m0 + c - 15;
    u16 v = 0;
    if (gl >= 0 && gl < 256 && gm >= 0 && gm < 2048)
      v = src[(long)gl * 2048 + gm];
    sIn[r * 120 + c] = v;
  }
  __syncthreads();
  const int wave = tid >> 6, lane = tid & 63;
  const int lr = lane & 15, lq = lane >> 4;

  f32x4 acc[4];
#pragma unroll
  for (int s = 0; s < 4; ++s) acc[s] = (f32x4){0.f, 0.f, 0.f, 0.f};

#pragma unroll 1
  for (int ki = 0; ki < 31; ++ki) {
    const u16* arow = &sIn[(wave * 16 + lr + ki) * 120];
#pragma unroll
    for (int h = 0; h < 2; ++h) {
      bf16x8 bv = *(const bf16x8*)&tb[((ki * 2 + h) * 16 + lr) * 32 + lq * 8];
#pragma unroll
      for (int ms = 0; ms < 4; ++ms) {
        bf16x8 av = *(const bf16x8*)&arow[ms * 16 + h * 32 + lq * 8];
        acc[ms] = __builtin_amdgcn_mfma_f32_16x16x32_bf16(av, bv, acc[ms], 0, 0, 0);
      }
    }
  }
#pragma unroll
  for (int ms = 0; ms < 4; ++ms) {
    f32x4 v = acc[ms];
#pragma unroll
    for (int r = 0; r < 4; ++r)
      dc[((long)b * 256 + l0 + wave * 16 + lq * 4 + r) * 2048 + m0 + ms * 16 + lr]
          = f2b(v[r]);
  }
}

// ---------------- fused transposed conv (stride 2x16), bf16 input ----------
__global__ __launch_bounds__(256) void convT_k(
    const u16* __restrict__ dc, const float* __restrict__ w,
    const float* __restrict__ wb, float* __restrict__ out)
{
  int j = blockIdx.x, b = blockIdx.y;
  __shared__ float sD[2048];
  __shared__ float sW[2048];
  int tid = threadIdx.x;
  const u16* drow = dc + ((long)b * 256 + j) * 2048;
  for (int i = tid; i < 2048; i += 256) { sD[i] = b2f(drow[i]); sW[i] = w[i]; }
  __syncthreads();
  float cb = wb[0];
  int owlo = tid & 15, ohbase = tid >> 4;
#pragma unroll
  for (int q = 0; q < 4; ++q) {
    int oh = ohbase + q * 16;
    int i = oh >> 1, a = oh & 1;
    float acc = cb;
#pragma unroll 8
    for (int e = 0; e < 64; ++e)
      acc += sD[e * 32 + i] * sW[e * 32 + a * 16 + owlo];
    out[((long)b * 64 + oh) * 4096 + j * 16 + owlo] = acc;
  }
}

// ---------------- launcher ----------------
extern "C" void kernel_launch(void* const* d_in, const int* in_sizes, int n_in,
                              void* d_out, int out_size, void* d_ws, size_t ws_size,
                              hipStream_t stream)
{
  const float* x      = (const float*)d_in[0];
  const int*   mask   = (const int*)d_in[1];
  const float* proj_w = (const float*)d_in[2];
  const float* proj_b = (const float*)d_in[3];
  const float* pos    = (const float*)d_in[4];
  const float* Wip    = (const float*)d_in[5];
  const float* convw  = (const float*)d_in[6];
  const float* convb  = (const float*)d_in[7];
  const float* Wx     = (const float*)d_in[8];
  const float* Wdt    = (const float*)d_in[9];
  const float* bdt    = (const float*)d_in[10];
  const float* Alog   = (const float*)d_in[11];
  const float* Dpv    = (const float*)d_in[12];
  const float* Wout   = (const float*)d_in[13];
  const float* lng    = (const float*)d_in[14];
  const float* lnb    = (const float*)d_in[15];
  const float* dkw    = (const float*)d_in[16];
  const float* ctw    = (const float*)d_in[17];
  const float* ctb    = (const float*)d_in[18];
  float* out = (float*)d_out;

  // workspace layout (bytes)
  char* p = (char*)d_ws;
  u16*   xz_bf   = (u16*)p;            // z-half used
  p += 67108864;
  u16*   u_bf    = (u16*)p;            // later dc alias (bf16)
  u16*   dc      = (u16*)p;
  p += 33554432;
  u16*   dt_bf   = (u16*)p; p += 67108864;     // also out_proj partials later
  float* xdbl    = (float*)p; p += 2621440;
  u16*   xdbl_bf = (u16*)p;  p += 1310720;
  u16*   h_bf    = (u16*)p;  p += 8388608;
  float* h2      = (float*)p; p += 16777216;   // used only as dtsum scratch
  u16*   y_bf    = (u16*)p;  p += 33554432;
  u16*   Wpool   = (u16*)p;  p += 67108864;    // Wip_bf; later Wout_bf (1st half)
  u16*   Wx_bf   = (u16*)p;  p += 2621440;
  u16*   Wdt_bf  = (u16*)p;  p += 2097152;
  u16*   tb      = (u16*)p;  p += 65536;
  u16*   h2b     = (u16*)p;  p += 8388608;

  // scratch aliases (temporally disjoint):
  float* part    = (float*)(Wpool + 16777216); // x_dbl split-K partials
  u16*   st_end  = (u16*)(Wpool + 16777216);   // scan chunk end-states (bf16)
  float* dtsum   = h2;
  u16*   opart   = dt_bf;                      // out_proj bf16 partials (dt dead)

  // weight converts + merged small prep
  cvt_bf16_k<<<32768, 256, 0, stream>>>(Wip, Wpool, 8388608);
  prep_k<<<2428, 256, 0, stream>>>(Wx, Wx_bf, Wdt, Wdt_bf, dkw, tb);

  // 1) patchify + pos embed (bf16 only)
  patchify_k<<<dim3(256, 8), 256, 0, stream>>>(x, mask, proj_w, proj_b, pos, h_bf);

  // 2) in_proj + fused conv1d/SiLU epilogue (XCD swizzle)
  gemm256_k<<<dim3(32, 8, 2), 512, 0, stream>>>(
      h_bf, Wpool, (long)8192 * 2048, xz_bf, (long)2048 * 8192,
      convw, convb, u_bf);

  // 3) x_dbl = u @ Wx^T via split-K(4) + reduce (fp32 + bf16 mirror)
  xdbl_part_k<<<dim3(2, 16, 8), 256, 0, stream>>>(u_bf, Wx_bf, part);
  xdbl_reduce_k<<<2560, 256, 0, stream>>>(part, xdbl, xdbl_bf);

  // 4) dt = softplus(x_dbl[:, :128] @ Wdt^T + bdt) -> bf16
  mfma_gemm_k<1, 0, 1><<<dim3(32, 16, 2), 256, 0, stream>>>(
      xdbl_bf, (long)2048 * 160, Wdt_bf, (long)4096 * 128, nullptr, 0L,
      dt_bf, (long)2048 * 4096, bdt, 4096, 4096, 128, 160, 0);

  // 5) chunked selective scan (bf16 end-states)
  scan_a_k<<<2048, 256, 0, stream>>>(dt_bf, u_bf, xdbl, Alog, Dpv, y_bf, st_end, dtsum);
  scan_b_k<<<1024, 512, 0, stream>>>(dt_bf, xz_bf, xdbl, Alog, st_end, dtsum, y_bf);

  // convert Wout into the (now dead) first half of Wpool
  cvt_bf16_k<<<16384, 256, 0, stream>>>(Wout, Wpool, 4194304);

  // 6) out_proj via 256^2 split-K(2), bf16 partials, XCD swizzle
  gemm256o_k<<<dim3(8, 8, 4), 512, 0, stream>>>(y_bf, Wpool, opart);

  // 7) h2b = LN(h_bf + p0+p1 + flip(p2+p3))
  add_ln_k<<<2048, 256, 0, stream>>>(h_bf, opart, lng, lnb, h2b);

  // 8) 31x31 same conv via MFMA Toeplitz (bf16 in/out) -> dc
  dec_conv31_k<<<dim3(32, 4, 8), 256, 0, stream>>>(h2b, tb, dc);

  // 9) fused transposed conv (bf16 in) -> rec
  convT_k<<<dim3(256, 8), 256, 0, stream>>>(dc, ctw, ctb, out);

  // 10) second output: x passthrough
  hipMemcpyAsync(out + 2097152, x, (size_t)2097152 * 4,
                 hipMemcpyDeviceToDevice, stream);
}